// Round 5
// baseline (481.380 us; speedup 1.0000x reference)
//
#include <hip/hip_runtime.h>
#include <math.h>

typedef short s16x8 __attribute__((ext_vector_type(8)));
typedef __bf16 b16x8 __attribute__((ext_vector_type(8)));
typedef float f32x4 __attribute__((ext_vector_type(4)));
typedef float f32x2 __attribute__((ext_vector_type(2)));
typedef unsigned int u32x4 __attribute__((ext_vector_type(4)));

__device__ inline short f2bf(float f) {
    unsigned u = __float_as_uint(f);
    unsigned r = u + 0x7FFFu + ((u >> 16) & 1u);   // RNE
    return (short)(r >> 16);
}
__device__ inline float bf2f(unsigned short u) {
    return __uint_as_float(((unsigned)u) << 16);
}

// ---------------- fused prep: count + make_wt1 + make_wt2 ----------------
// Wt chunk layout: [c = k0/32][b = n0/128][nt 0..7][lane 0..63][j 0..7]
//   value = W[c*32 + (lane>>4)*8 + j][b*128 + nt*16 + (lane&15)]

__device__ inline void make_wt_elem(const float* __restrict__ W, short* __restrict__ Wt,
                                    int K, int N, int idx) {
    int NB = N >> 7;
    int j = idx & 7;
    int l = (idx >> 3) & 63;
    int nt = (idx >> 9) & 7;
    int rest = idx >> 12;
    int b = rest % NB;
    int c = rest / NB;
    int k = c * 32 + (l >> 4) * 8 + j;
    int n = b * 128 + nt * 16 + (l & 15);
    Wt[idx] = f2bf(W[(size_t)k * N + n]);
}

__global__ void prep_kernel(const int* __restrict__ dst, int* __restrict__ cnt, int E,
                            const float* __restrict__ W1, short* __restrict__ Wt1,
                            const float* __restrict__ W2, short* __restrict__ Wt2,
                            int cb, int w1b) {
    int b = blockIdx.x;
    int tid = threadIdx.x;
    if (b < cb) {
        int e = b * 256 + tid;
        if (e < E) atomicAdd(&cnt[dst[e]], 1);
    } else if (b < cb + w1b) {
        int idx = (b - cb) * 256 + tid;
        make_wt_elem(W1, Wt1, 768, 256, idx);
    } else {
        int idx = (b - cb - w1b) * 256 + tid;
        make_wt_elem(W2, Wt2, 256, 128, idx);
    }
}

// ---------------- CSR scan chain ----------------

__global__ __launch_bounds__(1024) void blockscan_kernel(const int* __restrict__ cnt,
                                                         int* __restrict__ rp,
                                                         int* __restrict__ bsum, int n) {
    __shared__ int sdata[1024];
    int tid = threadIdx.x;
    int i = blockIdx.x * 1024 + tid;
    int v = (i < n) ? cnt[i] : 0;
    sdata[tid] = v;
    __syncthreads();
    for (int off = 1; off < 1024; off <<= 1) {
        int t = 0;
        if (tid >= off) t = sdata[tid - off];
        __syncthreads();
        sdata[tid] += t;
        __syncthreads();
    }
    if (i < n) rp[i] = sdata[tid] - v;       // local exclusive
    if (tid == 1023) bsum[blockIdx.x] = sdata[1023];
}

__global__ void topscan_kernel(int* bsum, int nb) {
    int lane = threadIdx.x;                   // 64 threads
    int carry = 0;
    for (int base = 0; base < nb; base += 64) {
        int idx = base + lane;
        int orig = (idx < nb) ? bsum[idx] : 0;
        int v = orig;
        for (int off = 1; off < 64; off <<= 1) {
            int t = __shfl_up(v, off, 64);
            if (lane >= off) v += t;
        }
        if (idx < nb) bsum[idx] = carry + v - orig;   // exclusive
        carry += __shfl(v, 63, 64);
    }
}

__global__ __launch_bounds__(1024) void fixup_kernel(int* __restrict__ rp,
                                                     const int* __restrict__ bsum,
                                                     const int* __restrict__ cnt,
                                                     int* __restrict__ cursor,
                                                     float* __restrict__ dinv,
                                                     int n, int E) {
    int i = blockIdx.x * 1024 + threadIdx.x;
    if (i < n) {
        int r = rp[i] + bsum[blockIdx.x];
        rp[i] = r;
        cursor[i] = r;
        dinv[i] = rsqrtf((float)cnt[i] + 1.0f);
    }
    if (i == 0) rp[n] = E;
}

__global__ void fill_kernel(const int* __restrict__ src, const int* __restrict__ dst,
                            int* __restrict__ cursor, const float* __restrict__ dinv,
                            int* __restrict__ csrc, float* __restrict__ cw, int E) {
    int e = blockIdx.x * blockDim.x + threadIdx.x;
    if (e >= E) return;
    int d = dst[e];
    int s = src[e];
    int p = atomicAdd(&cursor[d], 1);
    csrc[p] = s;
    cw[p] = dinv[s] * dinv[d];
}

// ---------------- GEMM1: h1(fp8)[M x 256] = x(fp32) @ Wt1(frag-ready bf16) ----------------
// round-2 v2 (best measured): 32 rows x 256 cols per block, 256 threads = 4 waves.
// Reg-stage fp32 -> truncate to bf16 -> swizzled fragment-ready LDS (48 KB,
// conflict-free layout shared with gemm_panel_kernel). One barrier; barrier-free K-loop.

__global__ __launch_bounds__(256, 3) void gemm1_kernel(const float* __restrict__ x,
                                                       const short* __restrict__ Wt,
                                                       unsigned char* __restrict__ h8,
                                                       int M) {
    constexpr int KC = 24;                     // 768 / 32
    constexpr int RT = 2;                      // row-tiles -> 32 rows per block
    constexpr int O = KC * 4;                  // 96 octets (8 k-elems) per row
    constexpr int F = KC * RT * 64 / 256;      // 12 frags staged per thread

    __shared__ s16x8 As[KC * RT * 64];         // 48 KB bf16, fragment-ready

    const int tid = threadIdx.x;
    const int m0 = blockIdx.x * (RT * 16);

    // stage: load fp32 pairs, truncation-pack to bf16
    s16x8 v[F];
#pragma unroll
    for (int i = 0; i < F; ++i) {
        int idx = i * 256 + tid;
        int r = idx / O;
        int o = idx - r * O;
        int row = m0 + r;
        if (row >= M) row = M - 1;
        const float4* fp = (const float4*)(x + (size_t)row * 768 + o * 8);
        float4 f0 = fp[0];
        float4 f1 = fp[1];
        u32x4 pk;
        pk.x = (__float_as_uint(f0.x) >> 16) | (__float_as_uint(f0.y) & 0xFFFF0000u);
        pk.y = (__float_as_uint(f0.z) >> 16) | (__float_as_uint(f0.w) & 0xFFFF0000u);
        pk.z = (__float_as_uint(f1.x) >> 16) | (__float_as_uint(f1.y) & 0xFFFF0000u);
        pk.w = (__float_as_uint(f1.z) >> 16) | (__float_as_uint(f1.w) & 0xFFFF0000u);
        v[i] = __builtin_bit_cast(s16x8, pk);
    }
#pragma unroll
    for (int i = 0; i < F; ++i) {
        int idx = i * 256 + tid;
        int r = idx / O;
        int o = idx - r * O;
        int c = o >> 2, q = o & 3;
        int slot = q * 16 + (((r & 15) + q + ((c & 3) << 2)) & 15);
        As[(c * RT + (r >> 4)) * 64 + slot] = v[i];
    }
    __syncthreads();

    const int lane = tid & 63;
    const int wave = tid >> 6;
    const int b128 = wave >> 1;                // 128-col B block
    const int nt0 = (wave & 1) * 4;            // first 16-col tile inside it
    const int q = lane >> 4;
    const int rl = lane & 15;
    const s16x8* wt = (const s16x8*)Wt;

    f32x4 acc[RT][4];
#pragma unroll
    for (int i = 0; i < RT; ++i)
#pragma unroll
        for (int j = 0; j < 4; ++j)
            acc[i][j] = (f32x4){0.f, 0.f, 0.f, 0.f};

#pragma unroll 4
    for (int c = 0; c < KC; ++c) {
        int slot = q * 16 + ((rl + q + ((c & 3) << 2)) & 15);
        b16x8 areg[RT], breg[4];
#pragma unroll
        for (int i = 0; i < RT; ++i)
            areg[i] = __builtin_bit_cast(b16x8, As[(c * RT + i) * 64 + slot]);
        size_t bb = (size_t)(c * 2 + b128) * 512 + nt0 * 64 + lane;
#pragma unroll
        for (int j = 0; j < 4; ++j)
            breg[j] = __builtin_bit_cast(b16x8, wt[bb + j * 64]);
#pragma unroll
        for (int i = 0; i < RT; ++i)
#pragma unroll
            for (int j = 0; j < 4; ++j)
                acc[i][j] = __builtin_amdgcn_mfma_f32_16x16x32_bf16(areg[i], breg[j], acc[i][j], 0, 0, 0);
    }

    const int quad = lane >> 4;
    const int nl = lane & 15;
#pragma unroll
    for (int i = 0; i < RT; ++i) {
        int rbase = m0 + i * 16 + quad * 4;
#pragma unroll
        for (int j = 0; j < 4; ++j) {
            int col = wave * 64 + j * 16 + nl;
#pragma unroll
            for (int r = 0; r < 4; ++r) {
                int row = rbase + r;
                if (row < M) {
                    unsigned u = __builtin_amdgcn_cvt_pk_fp8_f32(acc[i][j][r], acc[i][j][r], 0, false);
                    h8[(size_t)row * 256 + col] = (unsigned char)(u & 0xFF);
                }
            }
        }
    }
}

// ---------------- row-panel GEMM (bf16 A, layer 2) ----------------
// round-2 structure; F8 template flag: epilogue emits fp8 e4m3 bytes instead of bf16.

template<typename AT, int KC, int RT, int CW, int MINW, bool F8>
__global__ __launch_bounds__(256, MINW) void gemm_panel_kernel(
        const AT* __restrict__ A, const short* __restrict__ Wt,
        void* __restrict__ Cb, int M) {
    constexpr int K = KC * 32;
    constexpr int O = KC * 4;              // 8-elem octets per row
    constexpr int F = KC * RT / 4;         // frags staged per thread
    constexpr int NCOLS = CW * 64;
    constexpr int NB = NCOLS >> 7;         // 128-col B blocks
    constexpr int MT = RT * CW / 4;        // m-tiles per wave

    __shared__ s16x8 As[KC * RT * 64];

    const int tid = threadIdx.x;
    const int m0 = blockIdx.x * (RT * 16);

    s16x8 v[F];
#pragma unroll
    for (int i = 0; i < F; ++i) {
        int idx = i * 256 + tid;
        int r = idx / O;
        int o = idx - r * O;
        int row = m0 + r;
        if (row >= M) row = M - 1;
        v[i] = *(const s16x8*)((const unsigned short*)A + (size_t)row * K + o * 8);
    }
#pragma unroll
    for (int i = 0; i < F; ++i) {
        int idx = i * 256 + tid;
        int r = idx / O;
        int o = idx - r * O;
        int c = o >> 2, q = o & 3;
        int slot = q * 16 + (((r & 15) + q + ((c & 3) << 2)) & 15);
        As[(c * RT + (r >> 4)) * 64 + slot] = v[i];
    }
    __syncthreads();

    const int lane = tid & 63;
    const int wave = tid >> 6;
    const int cw_i = wave % CW;
    const int rg = wave / CW;
    const int mtb = rg * MT;
    const int b128 = (cw_i * 64) >> 7;
    const int nt0 = (cw_i * 4) & 7;
    const int q = lane >> 4;
    const int rl = lane & 15;
    const s16x8* wt = (const s16x8*)Wt;

    f32x4 acc[MT][4];
#pragma unroll
    for (int i = 0; i < MT; ++i)
#pragma unroll
        for (int j = 0; j < 4; ++j)
            acc[i][j] = (f32x4){0.f, 0.f, 0.f, 0.f};

#pragma unroll 4
    for (int c = 0; c < KC; ++c) {
        int slot = q * 16 + ((rl + q + ((c & 3) << 2)) & 15);
        b16x8 areg[MT], breg[4];
#pragma unroll
        for (int i = 0; i < MT; ++i)
            areg[i] = __builtin_bit_cast(b16x8, As[(c * RT + mtb + i) * 64 + slot]);
        size_t bb = (size_t)(c * NB + b128) * 512 + nt0 * 64 + lane;
#pragma unroll
        for (int j = 0; j < 4; ++j)
            breg[j] = __builtin_bit_cast(b16x8, wt[bb + j * 64]);
#pragma unroll
        for (int i = 0; i < MT; ++i)
#pragma unroll
            for (int j = 0; j < 4; ++j)
                acc[i][j] = __builtin_amdgcn_mfma_f32_16x16x32_bf16(areg[i], breg[j], acc[i][j], 0, 0, 0);
    }

    const int quad = lane >> 4;
    const int nl = lane & 15;
#pragma unroll
    for (int i = 0; i < MT; ++i) {
        int rbase = m0 + (mtb + i) * 16 + quad * 4;
#pragma unroll
        for (int j = 0; j < 4; ++j) {
            int col = cw_i * 64 + j * 16 + nl;
#pragma unroll
            for (int rr = 0; rr < 4; ++rr) {
                int row = rbase + rr;
                if (row < M) {
                    if (F8) {
                        unsigned u = __builtin_amdgcn_cvt_pk_fp8_f32(acc[i][j][rr], acc[i][j][rr], 0, false);
                        ((unsigned char*)Cb)[(size_t)row * NCOLS + col] = (unsigned char)(u & 0xFF);
                    } else {
                        ((unsigned short*)Cb)[(size_t)row * NCOLS + col] = (unsigned short)f2bf(acc[i][j][rr]);
                    }
                }
            }
        }
    }
}

// ---------------- aggregation ----------------
// 4-edge-parallel gather (round-2). Wave per node; lane = (eg = edge slot, ch = 16B chunk).
// Edge indices/weights batch-loaded 64-at-a-time to regs, distributed by shuffle, so the
// inner loop's only memory op is one dwordx4 row-gather. Cross-lane xor reduce combines
// the edge slots once per node.

__global__ __launch_bounds__(256) void agg256_f8_kernel(const unsigned char* __restrict__ h8,
                                                        const int* __restrict__ rp,
                                                        const int* __restrict__ csrc,
                                                        const float* __restrict__ cw,
                                                        const float* __restrict__ dinv,
                                                        const float* __restrict__ bias,
                                                        unsigned short* __restrict__ out, int n) {
    int node = blockIdx.x * 4 + (threadIdx.x >> 6);
    int lane = threadIdx.x & 63;
    if (node >= n) return;
    const int eg = lane >> 4;                    // edge slot 0..3
    const int ch = lane & 15;                    // 16-channel chunk
    float di = dinv[node];

    float acc[16];
    {
        u32x4 v = *(const u32x4*)(h8 + (size_t)node * 256 + ch * 16);
        float ws = (eg == 0) ? di * di : 0.f;    // self term counted once
#pragma unroll
        for (int u = 0; u < 4; ++u) {
            f32x2 lo = __builtin_amdgcn_cvt_pk_f32_fp8(v[u], false);
            f32x2 hi = __builtin_amdgcn_cvt_pk_f32_fp8(v[u], true);
            acc[u * 4 + 0] = ws * lo.x; acc[u * 4 + 1] = ws * lo.y;
            acc[u * 4 + 2] = ws * hi.x; acc[u * 4 + 3] = ws * hi.y;
        }
    }

    int e0 = rp[node], e1 = rp[node + 1];
    for (int base = e0; base < e1; base += 64) {
        int idx = base + lane;
        int sb = (idx < e1) ? csrc[idx] : 0;
        float wb = (idx < e1) ? cw[idx] : 0.f;
        int cnt = e1 - base; if (cnt > 64) cnt = 64;
#pragma unroll 2
        for (int i = 0; i < cnt; i += 4) {
            int s = __shfl(sb, i + eg, 64);       // i+eg <= 63 always (i step 4, i<=60)
            float w = __shfl(wb, i + eg, 64);
            u32x4 v = *(const u32x4*)(h8 + (size_t)s * 256 + ch * 16);
#pragma unroll
            for (int u = 0; u < 4; ++u) {
                f32x2 lo = __builtin_amdgcn_cvt_pk_f32_fp8(v[u], false);
                f32x2 hi = __builtin_amdgcn_cvt_pk_f32_fp8(v[u], true);
                acc[u * 4 + 0] += w * lo.x; acc[u * 4 + 1] += w * lo.y;
                acc[u * 4 + 2] += w * hi.x; acc[u * 4 + 3] += w * hi.y;
            }
        }
    }

    // combine the 4 edge slots
#pragma unroll
    for (int k = 0; k < 16; ++k) {
        acc[k] += __shfl_xor(acc[k], 16, 64);
        acc[k] += __shfl_xor(acc[k], 32, 64);
    }

    // bias + relu + pack to bf16; lanes eg 0/1 store the two 16B halves of the 32B chunk
    unsigned pk[8];
#pragma unroll
    for (int k = 0; k < 8; ++k) {
        float b0 = bias[ch * 16 + 2 * k];
        float b1 = bias[ch * 16 + 2 * k + 1];
        float a0 = fmaxf(acc[2 * k] + b0, 0.f);
        float a1 = fmaxf(acc[2 * k + 1] + b1, 0.f);
        pk[k] = ((unsigned)(unsigned short)f2bf(a0)) | (((unsigned)(unsigned short)f2bf(a1)) << 16);
    }
    if (eg < 2) {
        u32x4 ov;
        ov.x = pk[eg * 4 + 0]; ov.y = pk[eg * 4 + 1];
        ov.z = pk[eg * 4 + 2]; ov.w = pk[eg * 4 + 3];
        *(u32x4*)((char*)out + (size_t)node * 512 + ch * 32 + eg * 16) = ov;
    }
}

// Layer 2 fused with W3: v3 — h2 is fp8 e4m3 (128 B/row), wave is 8-edge-parallel:
// eg = lane>>3 (edge slot 0..7), ch = lane&7 (16B chunk = 16 channels). Gather traffic
// halves vs bf16 and MLP per wave doubles. a2 = relu(agg+b2); z = a2 @ W3 (128x2).
__global__ __launch_bounds__(256) void agg128_w3_kernel(const unsigned char* __restrict__ h,
                                                        const int* __restrict__ rp,
                                                        const int* __restrict__ csrc,
                                                        const float* __restrict__ cw,
                                                        const float* __restrict__ dinv,
                                                        const float* __restrict__ b2,
                                                        const float* __restrict__ W3,
                                                        float* __restrict__ z, int n) {
    int node = blockIdx.x * 4 + (threadIdx.x >> 6);
    int lane = threadIdx.x & 63;
    if (node >= n) return;
    const int eg = lane >> 3;                    // edge slot 0..7
    const int ch = lane & 7;                     // 16B chunk (16 fp8 channels)
    float di = dinv[node];

    float acc[16];
    {
        u32x4 v = *(const u32x4*)(h + (size_t)node * 128 + ch * 16);
        float ws = (eg == 0) ? di * di : 0.f;    // self term counted once
#pragma unroll
        for (int u = 0; u < 4; ++u) {
            f32x2 lo = __builtin_amdgcn_cvt_pk_f32_fp8(v[u], false);
            f32x2 hi = __builtin_amdgcn_cvt_pk_f32_fp8(v[u], true);
            acc[u * 4 + 0] = ws * lo.x; acc[u * 4 + 1] = ws * lo.y;
            acc[u * 4 + 2] = ws * hi.x; acc[u * 4 + 3] = ws * hi.y;
        }
    }

    int e0 = rp[node], e1 = rp[node + 1];
    for (int base = e0; base < e1; base += 64) {
        int idx = base + lane;
        int sb = (idx < e1) ? csrc[idx] : 0;
        float wb = (idx < e1) ? cw[idx] : 0.f;
        int cnt = e1 - base; if (cnt > 64) cnt = 64;
#pragma unroll 2
        for (int i = 0; i < cnt; i += 8) {
            int s = __shfl(sb, i + eg, 64);       // i+eg <= 63 (i step 8, i<=56, eg<=7)
            float w = __shfl(wb, i + eg, 64);
            u32x4 v = *(const u32x4*)(h + (size_t)s * 128 + ch * 16);
#pragma unroll
            for (int u = 0; u < 4; ++u) {
                f32x2 lo = __builtin_amdgcn_cvt_pk_f32_fp8(v[u], false);
                f32x2 hi = __builtin_amdgcn_cvt_pk_f32_fp8(v[u], true);
                acc[u * 4 + 0] += w * lo.x; acc[u * 4 + 1] += w * lo.y;
                acc[u * 4 + 2] += w * hi.x; acc[u * 4 + 3] += w * hi.y;
            }
        }
    }

    // combine the 8 edge slots (xor over lane bits 3..5)
#pragma unroll
    for (int k = 0; k < 16; ++k) {
        acc[k] += __shfl_xor(acc[k], 8, 64);
        acc[k] += __shfl_xor(acc[k], 16, 64);
        acc[k] += __shfl_xor(acc[k], 32, 64);
    }

    // a2 = relu(acc + b2); z partials over this lane's 16 channels
    float z0 = 0.f, z1 = 0.f;
#pragma unroll
    for (int k = 0; k < 16; ++k) {
        float a = fmaxf(acc[k] + b2[ch * 16 + k], 0.f);
        z0 += a * W3[(ch * 16 + k) * 2];
        z1 += a * W3[(ch * 16 + k) * 2 + 1];
    }
    // reduce over the 8 ch lanes (xor over lane bits 0..2)
    for (int off = 4; off > 0; off >>= 1) {
        z0 += __shfl_xor(z0, off, 64);
        z1 += __shfl_xor(z1, off, 64);
    }
    if (lane == 0) {
        z[2 * (size_t)node] = z0;
        z[2 * (size_t)node + 1] = z1;
    }
}

__global__ void agg3_kernel(const float* __restrict__ z, const int* __restrict__ rp,
                            const int* __restrict__ csrc, const float* __restrict__ cw,
                            const float* __restrict__ dinv, const float* __restrict__ bias,
                            float* __restrict__ out, int n) {
    int node = blockIdx.x * blockDim.x + threadIdx.x;
    if (node >= n) return;
    float di = dinv[node];
    float a0 = di * di * z[2 * (size_t)node];
    float a1 = di * di * z[2 * (size_t)node + 1];
    int e1 = rp[node + 1];
    for (int e = rp[node]; e < e1; ++e) {
        int s = csrc[e];
        float w = cw[e];
        a0 += w * z[2 * (size_t)s];
        a1 += w * z[2 * (size_t)s + 1];
    }
    a0 += bias[0];
    a1 += bias[1];
    out[2 * (size_t)node]     = 1.f / (1.f + __expf(-a0));
    out[2 * (size_t)node + 1] = 1.f / (1.f + __expf(-a1));
}

// ---------------- launch ----------------

extern "C" void kernel_launch(void* const* d_in, const int* in_sizes, int n_in,
                              void* d_out, int out_size, void* d_ws, size_t ws_size,
                              hipStream_t stream) {
    const float* x  = (const float*)d_in[0];
    const int*   ei = (const int*)d_in[1];
    const float* W1 = (const float*)d_in[2];
    const float* b1 = (const float*)d_in[3];
    const float* W2 = (const float*)d_in[4];
    const float* b2 = (const float*)d_in[5];
    const float* W3 = (const float*)d_in[6];
    const float* b3 = (const float*)d_in[7];
    float* out = (float*)d_out;

    const int E  = in_sizes[1] / 2;
    const int C1 = in_sizes[3];              // 256
    const int C2 = in_sizes[5];              // 128
    const int K1 = in_sizes[2] / C1;         // 768
    const int N  = in_sizes[0] / K1;         // 50000

    const int* srcv = ei;
    const int* dstv = ei + E;

    char* p = (char*)d_ws;
    auto carve = [&](size_t bytes) {
        char* r = p;
        p += (bytes + 255) & ~(size_t)255;
        return r;
    };
    int*   cnt    = (int*)carve((size_t)N * 4);
    int*   rp     = (int*)carve((size_t)(N + 1) * 4);
    int*   cursor = (int*)carve((size_t)N * 4);
    float* dinv   = (float*)carve((size_t)N * 4);
    int*   bsum   = (int*)carve(1024 * 4);
    int*   csrc   = (int*)carve((size_t)E * 4);
    float* cw     = (float*)carve((size_t)E * 4);
    short* Wt1    = (short*)carve((size_t)K1 * C1 * 2);
    short* Wt2    = (short*)carve((size_t)C1 * C2 * 2);
    unsigned char* h8 = (unsigned char*)carve((size_t)N * C1);       // fp8 h1
    unsigned short* hB = (unsigned short*)carve((size_t)N * C1 * 2); // bf16 a1
    unsigned char* h2 = (unsigned char*)carve((size_t)N * C2);       // fp8 h2
    float* zbuf   = (float*)carve((size_t)N * 2 * 4);

    const int nb = (N + 1023) / 1024;
    const int cb = (E + 255) / 256;
    const int w1b = (K1 * C1) / 256;         // 768
    const int w2b = (C1 * C2) / 256;         // 128

    // CSR + weight prep (fused)
    hipMemsetAsync(cnt, 0, (size_t)N * 4, stream);
    prep_kernel<<<cb + w1b + w2b, 256, 0, stream>>>(dstv, cnt, E, W1, Wt1, W2, Wt2, cb, w1b);
    blockscan_kernel<<<nb, 1024, 0, stream>>>(cnt, rp, bsum, N);
    topscan_kernel<<<1, 64, 0, stream>>>(bsum, nb);
    fixup_kernel<<<nb, 1024, 0, stream>>>(rp, bsum, cnt, cursor, dinv, N, E);
    fill_kernel<<<(E + 255) / 256, 256, 0, stream>>>(srcv, dstv, cursor, dinv, csrc, cw, E);

    // Layer 1: h1 = x @ W1 (fp8 out) ; a1 = relu(Ahat h1 + b1)
    gemm1_kernel<<<(N + 31) / 32, 256, 0, stream>>>(x, Wt1, h8, N);
    agg256_f8_kernel<<<(N + 3) / 4, 256, 0, stream>>>(h8, rp, csrc, cw, dinv, b1, hB, N);

    // Layer 2: h2 = a1 @ W2 (64-row panels, fp8 out) ; fused a2 = relu(agg+b2), z = a2 @ W3
    gemm_panel_kernel<unsigned short, 8, 4, 2, 4, true><<<(N + 63) / 64, 256, 0, stream>>>(hB, Wt2, h2, N);
    agg128_w3_kernel<<<(N + 3) / 4, 256, 0, stream>>>(h2, rp, csrc, cw, dinv, b2, W3, zbuf, N);

    // Layer 3 aggregation + sigmoid
    agg3_kernel<<<(N + 255) / 256, 256, 0, stream>>>(zbuf, rp, csrc, cw, dinv, b3, out, N);
}

// Round 6
// 460.278 us; speedup vs baseline: 1.0458x; 1.0458x over previous
//
#include <hip/hip_runtime.h>
#include <math.h>

typedef short s16x8 __attribute__((ext_vector_type(8)));
typedef __bf16 b16x8 __attribute__((ext_vector_type(8)));
typedef float f32x4 __attribute__((ext_vector_type(4)));
typedef float f32x2 __attribute__((ext_vector_type(2)));
typedef unsigned int u32x4 __attribute__((ext_vector_type(4)));

__device__ inline short f2bf(float f) {
    unsigned u = __float_as_uint(f);
    unsigned r = u + 0x7FFFu + ((u >> 16) & 1u);   // RNE
    return (short)(r >> 16);
}
__device__ inline float bf2f(unsigned short u) {
    return __uint_as_float(((unsigned)u) << 16);
}

// ---------------- fused prep: count + make_wt1 + make_wt2 ----------------
// Wt chunk layout: [c = k0/32][b = n0/128][nt 0..7][lane 0..63][j 0..7]
//   value = W[c*32 + (lane>>4)*8 + j][b*128 + nt*16 + (lane&15)]

__device__ inline void make_wt_elem(const float* __restrict__ W, short* __restrict__ Wt,
                                    int K, int N, int idx) {
    int NB = N >> 7;
    int j = idx & 7;
    int l = (idx >> 3) & 63;
    int nt = (idx >> 9) & 7;
    int rest = idx >> 12;
    int b = rest % NB;
    int c = rest / NB;
    int k = c * 32 + (l >> 4) * 8 + j;
    int n = b * 128 + nt * 16 + (l & 15);
    Wt[idx] = f2bf(W[(size_t)k * N + n]);
}

__global__ void prep_kernel(const int* __restrict__ dst, int* __restrict__ cnt, int E,
                            const float* __restrict__ W1, short* __restrict__ Wt1,
                            const float* __restrict__ W2, short* __restrict__ Wt2,
                            int cb, int w1b) {
    int b = blockIdx.x;
    int tid = threadIdx.x;
    if (b < cb) {
        int e = b * 256 + tid;
        if (e < E) atomicAdd(&cnt[dst[e]], 1);
    } else if (b < cb + w1b) {
        int idx = (b - cb) * 256 + tid;
        make_wt_elem(W1, Wt1, 768, 256, idx);
    } else {
        int idx = (b - cb - w1b) * 256 + tid;
        make_wt_elem(W2, Wt2, 256, 128, idx);
    }
}

// ---------------- CSR scan chain ----------------

__global__ __launch_bounds__(1024) void blockscan_kernel(const int* __restrict__ cnt,
                                                         int* __restrict__ rp,
                                                         int* __restrict__ bsum, int n) {
    __shared__ int sdata[1024];
    int tid = threadIdx.x;
    int i = blockIdx.x * 1024 + tid;
    int v = (i < n) ? cnt[i] : 0;
    sdata[tid] = v;
    __syncthreads();
    for (int off = 1; off < 1024; off <<= 1) {
        int t = 0;
        if (tid >= off) t = sdata[tid - off];
        __syncthreads();
        sdata[tid] += t;
        __syncthreads();
    }
    if (i < n) rp[i] = sdata[tid] - v;       // local exclusive
    if (tid == 1023) bsum[blockIdx.x] = sdata[1023];
}

__global__ void topscan_kernel(int* bsum, int nb) {
    int lane = threadIdx.x;                   // 64 threads
    int carry = 0;
    for (int base = 0; base < nb; base += 64) {
        int idx = base + lane;
        int orig = (idx < nb) ? bsum[idx] : 0;
        int v = orig;
        for (int off = 1; off < 64; off <<= 1) {
            int t = __shfl_up(v, off, 64);
            if (lane >= off) v += t;
        }
        if (idx < nb) bsum[idx] = carry + v - orig;   // exclusive
        carry += __shfl(v, 63, 64);
    }
}

__global__ __launch_bounds__(1024) void fixup_kernel(int* __restrict__ rp,
                                                     const int* __restrict__ bsum,
                                                     const int* __restrict__ cnt,
                                                     int* __restrict__ cursor,
                                                     float* __restrict__ dinv,
                                                     int n, int E) {
    int i = blockIdx.x * 1024 + threadIdx.x;
    if (i < n) {
        int r = rp[i] + bsum[blockIdx.x];
        rp[i] = r;
        cursor[i] = r;
        dinv[i] = rsqrtf((float)cnt[i] + 1.0f);
    }
    if (i == 0) rp[n] = E;
}

__global__ void fill_kernel(const int* __restrict__ src, const int* __restrict__ dst,
                            int* __restrict__ cursor, const float* __restrict__ dinv,
                            int* __restrict__ csrc, float* __restrict__ cw, int E) {
    int e = blockIdx.x * blockDim.x + threadIdx.x;
    if (e >= E) return;
    int d = dst[e];
    int s = src[e];
    int p = atomicAdd(&cursor[d], 1);
    csrc[p] = s;
    cw[p] = dinv[s] * dinv[d];
}

// ---------------- GEMM1: h1(fp8)[M x 256] = x(fp32) @ Wt1(frag-ready bf16) ----------------
// v5: same 32-row / 48 KB frag-ready LDS tile and K-loop as the round-2 champion, but
// 512 threads = 8 waves (2 row-groups x 4 col-groups) over the SAME LDS -> 3 blocks/CU
// x 8 waves = 24 waves/CU (was 12). Each wave: RT_W=1 row-tile, 4 MFMAs + 4 B-loads
// per K-step; rg=0/1 waves of a col-group read identical B frags (L1-served). Same
// accumulation order per output element -> bit-identical numerics.

__global__ __launch_bounds__(512, 6) void gemm1_kernel(const float* __restrict__ x,
                                                       const short* __restrict__ Wt,
                                                       unsigned char* __restrict__ h8,
                                                       int M) {
    constexpr int KC = 24;                     // 768 / 32
    constexpr int RT = 2;                      // row-tiles in LDS -> 32 rows per block
    constexpr int O = KC * 4;                  // 96 octets (8 k-elems) per row
    constexpr int F = KC * RT * 64 / 512;      // 6 frags staged per thread

    __shared__ s16x8 As[KC * RT * 64];         // 48 KB bf16, fragment-ready

    const int tid = threadIdx.x;
    const int m0 = blockIdx.x * (RT * 16);

    // stage: load fp32 pairs, truncation-pack to bf16
    s16x8 v[F];
#pragma unroll
    for (int i = 0; i < F; ++i) {
        int idx = i * 512 + tid;
        int r = idx / O;
        int o = idx - r * O;
        int row = m0 + r;
        if (row >= M) row = M - 1;
        const float4* fp = (const float4*)(x + (size_t)row * 768 + o * 8);
        float4 f0 = fp[0];
        float4 f1 = fp[1];
        u32x4 pk;
        pk.x = (__float_as_uint(f0.x) >> 16) | (__float_as_uint(f0.y) & 0xFFFF0000u);
        pk.y = (__float_as_uint(f0.z) >> 16) | (__float_as_uint(f0.w) & 0xFFFF0000u);
        pk.z = (__float_as_uint(f1.x) >> 16) | (__float_as_uint(f1.y) & 0xFFFF0000u);
        pk.w = (__float_as_uint(f1.z) >> 16) | (__float_as_uint(f1.w) & 0xFFFF0000u);
        v[i] = __builtin_bit_cast(s16x8, pk);
    }
#pragma unroll
    for (int i = 0; i < F; ++i) {
        int idx = i * 512 + tid;
        int r = idx / O;
        int o = idx - r * O;
        int c = o >> 2, q = o & 3;
        int slot = q * 16 + (((r & 15) + q + ((c & 3) << 2)) & 15);
        As[(c * RT + (r >> 4)) * 64 + slot] = v[i];
    }
    __syncthreads();

    const int lane = tid & 63;
    const int wave = tid >> 6;                 // 0..7
    const int cw_i = wave & 3;                 // col group (64 cols)
    const int rg = wave >> 2;                  // row tile 0..1
    const int b128 = cw_i >> 1;                // 128-col B block
    const int nt0 = (cw_i & 1) * 4;            // first 16-col tile inside it
    const int q = lane >> 4;
    const int rl = lane & 15;
    const s16x8* wt = (const s16x8*)Wt;

    f32x4 acc[4];
#pragma unroll
    for (int j = 0; j < 4; ++j) acc[j] = (f32x4){0.f, 0.f, 0.f, 0.f};

#pragma unroll 4
    for (int c = 0; c < KC; ++c) {
        int slot = q * 16 + ((rl + q + ((c & 3) << 2)) & 15);
        b16x8 areg = __builtin_bit_cast(b16x8, As[(c * RT + rg) * 64 + slot]);
        b16x8 breg[4];
        size_t bb = (size_t)(c * 2 + b128) * 512 + nt0 * 64 + lane;
#pragma unroll
        for (int j = 0; j < 4; ++j)
            breg[j] = __builtin_bit_cast(b16x8, wt[bb + j * 64]);
#pragma unroll
        for (int j = 0; j < 4; ++j)
            acc[j] = __builtin_amdgcn_mfma_f32_16x16x32_bf16(areg, breg[j], acc[j], 0, 0, 0);
    }

    const int quad = lane >> 4;
    const int nl = lane & 15;
    int rbase = m0 + rg * 16 + quad * 4;
#pragma unroll
    for (int j = 0; j < 4; ++j) {
        int col = cw_i * 64 + j * 16 + nl;
#pragma unroll
        for (int r = 0; r < 4; ++r) {
            int row = rbase + r;
            if (row < M) {
                unsigned u = __builtin_amdgcn_cvt_pk_fp8_f32(acc[j][r], acc[j][r], 0, false);
                h8[(size_t)row * 256 + col] = (unsigned char)(u & 0xFF);
            }
        }
    }
}

// ---------------- row-panel GEMM (bf16 A, layer 2) ----------------

template<typename AT, int KC, int RT, int CW, int MINW>
__global__ __launch_bounds__(256, MINW) void gemm_panel_kernel(
        const AT* __restrict__ A, const short* __restrict__ Wt,
        unsigned short* __restrict__ Cb, int M) {
    constexpr int K = KC * 32;
    constexpr int O = KC * 4;              // 8-elem octets per row
    constexpr int F = KC * RT / 4;         // frags staged per thread
    constexpr int NCOLS = CW * 64;
    constexpr int NB = NCOLS >> 7;         // 128-col B blocks
    constexpr int MT = RT * CW / 4;        // m-tiles per wave

    __shared__ s16x8 As[KC * RT * 64];

    const int tid = threadIdx.x;
    const int m0 = blockIdx.x * (RT * 16);

    s16x8 v[F];
#pragma unroll
    for (int i = 0; i < F; ++i) {
        int idx = i * 256 + tid;
        int r = idx / O;
        int o = idx - r * O;
        int row = m0 + r;
        if (row >= M) row = M - 1;
        v[i] = *(const s16x8*)((const unsigned short*)A + (size_t)row * K + o * 8);
    }
#pragma unroll
    for (int i = 0; i < F; ++i) {
        int idx = i * 256 + tid;
        int r = idx / O;
        int o = idx - r * O;
        int c = o >> 2, q = o & 3;
        int slot = q * 16 + (((r & 15) + q + ((c & 3) << 2)) & 15);
        As[(c * RT + (r >> 4)) * 64 + slot] = v[i];
    }
    __syncthreads();

    const int lane = tid & 63;
    const int wave = tid >> 6;
    const int cw_i = wave % CW;
    const int rg = wave / CW;
    const int mtb = rg * MT;
    const int b128 = (cw_i * 64) >> 7;
    const int nt0 = (cw_i * 4) & 7;
    const int q = lane >> 4;
    const int rl = lane & 15;
    const s16x8* wt = (const s16x8*)Wt;

    f32x4 acc[MT][4];
#pragma unroll
    for (int i = 0; i < MT; ++i)
#pragma unroll
        for (int j = 0; j < 4; ++j)
            acc[i][j] = (f32x4){0.f, 0.f, 0.f, 0.f};

#pragma unroll 4
    for (int c = 0; c < KC; ++c) {
        int slot = q * 16 + ((rl + q + ((c & 3) << 2)) & 15);
        b16x8 areg[MT], breg[4];
#pragma unroll
        for (int i = 0; i < MT; ++i)
            areg[i] = __builtin_bit_cast(b16x8, As[(c * RT + mtb + i) * 64 + slot]);
        size_t bb = (size_t)(c * NB + b128) * 512 + nt0 * 64 + lane;
#pragma unroll
        for (int j = 0; j < 4; ++j)
            breg[j] = __builtin_bit_cast(b16x8, wt[bb + j * 64]);
#pragma unroll
        for (int i = 0; i < MT; ++i)
#pragma unroll
            for (int j = 0; j < 4; ++j)
                acc[i][j] = __builtin_amdgcn_mfma_f32_16x16x32_bf16(areg[i], breg[j], acc[i][j], 0, 0, 0);
    }

    const int quad = lane >> 4;
    const int nl = lane & 15;
#pragma unroll
    for (int i = 0; i < MT; ++i) {
        int rbase = m0 + (mtb + i) * 16 + quad * 4;
#pragma unroll
        for (int j = 0; j < 4; ++j) {
            int col = cw_i * 64 + j * 16 + nl;
#pragma unroll
            for (int rr = 0; rr < 4; ++rr) {
                int row = rbase + rr;
                if (row < M) Cb[(size_t)row * NCOLS + col] = (unsigned short)f2bf(acc[i][j][rr]);
            }
        }
    }
}

// ---------------- aggregation ----------------
// 4-edge-parallel gather (round-2 champion). Wave per node; lane = (eg = edge slot 0..3,
// ch = 16B chunk). Edge indices/weights batch-loaded 64-at-a-time to regs, distributed
// by shuffle; inner loop's only memory op is one dwordx4 row-gather covering 4 edges.
// Cross-lane xor(16/32) reduction combines the 4 edge slots once per node.

__global__ __launch_bounds__(256) void agg256_f8_kernel(const unsigned char* __restrict__ h8,
                                                        const int* __restrict__ rp,
                                                        const int* __restrict__ csrc,
                                                        const float* __restrict__ cw,
                                                        const float* __restrict__ dinv,
                                                        const float* __restrict__ bias,
                                                        unsigned short* __restrict__ out, int n) {
    int node = blockIdx.x * 4 + (threadIdx.x >> 6);
    int lane = threadIdx.x & 63;
    if (node >= n) return;
    const int eg = lane >> 4;                    // edge slot 0..3
    const int ch = lane & 15;                    // 16-channel chunk
    float di = dinv[node];

    float acc[16];
    {
        u32x4 v = *(const u32x4*)(h8 + (size_t)node * 256 + ch * 16);
        float ws = (eg == 0) ? di * di : 0.f;    // self term counted once
#pragma unroll
        for (int u = 0; u < 4; ++u) {
            f32x2 lo = __builtin_amdgcn_cvt_pk_f32_fp8(v[u], false);
            f32x2 hi = __builtin_amdgcn_cvt_pk_f32_fp8(v[u], true);
            acc[u * 4 + 0] = ws * lo.x; acc[u * 4 + 1] = ws * lo.y;
            acc[u * 4 + 2] = ws * hi.x; acc[u * 4 + 3] = ws * hi.y;
        }
    }

    int e0 = rp[node], e1 = rp[node + 1];
    for (int base = e0; base < e1; base += 64) {
        int idx = base + lane;
        int sb = (idx < e1) ? csrc[idx] : 0;
        float wb = (idx < e1) ? cw[idx] : 0.f;
        int cnt = e1 - base; if (cnt > 64) cnt = 64;
#pragma unroll 2
        for (int i = 0; i < cnt; i += 4) {
            int s = __shfl(sb, i + eg, 64);       // i+eg <= 63 always (i step 4, i<=60)
            float w = __shfl(wb, i + eg, 64);
            u32x4 v = *(const u32x4*)(h8 + (size_t)s * 256 + ch * 16);
#pragma unroll
            for (int u = 0; u < 4; ++u) {
                f32x2 lo = __builtin_amdgcn_cvt_pk_f32_fp8(v[u], false);
                f32x2 hi = __builtin_amdgcn_cvt_pk_f32_fp8(v[u], true);
                acc[u * 4 + 0] += w * lo.x; acc[u * 4 + 1] += w * lo.y;
                acc[u * 4 + 2] += w * hi.x; acc[u * 4 + 3] += w * hi.y;
            }
        }
    }

    // combine the 4 edge slots
#pragma unroll
    for (int k = 0; k < 16; ++k) {
        acc[k] += __shfl_xor(acc[k], 16, 64);
        acc[k] += __shfl_xor(acc[k], 32, 64);
    }

    // bias + relu + pack to bf16; lanes eg 0/1 store the two 16B halves of the 32B chunk
    unsigned pk[8];
#pragma unroll
    for (int k = 0; k < 8; ++k) {
        float b0 = bias[ch * 16 + 2 * k];
        float b1 = bias[ch * 16 + 2 * k + 1];
        float a0 = fmaxf(acc[2 * k] + b0, 0.f);
        float a1 = fmaxf(acc[2 * k + 1] + b1, 0.f);
        pk[k] = ((unsigned)(unsigned short)f2bf(a0)) | (((unsigned)(unsigned short)f2bf(a1)) << 16);
    }
    if (eg < 2) {
        u32x4 ov;
        ov.x = pk[eg * 4 + 0]; ov.y = pk[eg * 4 + 1];
        ov.z = pk[eg * 4 + 2]; ov.w = pk[eg * 4 + 3];
        *(u32x4*)((char*)out + (size_t)node * 512 + ch * 32 + eg * 16) = ov;
    }
}

// Layer 2 fused with W3: 4-edge-parallel gather of bf16 h2; a2 = relu(agg+b2);
// z = a2 @ W3 (128x2) via per-lane partials + shuffle reduce. (round-2 champion)
__global__ __launch_bounds__(256) void agg128_w3_kernel(const unsigned short* __restrict__ h,
                                                        const int* __restrict__ rp,
                                                        const int* __restrict__ csrc,
                                                        const float* __restrict__ cw,
                                                        const float* __restrict__ dinv,
                                                        const float* __restrict__ b2,
                                                        const float* __restrict__ W3,
                                                        float* __restrict__ z, int n) {
    int node = blockIdx.x * 4 + (threadIdx.x >> 6);
    int lane = threadIdx.x & 63;
    if (node >= n) return;
    const int eg = lane >> 4;                    // edge slot 0..3
    const int ch = lane & 15;                    // 8-channel (16B) chunk
    float di = dinv[node];

    float acc[8];
    {
        u32x4 v = *(const u32x4*)((const char*)h + (size_t)node * 256 + ch * 16);
        float ws = (eg == 0) ? di * di : 0.f;
#pragma unroll
        for (int u = 0; u < 4; ++u) {
            acc[u * 2 + 0] = ws * __uint_as_float(v[u] << 16);
            acc[u * 2 + 1] = ws * __uint_as_float(v[u] & 0xFFFF0000u);
        }
    }

    int e0 = rp[node], e1 = rp[node + 1];
    for (int base = e0; base < e1; base += 64) {
        int idx = base + lane;
        int sb = (idx < e1) ? csrc[idx] : 0;
        float wb = (idx < e1) ? cw[idx] : 0.f;
        int cnt = e1 - base; if (cnt > 64) cnt = 64;
#pragma unroll 2
        for (int i = 0; i < cnt; i += 4) {
            int s = __shfl(sb, i + eg, 64);
            float w = __shfl(wb, i + eg, 64);
            u32x4 v = *(const u32x4*)((const char*)h + (size_t)s * 256 + ch * 16);
#pragma unroll
            for (int u = 0; u < 4; ++u) {
                acc[u * 2 + 0] += w * __uint_as_float(v[u] << 16);
                acc[u * 2 + 1] += w * __uint_as_float(v[u] & 0xFFFF0000u);
            }
        }
    }

#pragma unroll
    for (int k = 0; k < 8; ++k) {
        acc[k] += __shfl_xor(acc[k], 16, 64);
        acc[k] += __shfl_xor(acc[k], 32, 64);
    }

    // a2 = relu(acc + b2); z partials over this lane's 8 channels
    float z0 = 0.f, z1 = 0.f;
#pragma unroll
    for (int k = 0; k < 8; ++k) {
        float a = fmaxf(acc[k] + b2[ch * 8 + k], 0.f);
        z0 += a * W3[(ch * 8 + k) * 2];
        z1 += a * W3[(ch * 8 + k) * 2 + 1];
    }
    // reduce over the 16 ch groups (all eg groups hold identical values)
    for (int off = 8; off > 0; off >>= 1) {
        z0 += __shfl_xor(z0, off, 64);
        z1 += __shfl_xor(z1, off, 64);
    }
    if (lane == 0) {
        z[2 * (size_t)node] = z0;
        z[2 * (size_t)node + 1] = z1;
    }
}

__global__ void agg3_kernel(const float* __restrict__ z, const int* __restrict__ rp,
                            const int* __restrict__ csrc, const float* __restrict__ cw,
                            const float* __restrict__ dinv, const float* __restrict__ bias,
                            float* __restrict__ out, int n) {
    int node = blockIdx.x * blockDim.x + threadIdx.x;
    if (node >= n) return;
    float di = dinv[node];
    float a0 = di * di * z[2 * (size_t)node];
    float a1 = di * di * z[2 * (size_t)node + 1];
    int e1 = rp[node + 1];
    for (int e = rp[node]; e < e1; ++e) {
        int s = csrc[e];
        float w = cw[e];
        a0 += w * z[2 * (size_t)s];
        a1 += w * z[2 * (size_t)s + 1];
    }
    a0 += bias[0];
    a1 += bias[1];
    out[2 * (size_t)node]     = 1.f / (1.f + __expf(-a0));
    out[2 * (size_t)node + 1] = 1.f / (1.f + __expf(-a1));
}

// ---------------- launch ----------------

extern "C" void kernel_launch(void* const* d_in, const int* in_sizes, int n_in,
                              void* d_out, int out_size, void* d_ws, size_t ws_size,
                              hipStream_t stream) {
    const float* x  = (const float*)d_in[0];
    const int*   ei = (const int*)d_in[1];
    const float* W1 = (const float*)d_in[2];
    const float* b1 = (const float*)d_in[3];
    const float* W2 = (const float*)d_in[4];
    const float* b2 = (const float*)d_in[5];
    const float* W3 = (const float*)d_in[6];
    const float* b3 = (const float*)d_in[7];
    float* out = (float*)d_out;

    const int E  = in_sizes[1] / 2;
    const int C1 = in_sizes[3];              // 256
    const int C2 = in_sizes[5];              // 128
    const int K1 = in_sizes[2] / C1;         // 768
    const int N  = in_sizes[0] / K1;         // 50000

    const int* srcv = ei;
    const int* dstv = ei + E;

    char* p = (char*)d_ws;
    auto carve = [&](size_t bytes) {
        char* r = p;
        p += (bytes + 255) & ~(size_t)255;
        return r;
    };
    int*   cnt    = (int*)carve((size_t)N * 4);
    int*   rp     = (int*)carve((size_t)(N + 1) * 4);
    int*   cursor = (int*)carve((size_t)N * 4);
    float* dinv   = (float*)carve((size_t)N * 4);
    int*   bsum   = (int*)carve(1024 * 4);
    int*   csrc   = (int*)carve((size_t)E * 4);
    float* cw     = (float*)carve((size_t)E * 4);
    short* Wt1    = (short*)carve((size_t)K1 * C1 * 2);
    short* Wt2    = (short*)carve((size_t)C1 * C2 * 2);
    unsigned char* h8 = (unsigned char*)carve((size_t)N * C1);       // fp8 h1
    unsigned short* hB = (unsigned short*)carve((size_t)N * C1 * 2); // bf16 a1
    unsigned short* h2 = (unsigned short*)carve((size_t)N * C2 * 2); // bf16 h2
    float* zbuf   = (float*)carve((size_t)N * 2 * 4);

    const int nb = (N + 1023) / 1024;
    const int cb = (E + 255) / 256;
    const int w1b = (K1 * C1) / 256;         // 768
    const int w2b = (C1 * C2) / 256;         // 128

    // CSR + weight prep (fused)
    hipMemsetAsync(cnt, 0, (size_t)N * 4, stream);
    prep_kernel<<<cb + w1b + w2b, 256, 0, stream>>>(dstv, cnt, E, W1, Wt1, W2, Wt2, cb, w1b);
    blockscan_kernel<<<nb, 1024, 0, stream>>>(cnt, rp, bsum, N);
    topscan_kernel<<<1, 64, 0, stream>>>(bsum, nb);
    fixup_kernel<<<nb, 1024, 0, stream>>>(rp, bsum, cnt, cursor, dinv, N, E);
    fill_kernel<<<(E + 255) / 256, 256, 0, stream>>>(srcv, dstv, cursor, dinv, csrc, cw, E);

    // Layer 1: h1 = x @ W1 (fp8 out, 8-wave blocks) ; a1 = relu(Ahat h1 + b1)
    gemm1_kernel<<<(N + 31) / 32, 512, 0, stream>>>(x, Wt1, h8, N);
    agg256_f8_kernel<<<(N + 3) / 4, 256, 0, stream>>>(h8, rp, csrc, cw, dinv, b1, hB, N);

    // Layer 2: h2 = a1 @ W2 (64-row panels) ; fused a2 = relu(agg+b2), z = a2 @ W3
    gemm_panel_kernel<unsigned short, 8, 4, 2, 4><<<(N + 63) / 64, 256, 0, stream>>>(hB, Wt2, h2, N);
    agg128_w3_kernel<<<(N + 3) / 4, 256, 0, stream>>>(h2, rp, csrc, cw, dinv, b2, W3, zbuf, N);

    // Layer 3 aggregation + sigmoid
    agg3_kernel<<<(N + 255) / 256, 256, 0, stream>>>(zbuf, rp, csrc, cw, dinv, b3, out, N);
}

// Round 7
// 451.141 us; speedup vs baseline: 1.0670x; 1.0203x over previous
//
#include <hip/hip_runtime.h>
#include <math.h>

typedef short s16x8 __attribute__((ext_vector_type(8)));
typedef __bf16 b16x8 __attribute__((ext_vector_type(8)));
typedef float f32x4 __attribute__((ext_vector_type(4)));
typedef float f32x2 __attribute__((ext_vector_type(2)));
typedef unsigned int u32x4 __attribute__((ext_vector_type(4)));
typedef unsigned int u32x2 __attribute__((ext_vector_type(2)));
typedef unsigned long u64x2 __attribute__((ext_vector_type(2)));

__device__ inline short f2bf(float f) {
    unsigned u = __float_as_uint(f);
    unsigned r = u + 0x7FFFu + ((u >> 16) & 1u);   // RNE
    return (short)(r >> 16);
}
__device__ inline float bf2f(unsigned short u) {
    return __uint_as_float(((unsigned)u) << 16);
}

// ---------------- fused prep: count + make_wt1(fp8) + make_wt2(bf16) ----------------
// Wt2 chunk layout (bf16): [c = k0/32][b = n0/128][nt 0..7][lane 0..63][j 0..7]
//   value = W[c*32 + (lane>>4)*8 + j][b*128 + nt*16 + (lane&15)]
// Wt1 fp8 layout: [c = k0/32][cw 0..3][lane 0..63][t 0..3][j 0..7] (1 B each)
//   value = fp8(W1[c*32 + (lane>>4)*8 + j][cw*64 + t*16 + (lane&15)])

__device__ inline void make_wt_elem(const float* __restrict__ W, short* __restrict__ Wt,
                                    int K, int N, int idx) {
    int NB = N >> 7;
    int j = idx & 7;
    int l = (idx >> 3) & 63;
    int nt = (idx >> 9) & 7;
    int rest = idx >> 12;
    int b = rest % NB;
    int c = rest / NB;
    int k = c * 32 + (l >> 4) * 8 + j;
    int n = b * 128 + nt * 16 + (l & 15);
    Wt[idx] = f2bf(W[(size_t)k * N + n]);
}

__global__ void prep_kernel(const int* __restrict__ dst, int* __restrict__ cnt, int E,
                            const float* __restrict__ W1, unsigned char* __restrict__ Wt1,
                            const float* __restrict__ W2, short* __restrict__ Wt2,
                            int cb, int w1b) {
    int b = blockIdx.x;
    int tid = threadIdx.x;
    if (b < cb) {
        int e = b * 256 + tid;
        if (e < E) atomicAdd(&cnt[dst[e]], 1);
    } else if (b < cb + w1b) {
        int idx = (b - cb) * 256 + tid;          // 0 .. 196607
        int j = idx & 7;
        int t = (idx >> 3) & 3;
        int l = (idx >> 5) & 63;
        int cw = (idx >> 11) & 3;
        int c = idx >> 13;                       // 0..23
        int k = c * 32 + (l >> 4) * 8 + j;
        int n = cw * 64 + t * 16 + (l & 15);
        float v = W1[(size_t)k * 256 + n];
        unsigned u = __builtin_amdgcn_cvt_pk_fp8_f32(v, v, 0u, false);
        Wt1[idx] = (unsigned char)(u & 0xFF);
    } else {
        int idx = (b - cb - w1b) * 256 + tid;
        make_wt_elem(W2, Wt2, 256, 128, idx);
    }
}

// ---------------- CSR scan chain ----------------

__global__ __launch_bounds__(1024) void blockscan_kernel(const int* __restrict__ cnt,
                                                         int* __restrict__ rp,
                                                         int* __restrict__ bsum, int n) {
    __shared__ int sdata[1024];
    int tid = threadIdx.x;
    int i = blockIdx.x * 1024 + tid;
    int v = (i < n) ? cnt[i] : 0;
    sdata[tid] = v;
    __syncthreads();
    for (int off = 1; off < 1024; off <<= 1) {
        int t = 0;
        if (tid >= off) t = sdata[tid - off];
        __syncthreads();
        sdata[tid] += t;
        __syncthreads();
    }
    if (i < n) rp[i] = sdata[tid] - v;       // local exclusive
    if (tid == 1023) bsum[blockIdx.x] = sdata[1023];
}

__global__ void topscan_kernel(int* bsum, int nb) {
    int lane = threadIdx.x;                   // 64 threads
    int carry = 0;
    for (int base = 0; base < nb; base += 64) {
        int idx = base + lane;
        int orig = (idx < nb) ? bsum[idx] : 0;
        int v = orig;
        for (int off = 1; off < 64; off <<= 1) {
            int t = __shfl_up(v, off, 64);
            if (lane >= off) v += t;
        }
        if (idx < nb) bsum[idx] = carry + v - orig;   // exclusive
        carry += __shfl(v, 63, 64);
    }
}

__global__ __launch_bounds__(1024) void fixup_kernel(int* __restrict__ rp,
                                                     const int* __restrict__ bsum,
                                                     const int* __restrict__ cnt,
                                                     int* __restrict__ cursor,
                                                     float* __restrict__ dinv,
                                                     int n, int E) {
    int i = blockIdx.x * 1024 + threadIdx.x;
    if (i < n) {
        int r = rp[i] + bsum[blockIdx.x];
        rp[i] = r;
        cursor[i] = r;
        dinv[i] = rsqrtf((float)cnt[i] + 1.0f);
    }
    if (i == 0) rp[n] = E;
}

__global__ void fill_kernel(const int* __restrict__ src, const int* __restrict__ dst,
                            int* __restrict__ cursor, const float* __restrict__ dinv,
                            int* __restrict__ csrc, float* __restrict__ cw, int E) {
    int e = blockIdx.x * blockDim.x + threadIdx.x;
    if (e >= E) return;
    int d = dst[e];
    int s = src[e];
    int p = atomicAdd(&cursor[d], 1);
    csrc[p] = s;
    cw[p] = dinv[s] * dinv[d];
}

// ---------------- GEMM1: h1(fp8)[M x 256] = fp8(x) @ Wt1(frag-ready fp8) ----------------
// v6: fp8 x fp8 MFMA. 64 rows x 256 cols per block, 256 threads = 4 waves (wave = 64-col
// group). x staged to LDS as fp8 (48 KB, swizzled frag-ready; same slot formula as the
// proven bf16 layout, 8 B frags). Per K-step per wave: 4 ds_read_b64 (A) + 2 dwordx4 (B)
// feed 16 MFMAs -> MFMA:B-load = 8:1 (was 2:1). Wt1 re-read traffic: 782 blocks x 192 KB
// = 150 MB (was 600 MB). One barrier; barrier-free K-loop.

__global__ __launch_bounds__(256, 3) void gemm1_kernel(const float* __restrict__ x,
                                                       const unsigned char* __restrict__ Wt,
                                                       unsigned char* __restrict__ h8,
                                                       int M) {
    constexpr int KC = 24;                     // 768 / 32
    constexpr int RT = 4;                      // row-tiles -> 64 rows per block

    __shared__ u32x2 As[KC * RT * 64];         // 48 KB fp8, fragment-ready (8 B frags)

    const int tid = threadIdx.x;
    const int m0 = blockIdx.x * 64;

    // stage: load fp32 octets, cvt to fp8, swizzled ds_write_b64 (one frag per octet)
#pragma unroll 4
    for (int i = 0; i < 24; ++i) {
        int idx = i * 256 + tid;               // (row 0..63) x (octet 0..95)
        int r = idx / 96;
        int o = idx - r * 96;
        int row = m0 + r;
        if (row >= M) row = M - 1;
        const float4* fp = (const float4*)(x + (size_t)row * 768 + o * 8);
        float4 f0 = fp[0];
        float4 f1 = fp[1];
        unsigned w0 = __builtin_amdgcn_cvt_pk_fp8_f32(f0.x, f0.y, 0u, false);
        w0 = __builtin_amdgcn_cvt_pk_fp8_f32(f0.z, f0.w, w0, true);
        unsigned w1 = __builtin_amdgcn_cvt_pk_fp8_f32(f1.x, f1.y, 0u, false);
        w1 = __builtin_amdgcn_cvt_pk_fp8_f32(f1.z, f1.w, w1, true);
        int c = o >> 2, q = o & 3;
        int slot = q * 16 + (((r & 15) + q + ((c & 3) << 2)) & 15);
        As[(c * RT + (r >> 4)) * 64 + slot] = (u32x2){w0, w1};
    }
    __syncthreads();

    const int lane = tid & 63;
    const int cw = tid >> 6;                   // 64-col group 0..3
    const int q = lane >> 4;
    const int rl = lane & 15;

    f32x4 acc[RT][4];
#pragma unroll
    for (int i = 0; i < RT; ++i)
#pragma unroll
        for (int j = 0; j < 4; ++j)
            acc[i][j] = (f32x4){0.f, 0.f, 0.f, 0.f};

#pragma unroll 4
    for (int c = 0; c < KC; ++c) {
        int slot = q * 16 + ((rl + q + ((c & 3) << 2)) & 15);
        long a8[RT];
#pragma unroll
        for (int i = 0; i < RT; ++i)
            a8[i] = __builtin_bit_cast(long, As[(c * RT + i) * 64 + slot]);
        const char* bp = (const char*)Wt + ((size_t)(c * 4 + cw) * 64 + lane) * 32;
        u64x2 B0 = *(const u64x2*)bp;
        u64x2 B1 = *(const u64x2*)(bp + 16);
        long b8[4];
        b8[0] = (long)B0.x; b8[1] = (long)B0.y;
        b8[2] = (long)B1.x; b8[3] = (long)B1.y;
#pragma unroll
        for (int i = 0; i < RT; ++i)
#pragma unroll
            for (int j = 0; j < 4; ++j)
                acc[i][j] = __builtin_amdgcn_mfma_f32_16x16x32_fp8_fp8(a8[i], b8[j], acc[i][j], 0, 0, 0);
    }

    const int quad = lane >> 4;
    const int nl = lane & 15;
#pragma unroll
    for (int i = 0; i < RT; ++i) {
        int rbase = m0 + i * 16 + quad * 4;
#pragma unroll
        for (int j = 0; j < 4; ++j) {
            int col = cw * 64 + j * 16 + nl;
#pragma unroll
            for (int r = 0; r < 4; ++r) {
                int row = rbase + r;
                if (row < M) {
                    unsigned u = __builtin_amdgcn_cvt_pk_fp8_f32(acc[i][j][r], acc[i][j][r], 0, false);
                    h8[(size_t)row * 256 + col] = (unsigned char)(u & 0xFF);
                }
            }
        }
    }
}

// ---------------- row-panel GEMM (bf16 A, layer 2) — round-2 champion ----------------

template<typename AT, int KC, int RT, int CW, int MINW>
__global__ __launch_bounds__(256, MINW) void gemm_panel_kernel(
        const AT* __restrict__ A, const short* __restrict__ Wt,
        unsigned short* __restrict__ Cb, int M) {
    constexpr int K = KC * 32;
    constexpr int O = KC * 4;              // 8-elem octets per row
    constexpr int F = KC * RT / 4;         // frags staged per thread
    constexpr int NCOLS = CW * 64;
    constexpr int NB = NCOLS >> 7;         // 128-col B blocks
    constexpr int MT = RT * CW / 4;        // m-tiles per wave

    __shared__ s16x8 As[KC * RT * 64];

    const int tid = threadIdx.x;
    const int m0 = blockIdx.x * (RT * 16);

    s16x8 v[F];
#pragma unroll
    for (int i = 0; i < F; ++i) {
        int idx = i * 256 + tid;
        int r = idx / O;
        int o = idx - r * O;
        int row = m0 + r;
        if (row >= M) row = M - 1;
        v[i] = *(const s16x8*)((const unsigned short*)A + (size_t)row * K + o * 8);
    }
#pragma unroll
    for (int i = 0; i < F; ++i) {
        int idx = i * 256 + tid;
        int r = idx / O;
        int o = idx - r * O;
        int c = o >> 2, q = o & 3;
        int slot = q * 16 + (((r & 15) + q + ((c & 3) << 2)) & 15);
        As[(c * RT + (r >> 4)) * 64 + slot] = v[i];
    }
    __syncthreads();

    const int lane = tid & 63;
    const int wave = tid >> 6;
    const int cw_i = wave % CW;
    const int rg = wave / CW;
    const int mtb = rg * MT;
    const int b128 = (cw_i * 64) >> 7;
    const int nt0 = (cw_i * 4) & 7;
    const int q = lane >> 4;
    const int rl = lane & 15;
    const s16x8* wt = (const s16x8*)Wt;

    f32x4 acc[MT][4];
#pragma unroll
    for (int i = 0; i < MT; ++i)
#pragma unroll
        for (int j = 0; j < 4; ++j)
            acc[i][j] = (f32x4){0.f, 0.f, 0.f, 0.f};

#pragma unroll 4
    for (int c = 0; c < KC; ++c) {
        int slot = q * 16 + ((rl + q + ((c & 3) << 2)) & 15);
        b16x8 areg[MT], breg[4];
#pragma unroll
        for (int i = 0; i < MT; ++i)
            areg[i] = __builtin_bit_cast(b16x8, As[(c * RT + mtb + i) * 64 + slot]);
        size_t bb = (size_t)(c * NB + b128) * 512 + nt0 * 64 + lane;
#pragma unroll
        for (int j = 0; j < 4; ++j)
            breg[j] = __builtin_bit_cast(b16x8, wt[bb + j * 64]);
#pragma unroll
        for (int i = 0; i < MT; ++i)
#pragma unroll
            for (int j = 0; j < 4; ++j)
                acc[i][j] = __builtin_amdgcn_mfma_f32_16x16x32_bf16(areg[i], breg[j], acc[i][j], 0, 0, 0);
    }

    const int quad = lane >> 4;
    const int nl = lane & 15;
#pragma unroll
    for (int i = 0; i < MT; ++i) {
        int rbase = m0 + (mtb + i) * 16 + quad * 4;
#pragma unroll
        for (int j = 0; j < 4; ++j) {
            int col = cw_i * 64 + j * 16 + nl;
#pragma unroll
            for (int rr = 0; rr < 4; ++rr) {
                int row = rbase + rr;
                if (row < M) Cb[(size_t)row * NCOLS + col] = (unsigned short)f2bf(acc[i][j][rr]);
            }
        }
    }
}

// ---------------- aggregation (round-2 champion) ----------------
// 4-edge-parallel gather. Wave per node; lane = (eg = edge slot 0..3, ch = 16B chunk).
// Edge indices/weights batch-loaded 64-at-a-time to regs, distributed by shuffle;
// inner loop's only memory op is one dwordx4 row-gather covering 4 edges.
// Cross-lane xor(16/32) reduction combines the 4 edge slots once per node.

__global__ __launch_bounds__(256) void agg256_f8_kernel(const unsigned char* __restrict__ h8,
                                                        const int* __restrict__ rp,
                                                        const int* __restrict__ csrc,
                                                        const float* __restrict__ cw,
                                                        const float* __restrict__ dinv,
                                                        const float* __restrict__ bias,
                                                        unsigned short* __restrict__ out, int n) {
    int node = blockIdx.x * 4 + (threadIdx.x >> 6);
    int lane = threadIdx.x & 63;
    if (node >= n) return;
    const int eg = lane >> 4;                    // edge slot 0..3
    const int ch = lane & 15;                    // 16-channel chunk
    float di = dinv[node];

    float acc[16];
    {
        u32x4 v = *(const u32x4*)(h8 + (size_t)node * 256 + ch * 16);
        float ws = (eg == 0) ? di * di : 0.f;    // self term counted once
#pragma unroll
        for (int u = 0; u < 4; ++u) {
            f32x2 lo = __builtin_amdgcn_cvt_pk_f32_fp8(v[u], false);
            f32x2 hi = __builtin_amdgcn_cvt_pk_f32_fp8(v[u], true);
            acc[u * 4 + 0] = ws * lo.x; acc[u * 4 + 1] = ws * lo.y;
            acc[u * 4 + 2] = ws * hi.x; acc[u * 4 + 3] = ws * hi.y;
        }
    }

    int e0 = rp[node], e1 = rp[node + 1];
    for (int base = e0; base < e1; base += 64) {
        int idx = base + lane;
        int sb = (idx < e1) ? csrc[idx] : 0;
        float wb = (idx < e1) ? cw[idx] : 0.f;
        int cnt = e1 - base; if (cnt > 64) cnt = 64;
#pragma unroll 2
        for (int i = 0; i < cnt; i += 4) {
            int s = __shfl(sb, i + eg, 64);       // i+eg <= 63 always (i step 4, i<=60)
            float w = __shfl(wb, i + eg, 64);
            u32x4 v = *(const u32x4*)(h8 + (size_t)s * 256 + ch * 16);
#pragma unroll
            for (int u = 0; u < 4; ++u) {
                f32x2 lo = __builtin_amdgcn_cvt_pk_f32_fp8(v[u], false);
                f32x2 hi = __builtin_amdgcn_cvt_pk_f32_fp8(v[u], true);
                acc[u * 4 + 0] += w * lo.x; acc[u * 4 + 1] += w * lo.y;
                acc[u * 4 + 2] += w * hi.x; acc[u * 4 + 3] += w * hi.y;
            }
        }
    }

    // combine the 4 edge slots
#pragma unroll
    for (int k = 0; k < 16; ++k) {
        acc[k] += __shfl_xor(acc[k], 16, 64);
        acc[k] += __shfl_xor(acc[k], 32, 64);
    }

    // bias + relu + pack to bf16; lanes eg 0/1 store the two 16B halves of the 32B chunk
    unsigned pk[8];
#pragma unroll
    for (int k = 0; k < 8; ++k) {
        float b0 = bias[ch * 16 + 2 * k];
        float b1 = bias[ch * 16 + 2 * k + 1];
        float a0 = fmaxf(acc[2 * k] + b0, 0.f);
        float a1 = fmaxf(acc[2 * k + 1] + b1, 0.f);
        pk[k] = ((unsigned)(unsigned short)f2bf(a0)) | (((unsigned)(unsigned short)f2bf(a1)) << 16);
    }
    if (eg < 2) {
        u32x4 ov;
        ov.x = pk[eg * 4 + 0]; ov.y = pk[eg * 4 + 1];
        ov.z = pk[eg * 4 + 2]; ov.w = pk[eg * 4 + 3];
        *(u32x4*)((char*)out + (size_t)node * 512 + ch * 32 + eg * 16) = ov;
    }
}

// Layer 2 fused with W3: 4-edge-parallel gather of bf16 h2; a2 = relu(agg+b2);
// z = a2 @ W3 (128x2) via per-lane partials + shuffle reduce. (round-2 champion)
__global__ __launch_bounds__(256) void agg128_w3_kernel(const unsigned short* __restrict__ h,
                                                        const int* __restrict__ rp,
                                                        const int* __restrict__ csrc,
                                                        const float* __restrict__ cw,
                                                        const float* __restrict__ dinv,
                                                        const float* __restrict__ b2,
                                                        const float* __restrict__ W3,
                                                        float* __restrict__ z, int n) {
    int node = blockIdx.x * 4 + (threadIdx.x >> 6);
    int lane = threadIdx.x & 63;
    if (node >= n) return;
    const int eg = lane >> 4;                    // edge slot 0..3
    const int ch = lane & 15;                    // 8-channel (16B) chunk
    float di = dinv[node];

    float acc[8];
    {
        u32x4 v = *(const u32x4*)((const char*)h + (size_t)node * 256 + ch * 16);
        float ws = (eg == 0) ? di * di : 0.f;
#pragma unroll
        for (int u = 0; u < 4; ++u) {
            acc[u * 2 + 0] = ws * __uint_as_float(v[u] << 16);
            acc[u * 2 + 1] = ws * __uint_as_float(v[u] & 0xFFFF0000u);
        }
    }

    int e0 = rp[node], e1 = rp[node + 1];
    for (int base = e0; base < e1; base += 64) {
        int idx = base + lane;
        int sb = (idx < e1) ? csrc[idx] : 0;
        float wb = (idx < e1) ? cw[idx] : 0.f;
        int cnt = e1 - base; if (cnt > 64) cnt = 64;
#pragma unroll 2
        for (int i = 0; i < cnt; i += 4) {
            int s = __shfl(sb, i + eg, 64);
            float w = __shfl(wb, i + eg, 64);
            u32x4 v = *(const u32x4*)((const char*)h + (size_t)s * 256 + ch * 16);
#pragma unroll
            for (int u = 0; u < 4; ++u) {
                acc[u * 2 + 0] += w * __uint_as_float(v[u] << 16);
                acc[u * 2 + 1] += w * __uint_as_float(v[u] & 0xFFFF0000u);
            }
        }
    }

#pragma unroll
    for (int k = 0; k < 8; ++k) {
        acc[k] += __shfl_xor(acc[k], 16, 64);
        acc[k] += __shfl_xor(acc[k], 32, 64);
    }

    // a2 = relu(acc + b2); z partials over this lane's 8 channels
    float z0 = 0.f, z1 = 0.f;
#pragma unroll
    for (int k = 0; k < 8; ++k) {
        float a = fmaxf(acc[k] + b2[ch * 8 + k], 0.f);
        z0 += a * W3[(ch * 8 + k) * 2];
        z1 += a * W3[(ch * 8 + k) * 2 + 1];
    }
    // reduce over the 16 ch groups (all eg groups hold identical values)
    for (int off = 8; off > 0; off >>= 1) {
        z0 += __shfl_xor(z0, off, 64);
        z1 += __shfl_xor(z1, off, 64);
    }
    if (lane == 0) {
        z[2 * (size_t)node] = z0;
        z[2 * (size_t)node + 1] = z1;
    }
}

__global__ void agg3_kernel(const float* __restrict__ z, const int* __restrict__ rp,
                            const int* __restrict__ csrc, const float* __restrict__ cw,
                            const float* __restrict__ dinv, const float* __restrict__ bias,
                            float* __restrict__ out, int n) {
    int node = blockIdx.x * blockDim.x + threadIdx.x;
    if (node >= n) return;
    float di = dinv[node];
    float a0 = di * di * z[2 * (size_t)node];
    float a1 = di * di * z[2 * (size_t)node + 1];
    int e1 = rp[node + 1];
    for (int e = rp[node]; e < e1; ++e) {
        int s = csrc[e];
        float w = cw[e];
        a0 += w * z[2 * (size_t)s];
        a1 += w * z[2 * (size_t)s + 1];
    }
    a0 += bias[0];
    a1 += bias[1];
    out[2 * (size_t)node]     = 1.f / (1.f + __expf(-a0));
    out[2 * (size_t)node + 1] = 1.f / (1.f + __expf(-a1));
}

// ---------------- launch ----------------

extern "C" void kernel_launch(void* const* d_in, const int* in_sizes, int n_in,
                              void* d_out, int out_size, void* d_ws, size_t ws_size,
                              hipStream_t stream) {
    const float* x  = (const float*)d_in[0];
    const int*   ei = (const int*)d_in[1];
    const float* W1 = (const float*)d_in[2];
    const float* b1 = (const float*)d_in[3];
    const float* W2 = (const float*)d_in[4];
    const float* b2 = (const float*)d_in[5];
    const float* W3 = (const float*)d_in[6];
    const float* b3 = (const float*)d_in[7];
    float* out = (float*)d_out;

    const int E  = in_sizes[1] / 2;
    const int C1 = in_sizes[3];              // 256
    const int C2 = in_sizes[5];              // 128
    const int K1 = in_sizes[2] / C1;         // 768
    const int N  = in_sizes[0] / K1;         // 50000

    const int* srcv = ei;
    const int* dstv = ei + E;

    char* p = (char*)d_ws;
    auto carve = [&](size_t bytes) {
        char* r = p;
        p += (bytes + 255) & ~(size_t)255;
        return r;
    };
    int*   cnt    = (int*)carve((size_t)N * 4);
    int*   rp     = (int*)carve((size_t)(N + 1) * 4);
    int*   cursor = (int*)carve((size_t)N * 4);
    float* dinv   = (float*)carve((size_t)N * 4);
    int*   bsum   = (int*)carve(1024 * 4);
    int*   csrc   = (int*)carve((size_t)E * 4);
    float* cw     = (float*)carve((size_t)E * 4);
    unsigned char* Wt1 = (unsigned char*)carve((size_t)K1 * C1);     // fp8 frag-ready
    short* Wt2    = (short*)carve((size_t)C1 * C2 * 2);
    unsigned char* h8 = (unsigned char*)carve((size_t)N * C1);       // fp8 h1
    unsigned short* hB = (unsigned short*)carve((size_t)N * C1 * 2); // bf16 a1
    unsigned short* h2 = (unsigned short*)carve((size_t)N * C2 * 2); // bf16 h2
    float* zbuf   = (float*)carve((size_t)N * 2 * 4);

    const int nb = (N + 1023) / 1024;
    const int cb = (E + 255) / 256;
    const int w1b = (K1 * C1) / 256;         // 768 (fp8: 1 B per elem)
    const int w2b = (C1 * C2) / 256;         // 128

    // CSR + weight prep (fused)
    hipMemsetAsync(cnt, 0, (size_t)N * 4, stream);
    prep_kernel<<<cb + w1b + w2b, 256, 0, stream>>>(dstv, cnt, E, W1, Wt1, W2, Wt2, cb, w1b);
    blockscan_kernel<<<nb, 1024, 0, stream>>>(cnt, rp, bsum, N);
    topscan_kernel<<<1, 64, 0, stream>>>(bsum, nb);
    fixup_kernel<<<nb, 1024, 0, stream>>>(rp, bsum, cnt, cursor, dinv, N, E);
    fill_kernel<<<(E + 255) / 256, 256, 0, stream>>>(srcv, dstv, cursor, dinv, csrc, cw, E);

    // Layer 1: h1 = fp8(x) @ fp8(W1) (fp8 out, 64-row blocks) ; a1 = relu(Ahat h1 + b1)
    gemm1_kernel<<<(N + 63) / 64, 256, 0, stream>>>(x, Wt1, h8, N);
    agg256_f8_kernel<<<(N + 3) / 4, 256, 0, stream>>>(h8, rp, csrc, cw, dinv, b1, hB, N);

    // Layer 2: h2 = a1 @ W2 (64-row panels) ; fused a2 = relu(agg+b2), z = a2 @ W3
    gemm_panel_kernel<unsigned short, 8, 4, 2, 4><<<(N + 63) / 64, 256, 0, stream>>>(hB, Wt2, h2, N);
    agg128_w3_kernel<<<(N + 3) / 4, 256, 0, stream>>>(h2, rp, csrc, cw, dinv, b2, W3, zbuf, N);

    // Layer 3 aggregation + sigmoid
    agg3_kernel<<<(N + 255) / 256, 256, 0, stream>>>(zbuf, rp, csrc, cw, dinv, b3, out, N);
}

// Round 8
// 445.692 us; speedup vs baseline: 1.0801x; 1.0122x over previous
//
#include <hip/hip_runtime.h>
#include <math.h>

typedef short s16x8 __attribute__((ext_vector_type(8)));
typedef __bf16 b16x8 __attribute__((ext_vector_type(8)));
typedef float f32x4 __attribute__((ext_vector_type(4)));
typedef float f32x2 __attribute__((ext_vector_type(2)));
typedef unsigned int u32x4 __attribute__((ext_vector_type(4)));

__device__ inline short f2bf(float f) {
    unsigned u = __float_as_uint(f);
    unsigned r = u + 0x7FFFu + ((u >> 16) & 1u);   // RNE
    return (short)(r >> 16);
}
__device__ inline float bf2f(unsigned short u) {
    return __uint_as_float(((unsigned)u) << 16);
}

// ---------------- fused prep: count + make_wt1 + make_wt2 ----------------
// Wt chunk layout: [c = k0/32][b = n0/128][nt 0..7][lane 0..63][j 0..7]
//   value = W[c*32 + (lane>>4)*8 + j][b*128 + nt*16 + (lane&15)]

__device__ inline void make_wt_elem(const float* __restrict__ W, short* __restrict__ Wt,
                                    int K, int N, int idx) {
    int NB = N >> 7;
    int j = idx & 7;
    int l = (idx >> 3) & 63;
    int nt = (idx >> 9) & 7;
    int rest = idx >> 12;
    int b = rest % NB;
    int c = rest / NB;
    int k = c * 32 + (l >> 4) * 8 + j;
    int n = b * 128 + nt * 16 + (l & 15);
    Wt[idx] = f2bf(W[(size_t)k * N + n]);
}

__global__ void prep_kernel(const int* __restrict__ dst, int* __restrict__ cnt, int E,
                            const float* __restrict__ W1, short* __restrict__ Wt1,
                            const float* __restrict__ W2, short* __restrict__ Wt2,
                            int cb, int w1b) {
    int b = blockIdx.x;
    int tid = threadIdx.x;
    if (b < cb) {
        int e = b * 256 + tid;
        if (e < E) atomicAdd(&cnt[dst[e]], 1);
    } else if (b < cb + w1b) {
        int idx = (b - cb) * 256 + tid;
        make_wt_elem(W1, Wt1, 768, 256, idx);
    } else {
        int idx = (b - cb - w1b) * 256 + tid;
        make_wt_elem(W2, Wt2, 256, 128, idx);
    }
}

// ---------------- CSR scan chain ----------------

__global__ __launch_bounds__(1024) void blockscan_kernel(const int* __restrict__ cnt,
                                                         int* __restrict__ rp,
                                                         int* __restrict__ bsum, int n) {
    __shared__ int sdata[1024];
    int tid = threadIdx.x;
    int i = blockIdx.x * 1024 + tid;
    int v = (i < n) ? cnt[i] : 0;
    sdata[tid] = v;
    __syncthreads();
    for (int off = 1; off < 1024; off <<= 1) {
        int t = 0;
        if (tid >= off) t = sdata[tid - off];
        __syncthreads();
        sdata[tid] += t;
        __syncthreads();
    }
    if (i < n) rp[i] = sdata[tid] - v;       // local exclusive
    if (tid == 1023) bsum[blockIdx.x] = sdata[1023];
}

// fixup v2: inlines the bsum prefix (topscan) — one wave scans bsum[0..blockIdx.x-1]
// (<= 48 ints), broadcast via LDS. Eliminates the single-block topscan launch.
__global__ __launch_bounds__(1024) void fixup_kernel(int* __restrict__ rp,
                                                     const int* __restrict__ bsum,
                                                     const int* __restrict__ cnt,
                                                     int* __restrict__ cursor,
                                                     float* __restrict__ dinv,
                                                     int n, int E) {
    __shared__ int carry_s;
    int tid = threadIdx.x;
    if (tid < 64) {
        int sum = 0;
        for (int i = tid; i < blockIdx.x; i += 64) sum += bsum[i];
        for (int off = 32; off > 0; off >>= 1) sum += __shfl_xor(sum, off, 64);
        if (tid == 0) carry_s = sum;
    }
    __syncthreads();
    int carry = carry_s;
    int i = blockIdx.x * 1024 + tid;
    if (i < n) {
        int r = rp[i] + carry;
        rp[i] = r;
        cursor[i] = r;
        dinv[i] = rsqrtf((float)cnt[i] + 1.0f);
    }
    if (i == 0) rp[n] = E;
}

__global__ void fill_kernel(const int* __restrict__ src, const int* __restrict__ dst,
                            int* __restrict__ cursor, const float* __restrict__ dinv,
                            int* __restrict__ csrc, float* __restrict__ cw, int E) {
    int e = blockIdx.x * blockDim.x + threadIdx.x;
    if (e >= E) return;
    int d = dst[e];
    int s = src[e];
    int p = atomicAdd(&cursor[d], 1);
    csrc[p] = s;
    cw[p] = dinv[s] * dinv[d];
}

// ---------------- GEMM1: h1(fp8)[M x 256] = x(fp32) @ Wt1(frag-ready bf16) ----------------
// round-2 champion: 32 rows x 256 cols per block, 256 threads = 4 waves.
// Reg-stage fp32 -> truncate to bf16 -> swizzled fragment-ready LDS (48 KB,
// conflict-free layout shared with gemm_panel_kernel). One barrier; barrier-free K-loop.

__global__ __launch_bounds__(256, 3) void gemm1_kernel(const float* __restrict__ x,
                                                       const short* __restrict__ Wt,
                                                       unsigned char* __restrict__ h8,
                                                       int M) {
    constexpr int KC = 24;                     // 768 / 32
    constexpr int RT = 2;                      // row-tiles -> 32 rows per block
    constexpr int O = KC * 4;                  // 96 octets (8 k-elems) per row
    constexpr int F = KC * RT * 64 / 256;      // 12 frags staged per thread

    __shared__ s16x8 As[KC * RT * 64];         // 48 KB bf16, fragment-ready

    const int tid = threadIdx.x;
    const int m0 = blockIdx.x * (RT * 16);

    // stage: load fp32 pairs, truncation-pack to bf16
    s16x8 v[F];
#pragma unroll
    for (int i = 0; i < F; ++i) {
        int idx = i * 256 + tid;
        int r = idx / O;
        int o = idx - r * O;
        int row = m0 + r;
        if (row >= M) row = M - 1;
        const float4* fp = (const float4*)(x + (size_t)row * 768 + o * 8);
        float4 f0 = fp[0];
        float4 f1 = fp[1];
        u32x4 pk;
        pk.x = (__float_as_uint(f0.x) >> 16) | (__float_as_uint(f0.y) & 0xFFFF0000u);
        pk.y = (__float_as_uint(f0.z) >> 16) | (__float_as_uint(f0.w) & 0xFFFF0000u);
        pk.z = (__float_as_uint(f1.x) >> 16) | (__float_as_uint(f1.y) & 0xFFFF0000u);
        pk.w = (__float_as_uint(f1.z) >> 16) | (__float_as_uint(f1.w) & 0xFFFF0000u);
        v[i] = __builtin_bit_cast(s16x8, pk);
    }
#pragma unroll
    for (int i = 0; i < F; ++i) {
        int idx = i * 256 + tid;
        int r = idx / O;
        int o = idx - r * O;
        int c = o >> 2, q = o & 3;
        int slot = q * 16 + (((r & 15) + q + ((c & 3) << 2)) & 15);
        As[(c * RT + (r >> 4)) * 64 + slot] = v[i];
    }
    __syncthreads();

    const int lane = tid & 63;
    const int wave = tid >> 6;
    const int b128 = wave >> 1;                // 128-col B block
    const int nt0 = (wave & 1) * 4;            // first 16-col tile inside it
    const int q = lane >> 4;
    const int rl = lane & 15;
    const s16x8* wt = (const s16x8*)Wt;

    f32x4 acc[RT][4];
#pragma unroll
    for (int i = 0; i < RT; ++i)
#pragma unroll
        for (int j = 0; j < 4; ++j)
            acc[i][j] = (f32x4){0.f, 0.f, 0.f, 0.f};

#pragma unroll 4
    for (int c = 0; c < KC; ++c) {
        int slot = q * 16 + ((rl + q + ((c & 3) << 2)) & 15);
        b16x8 areg[RT], breg[4];
#pragma unroll
        for (int i = 0; i < RT; ++i)
            areg[i] = __builtin_bit_cast(b16x8, As[(c * RT + i) * 64 + slot]);
        size_t bb = (size_t)(c * 2 + b128) * 512 + nt0 * 64 + lane;
#pragma unroll
        for (int j = 0; j < 4; ++j)
            breg[j] = __builtin_bit_cast(b16x8, wt[bb + j * 64]);
#pragma unroll
        for (int i = 0; i < RT; ++i)
#pragma unroll
            for (int j = 0; j < 4; ++j)
                acc[i][j] = __builtin_amdgcn_mfma_f32_16x16x32_bf16(areg[i], breg[j], acc[i][j], 0, 0, 0);
    }

    const int quad = lane >> 4;
    const int nl = lane & 15;
#pragma unroll
    for (int i = 0; i < RT; ++i) {
        int rbase = m0 + i * 16 + quad * 4;
#pragma unroll
        for (int j = 0; j < 4; ++j) {
            int col = wave * 64 + j * 16 + nl;
#pragma unroll
            for (int r = 0; r < 4; ++r) {
                int row = rbase + r;
                if (row < M) {
                    unsigned u = __builtin_amdgcn_cvt_pk_fp8_f32(acc[i][j][r], acc[i][j][r], 0, false);
                    h8[(size_t)row * 256 + col] = (unsigned char)(u & 0xFF);
                }
            }
        }
    }
}

// ---------------- row-panel GEMM (bf16 A, layer 2) — round-2 champion ----------------

template<typename AT, int KC, int RT, int CW, int MINW>
__global__ __launch_bounds__(256, MINW) void gemm_panel_kernel(
        const AT* __restrict__ A, const short* __restrict__ Wt,
        unsigned short* __restrict__ Cb, int M) {
    constexpr int K = KC * 32;
    constexpr int O = KC * 4;              // 8-elem octets per row
    constexpr int F = KC * RT / 4;         // frags staged per thread
    constexpr int NCOLS = CW * 64;
    constexpr int NB = NCOLS >> 7;         // 128-col B blocks
    constexpr int MT = RT * CW / 4;        // m-tiles per wave

    __shared__ s16x8 As[KC * RT * 64];

    const int tid = threadIdx.x;
    const int m0 = blockIdx.x * (RT * 16);

    s16x8 v[F];
#pragma unroll
    for (int i = 0; i < F; ++i) {
        int idx = i * 256 + tid;
        int r = idx / O;
        int o = idx - r * O;
        int row = m0 + r;
        if (row >= M) row = M - 1;
        v[i] = *(const s16x8*)((const unsigned short*)A + (size_t)row * K + o * 8);
    }
#pragma unroll
    for (int i = 0; i < F; ++i) {
        int idx = i * 256 + tid;
        int r = idx / O;
        int o = idx - r * O;
        int c = o >> 2, q = o & 3;
        int slot = q * 16 + (((r & 15) + q + ((c & 3) << 2)) & 15);
        As[(c * RT + (r >> 4)) * 64 + slot] = v[i];
    }
    __syncthreads();

    const int lane = tid & 63;
    const int wave = tid >> 6;
    const int cw_i = wave % CW;
    const int rg = wave / CW;
    const int mtb = rg * MT;
    const int b128 = (cw_i * 64) >> 7;
    const int nt0 = (cw_i * 4) & 7;
    const int q = lane >> 4;
    const int rl = lane & 15;
    const s16x8* wt = (const s16x8*)Wt;

    f32x4 acc[MT][4];
#pragma unroll
    for (int i = 0; i < MT; ++i)
#pragma unroll
        for (int j = 0; j < 4; ++j)
            acc[i][j] = (f32x4){0.f, 0.f, 0.f, 0.f};

#pragma unroll 4
    for (int c = 0; c < KC; ++c) {
        int slot = q * 16 + ((rl + q + ((c & 3) << 2)) & 15);
        b16x8 areg[MT], breg[4];
#pragma unroll
        for (int i = 0; i < MT; ++i)
            areg[i] = __builtin_bit_cast(b16x8, As[(c * RT + mtb + i) * 64 + slot]);
        size_t bb = (size_t)(c * NB + b128) * 512 + nt0 * 64 + lane;
#pragma unroll
        for (int j = 0; j < 4; ++j)
            breg[j] = __builtin_bit_cast(b16x8, wt[bb + j * 64]);
#pragma unroll
        for (int i = 0; i < MT; ++i)
#pragma unroll
            for (int j = 0; j < 4; ++j)
                acc[i][j] = __builtin_amdgcn_mfma_f32_16x16x32_bf16(areg[i], breg[j], acc[i][j], 0, 0, 0);
    }

    const int quad = lane >> 4;
    const int nl = lane & 15;
#pragma unroll
    for (int i = 0; i < MT; ++i) {
        int rbase = m0 + (mtb + i) * 16 + quad * 4;
#pragma unroll
        for (int j = 0; j < 4; ++j) {
            int col = cw_i * 64 + j * 16 + nl;
#pragma unroll
            for (int rr = 0; rr < 4; ++rr) {
                int row = rbase + rr;
                if (row < M) Cb[(size_t)row * NCOLS + col] = (unsigned short)f2bf(acc[i][j][rr]);
            }
        }
    }
}

// ---------------- aggregation (round-2 champion) ----------------
// 4-edge-parallel gather. Wave per node; lane = (eg = edge slot 0..3, ch = 16B chunk).
// Edge indices/weights batch-loaded 64-at-a-time to regs, distributed by shuffle;
// inner loop's only memory op is one dwordx4 row-gather covering 4 edges.
// Cross-lane xor(16/32) reduction combines the 4 edge slots once per node.

__global__ __launch_bounds__(256) void agg256_f8_kernel(const unsigned char* __restrict__ h8,
                                                        const int* __restrict__ rp,
                                                        const int* __restrict__ csrc,
                                                        const float* __restrict__ cw,
                                                        const float* __restrict__ dinv,
                                                        const float* __restrict__ bias,
                                                        unsigned short* __restrict__ out, int n) {
    int node = blockIdx.x * 4 + (threadIdx.x >> 6);
    int lane = threadIdx.x & 63;
    if (node >= n) return;
    const int eg = lane >> 4;                    // edge slot 0..3
    const int ch = lane & 15;                    // 16-channel chunk
    float di = dinv[node];

    float acc[16];
    {
        u32x4 v = *(const u32x4*)(h8 + (size_t)node * 256 + ch * 16);
        float ws = (eg == 0) ? di * di : 0.f;    // self term counted once
#pragma unroll
        for (int u = 0; u < 4; ++u) {
            f32x2 lo = __builtin_amdgcn_cvt_pk_f32_fp8(v[u], false);
            f32x2 hi = __builtin_amdgcn_cvt_pk_f32_fp8(v[u], true);
            acc[u * 4 + 0] = ws * lo.x; acc[u * 4 + 1] = ws * lo.y;
            acc[u * 4 + 2] = ws * hi.x; acc[u * 4 + 3] = ws * hi.y;
        }
    }

    int e0 = rp[node], e1 = rp[node + 1];
    for (int base = e0; base < e1; base += 64) {
        int idx = base + lane;
        int sb = (idx < e1) ? csrc[idx] : 0;
        float wb = (idx < e1) ? cw[idx] : 0.f;
        int cnt = e1 - base; if (cnt > 64) cnt = 64;
#pragma unroll 2
        for (int i = 0; i < cnt; i += 4) {
            int s = __shfl(sb, i + eg, 64);       // i+eg <= 63 always (i step 4, i<=60)
            float w = __shfl(wb, i + eg, 64);
            u32x4 v = *(const u32x4*)(h8 + (size_t)s * 256 + ch * 16);
#pragma unroll
            for (int u = 0; u < 4; ++u) {
                f32x2 lo = __builtin_amdgcn_cvt_pk_f32_fp8(v[u], false);
                f32x2 hi = __builtin_amdgcn_cvt_pk_f32_fp8(v[u], true);
                acc[u * 4 + 0] += w * lo.x; acc[u * 4 + 1] += w * lo.y;
                acc[u * 4 + 2] += w * hi.x; acc[u * 4 + 3] += w * hi.y;
            }
        }
    }

    // combine the 4 edge slots
#pragma unroll
    for (int k = 0; k < 16; ++k) {
        acc[k] += __shfl_xor(acc[k], 16, 64);
        acc[k] += __shfl_xor(acc[k], 32, 64);
    }

    // bias + relu + pack to bf16; lanes eg 0/1 store the two 16B halves of the 32B chunk
    unsigned pk[8];
#pragma unroll
    for (int k = 0; k < 8; ++k) {
        float b0 = bias[ch * 16 + 2 * k];
        float b1 = bias[ch * 16 + 2 * k + 1];
        float a0 = fmaxf(acc[2 * k] + b0, 0.f);
        float a1 = fmaxf(acc[2 * k + 1] + b1, 0.f);
        pk[k] = ((unsigned)(unsigned short)f2bf(a0)) | (((unsigned)(unsigned short)f2bf(a1)) << 16);
    }
    if (eg < 2) {
        u32x4 ov;
        ov.x = pk[eg * 4 + 0]; ov.y = pk[eg * 4 + 1];
        ov.z = pk[eg * 4 + 2]; ov.w = pk[eg * 4 + 3];
        *(u32x4*)((char*)out + (size_t)node * 512 + ch * 32 + eg * 16) = ov;
    }
}

// Layer 2 fused with W3: 4-edge-parallel gather of bf16 h2; a2 = relu(agg+b2);
// z = a2 @ W3 (128x2) via per-lane partials + shuffle reduce. (round-2 champion)
__global__ __launch_bounds__(256) void agg128_w3_kernel(const unsigned short* __restrict__ h,
                                                        const int* __restrict__ rp,
                                                        const int* __restrict__ csrc,
                                                        const float* __restrict__ cw,
                                                        const float* __restrict__ dinv,
                                                        const float* __restrict__ b2,
                                                        const float* __restrict__ W3,
                                                        float* __restrict__ z, int n) {
    int node = blockIdx.x * 4 + (threadIdx.x >> 6);
    int lane = threadIdx.x & 63;
    if (node >= n) return;
    const int eg = lane >> 4;                    // edge slot 0..3
    const int ch = lane & 15;                    // 8-channel (16B) chunk
    float di = dinv[node];

    float acc[8];
    {
        u32x4 v = *(const u32x4*)((const char*)h + (size_t)node * 256 + ch * 16);
        float ws = (eg == 0) ? di * di : 0.f;
#pragma unroll
        for (int u = 0; u < 4; ++u) {
            acc[u * 2 + 0] = ws * __uint_as_float(v[u] << 16);
            acc[u * 2 + 1] = ws * __uint_as_float(v[u] & 0xFFFF0000u);
        }
    }

    int e0 = rp[node], e1 = rp[node + 1];
    for (int base = e0; base < e1; base += 64) {
        int idx = base + lane;
        int sb = (idx < e1) ? csrc[idx] : 0;
        float wb = (idx < e1) ? cw[idx] : 0.f;
        int cnt = e1 - base; if (cnt > 64) cnt = 64;
#pragma unroll 2
        for (int i = 0; i < cnt; i += 4) {
            int s = __shfl(sb, i + eg, 64);
            float w = __shfl(wb, i + eg, 64);
            u32x4 v = *(const u32x4*)((const char*)h + (size_t)s * 256 + ch * 16);
#pragma unroll
            for (int u = 0; u < 4; ++u) {
                acc[u * 2 + 0] += w * __uint_as_float(v[u] << 16);
                acc[u * 2 + 1] += w * __uint_as_float(v[u] & 0xFFFF0000u);
            }
        }
    }

#pragma unroll
    for (int k = 0; k < 8; ++k) {
        acc[k] += __shfl_xor(acc[k], 16, 64);
        acc[k] += __shfl_xor(acc[k], 32, 64);
    }

    // a2 = relu(acc + b2); z partials over this lane's 8 channels
    float z0 = 0.f, z1 = 0.f;
#pragma unroll
    for (int k = 0; k < 8; ++k) {
        float a = fmaxf(acc[k] + b2[ch * 8 + k], 0.f);
        z0 += a * W3[(ch * 8 + k) * 2];
        z1 += a * W3[(ch * 8 + k) * 2 + 1];
    }
    // reduce over the 16 ch groups (all eg groups hold identical values)
    for (int off = 8; off > 0; off >>= 1) {
        z0 += __shfl_xor(z0, off, 64);
        z1 += __shfl_xor(z1, off, 64);
    }
    if (lane == 0) {
        z[2 * (size_t)node] = z0;
        z[2 * (size_t)node + 1] = z1;
    }
}

// agg3 v2: wave per node (was 1 thread per node, serial ~17-iter loop).
// 64-lane edge-parallel gather of z pairs + xor-tree reduce; one batch covers
// nearly all nodes (deg << 64). csrc/cw reads coalesced across lanes.
__global__ __launch_bounds__(256) void agg3_kernel(const float* __restrict__ z,
                                                   const int* __restrict__ rp,
                                                   const int* __restrict__ csrc,
                                                   const float* __restrict__ cw,
                                                   const float* __restrict__ dinv,
                                                   const float* __restrict__ bias,
                                                   float* __restrict__ out, int n) {
    int node = blockIdx.x * 4 + (threadIdx.x >> 6);
    int lane = threadIdx.x & 63;
    if (node >= n) return;
    float a0 = 0.f, a1 = 0.f;
    int e0 = rp[node], e1 = rp[node + 1];
    for (int idx = e0 + lane; idx < e1; idx += 64) {
        int s = csrc[idx];
        float w = cw[idx];
        float2 zz = *(const float2*)(z + 2 * (size_t)s);
        a0 += w * zz.x;
        a1 += w * zz.y;
    }
    for (int off = 32; off > 0; off >>= 1) {
        a0 += __shfl_xor(a0, off, 64);
        a1 += __shfl_xor(a1, off, 64);
    }
    if (lane == 0) {
        float di = dinv[node];
        float2 zn = *(const float2*)(z + 2 * (size_t)node);
        a0 += di * di * zn.x + bias[0];
        a1 += di * di * zn.y + bias[1];
        out[2 * (size_t)node]     = 1.f / (1.f + __expf(-a0));
        out[2 * (size_t)node + 1] = 1.f / (1.f + __expf(-a1));
    }
}

// ---------------- launch ----------------

extern "C" void kernel_launch(void* const* d_in, const int* in_sizes, int n_in,
                              void* d_out, int out_size, void* d_ws, size_t ws_size,
                              hipStream_t stream) {
    const float* x  = (const float*)d_in[0];
    const int*   ei = (const int*)d_in[1];
    const float* W1 = (const float*)d_in[2];
    const float* b1 = (const float*)d_in[3];
    const float* W2 = (const float*)d_in[4];
    const float* b2 = (const float*)d_in[5];
    const float* W3 = (const float*)d_in[6];
    const float* b3 = (const float*)d_in[7];
    float* out = (float*)d_out;

    const int E  = in_sizes[1] / 2;
    const int C1 = in_sizes[3];              // 256
    const int C2 = in_sizes[5];              // 128
    const int K1 = in_sizes[2] / C1;         // 768
    const int N  = in_sizes[0] / K1;         // 50000

    const int* srcv = ei;
    const int* dstv = ei + E;

    char* p = (char*)d_ws;
    auto carve = [&](size_t bytes) {
        char* r = p;
        p += (bytes + 255) & ~(size_t)255;
        return r;
    };
    int*   cnt    = (int*)carve((size_t)N * 4);
    int*   rp     = (int*)carve((size_t)(N + 1) * 4);
    int*   cursor = (int*)carve((size_t)N * 4);
    float* dinv   = (float*)carve((size_t)N * 4);
    int*   bsum   = (int*)carve(1024 * 4);
    int*   csrc   = (int*)carve((size_t)E * 4);
    float* cw     = (float*)carve((size_t)E * 4);
    short* Wt1    = (short*)carve((size_t)K1 * C1 * 2);
    short* Wt2    = (short*)carve((size_t)C1 * C2 * 2);
    unsigned char* h8 = (unsigned char*)carve((size_t)N * C1);       // fp8 h1
    unsigned short* hB = (unsigned short*)carve((size_t)N * C1 * 2); // bf16 a1
    unsigned short* h2 = (unsigned short*)carve((size_t)N * C2 * 2); // bf16 h2
    float* zbuf   = (float*)carve((size_t)N * 2 * 4);

    const int nb = (N + 1023) / 1024;
    const int cb = (E + 255) / 256;
    const int w1b = (K1 * C1) / 256;         // 768
    const int w2b = (C1 * C2) / 256;         // 128

    // CSR + weight prep (fused)
    hipMemsetAsync(cnt, 0, (size_t)N * 4, stream);
    prep_kernel<<<cb + w1b + w2b, 256, 0, stream>>>(dstv, cnt, E, W1, Wt1, W2, Wt2, cb, w1b);
    blockscan_kernel<<<nb, 1024, 0, stream>>>(cnt, rp, bsum, N);
    fixup_kernel<<<nb, 1024, 0, stream>>>(rp, bsum, cnt, cursor, dinv, N, E);
    fill_kernel<<<(E + 255) / 256, 256, 0, stream>>>(srcv, dstv, cursor, dinv, csrc, cw, E);

    // Layer 1: h1 = x @ W1 (fp8 out) ; a1 = relu(Ahat h1 + b1)
    gemm1_kernel<<<(N + 31) / 32, 256, 0, stream>>>(x, Wt1, h8, N);
    agg256_f8_kernel<<<(N + 3) / 4, 256, 0, stream>>>(h8, rp, csrc, cw, dinv, b1, hB, N);

    // Layer 2: h2 = a1 @ W2 (64-row panels) ; fused a2 = relu(agg+b2), z = a2 @ W3
    gemm_panel_kernel<unsigned short, 8, 4, 2, 4><<<(N + 63) / 64, 256, 0, stream>>>(hB, Wt2, h2, N);
    agg128_w3_kernel<<<(N + 3) / 4, 256, 0, stream>>>(h2, rp, csrc, cw, dinv, b2, W3, zbuf, N);

    // Layer 3 aggregation + sigmoid (wave-parallel)
    agg3_kernel<<<(N + 3) / 4, 256, 0, stream>>>(zbuf, rp, csrc, cw, dinv, b3, out, N);
}

// Round 9
// 444.393 us; speedup vs baseline: 1.0832x; 1.0029x over previous
//
#include <hip/hip_runtime.h>
#include <math.h>

typedef short s16x8 __attribute__((ext_vector_type(8)));
typedef __bf16 b16x8 __attribute__((ext_vector_type(8)));
typedef float f32x4 __attribute__((ext_vector_type(4)));
typedef float f32x2 __attribute__((ext_vector_type(2)));
typedef unsigned int u32x4 __attribute__((ext_vector_type(4)));

__device__ inline short f2bf(float f) {
    unsigned u = __float_as_uint(f);
    unsigned r = u + 0x7FFFu + ((u >> 16) & 1u);   // RNE
    return (short)(r >> 16);
}
__device__ inline float bf2f(unsigned short u) {
    return __uint_as_float(((unsigned)u) << 16);
}

// ---------------- fused prep: count + make_wt1 + make_wt2 ----------------
// Wt chunk layout: [c = k0/32][b = n0/128][nt 0..7][lane 0..63][j 0..7]
//   value = W[c*32 + (lane>>4)*8 + j][b*128 + nt*16 + (lane&15)]

__device__ inline void make_wt_elem(const float* __restrict__ W, short* __restrict__ Wt,
                                    int K, int N, int idx) {
    int NB = N >> 7;
    int j = idx & 7;
    int l = (idx >> 3) & 63;
    int nt = (idx >> 9) & 7;
    int rest = idx >> 12;
    int b = rest % NB;
    int c = rest / NB;
    int k = c * 32 + (l >> 4) * 8 + j;
    int n = b * 128 + nt * 16 + (l & 15);
    Wt[idx] = f2bf(W[(size_t)k * N + n]);
}

__global__ void prep_kernel(const int* __restrict__ dst, int* __restrict__ cnt, int E,
                            const float* __restrict__ W1, short* __restrict__ Wt1,
                            const float* __restrict__ W2, short* __restrict__ Wt2,
                            int cb, int w1b) {
    int b = blockIdx.x;
    int tid = threadIdx.x;
    if (b < cb) {
        int e = b * 256 + tid;
        if (e < E) atomicAdd(&cnt[dst[e]], 1);
    } else if (b < cb + w1b) {
        int idx = (b - cb) * 256 + tid;
        make_wt_elem(W1, Wt1, 768, 256, idx);
    } else {
        int idx = (b - cb - w1b) * 256 + tid;
        make_wt_elem(W2, Wt2, 256, 128, idx);
    }
}

// ---------------- CSR scan chain ----------------

__global__ __launch_bounds__(1024) void blockscan_kernel(const int* __restrict__ cnt,
                                                         int* __restrict__ rp,
                                                         int* __restrict__ bsum, int n) {
    __shared__ int sdata[1024];
    int tid = threadIdx.x;
    int i = blockIdx.x * 1024 + tid;
    int v = (i < n) ? cnt[i] : 0;
    sdata[tid] = v;
    __syncthreads();
    for (int off = 1; off < 1024; off <<= 1) {
        int t = 0;
        if (tid >= off) t = sdata[tid - off];
        __syncthreads();
        sdata[tid] += t;
        __syncthreads();
    }
    if (i < n) rp[i] = sdata[tid] - v;       // local exclusive
    if (tid == 1023) bsum[blockIdx.x] = sdata[1023];
}

// fixup v2: inlines the bsum prefix (topscan) — one wave scans bsum[0..blockIdx.x-1]
// (<= 48 ints), broadcast via LDS. Eliminates the single-block topscan launch.
__global__ __launch_bounds__(1024) void fixup_kernel(int* __restrict__ rp,
                                                     const int* __restrict__ bsum,
                                                     const int* __restrict__ cnt,
                                                     int* __restrict__ cursor,
                                                     float* __restrict__ dinv,
                                                     int n, int E) {
    __shared__ int carry_s;
    int tid = threadIdx.x;
    if (tid < 64) {
        int sum = 0;
        for (int i = tid; i < blockIdx.x; i += 64) sum += bsum[i];
        for (int off = 32; off > 0; off >>= 1) sum += __shfl_xor(sum, off, 64);
        if (tid == 0) carry_s = sum;
    }
    __syncthreads();
    int carry = carry_s;
    int i = blockIdx.x * 1024 + tid;
    if (i < n) {
        int r = rp[i] + carry;
        rp[i] = r;
        cursor[i] = r;
        dinv[i] = rsqrtf((float)cnt[i] + 1.0f);
    }
    if (i == 0) rp[n] = E;
}

// fill v2: one packed 8B store per edge (csrc+cw merged into int2 record) —
// halves scattered-store request count here and edge-list load requests downstream.
__global__ void fill_kernel(const int* __restrict__ src, const int* __restrict__ dst,
                            int* __restrict__ cursor, const float* __restrict__ dinv,
                            int2* __restrict__ ecw, int E) {
    int e = blockIdx.x * blockDim.x + threadIdx.x;
    if (e >= E) return;
    int d = dst[e];
    int s = src[e];
    int p = atomicAdd(&cursor[d], 1);
    ecw[p] = make_int2(s, __float_as_int(dinv[s] * dinv[d]));
}

// ---------------- GEMM1: h1(fp8)[M x 256] = x(fp32) @ Wt1(frag-ready bf16) ----------------
// round-2 champion: 32 rows x 256 cols per block, 256 threads = 4 waves.
// Reg-stage fp32 -> truncate to bf16 -> swizzled fragment-ready LDS (48 KB,
// conflict-free layout shared with gemm_panel_kernel). One barrier; barrier-free K-loop.

__global__ __launch_bounds__(256, 3) void gemm1_kernel(const float* __restrict__ x,
                                                       const short* __restrict__ Wt,
                                                       unsigned char* __restrict__ h8,
                                                       int M) {
    constexpr int KC = 24;                     // 768 / 32
    constexpr int RT = 2;                      // row-tiles -> 32 rows per block
    constexpr int O = KC * 4;                  // 96 octets (8 k-elems) per row
    constexpr int F = KC * RT * 64 / 256;      // 12 frags staged per thread

    __shared__ s16x8 As[KC * RT * 64];         // 48 KB bf16, fragment-ready

    const int tid = threadIdx.x;
    const int m0 = blockIdx.x * (RT * 16);

    // stage: load fp32 pairs, truncation-pack to bf16
    s16x8 v[F];
#pragma unroll
    for (int i = 0; i < F; ++i) {
        int idx = i * 256 + tid;
        int r = idx / O;
        int o = idx - r * O;
        int row = m0 + r;
        if (row >= M) row = M - 1;
        const float4* fp = (const float4*)(x + (size_t)row * 768 + o * 8);
        float4 f0 = fp[0];
        float4 f1 = fp[1];
        u32x4 pk;
        pk.x = (__float_as_uint(f0.x) >> 16) | (__float_as_uint(f0.y) & 0xFFFF0000u);
        pk.y = (__float_as_uint(f0.z) >> 16) | (__float_as_uint(f0.w) & 0xFFFF0000u);
        pk.z = (__float_as_uint(f1.x) >> 16) | (__float_as_uint(f1.y) & 0xFFFF0000u);
        pk.w = (__float_as_uint(f1.z) >> 16) | (__float_as_uint(f1.w) & 0xFFFF0000u);
        v[i] = __builtin_bit_cast(s16x8, pk);
    }
#pragma unroll
    for (int i = 0; i < F; ++i) {
        int idx = i * 256 + tid;
        int r = idx / O;
        int o = idx - r * O;
        int c = o >> 2, q = o & 3;
        int slot = q * 16 + (((r & 15) + q + ((c & 3) << 2)) & 15);
        As[(c * RT + (r >> 4)) * 64 + slot] = v[i];
    }
    __syncthreads();

    const int lane = tid & 63;
    const int wave = tid >> 6;
    const int b128 = wave >> 1;                // 128-col B block
    const int nt0 = (wave & 1) * 4;            // first 16-col tile inside it
    const int q = lane >> 4;
    const int rl = lane & 15;
    const s16x8* wt = (const s16x8*)Wt;

    f32x4 acc[RT][4];
#pragma unroll
    for (int i = 0; i < RT; ++i)
#pragma unroll
        for (int j = 0; j < 4; ++j)
            acc[i][j] = (f32x4){0.f, 0.f, 0.f, 0.f};

#pragma unroll 4
    for (int c = 0; c < KC; ++c) {
        int slot = q * 16 + ((rl + q + ((c & 3) << 2)) & 15);
        b16x8 areg[RT], breg[4];
#pragma unroll
        for (int i = 0; i < RT; ++i)
            areg[i] = __builtin_bit_cast(b16x8, As[(c * RT + i) * 64 + slot]);
        size_t bb = (size_t)(c * 2 + b128) * 512 + nt0 * 64 + lane;
#pragma unroll
        for (int j = 0; j < 4; ++j)
            breg[j] = __builtin_bit_cast(b16x8, wt[bb + j * 64]);
#pragma unroll
        for (int i = 0; i < RT; ++i)
#pragma unroll
            for (int j = 0; j < 4; ++j)
                acc[i][j] = __builtin_amdgcn_mfma_f32_16x16x32_bf16(areg[i], breg[j], acc[i][j], 0, 0, 0);
    }

    const int quad = lane >> 4;
    const int nl = lane & 15;
#pragma unroll
    for (int i = 0; i < RT; ++i) {
        int rbase = m0 + i * 16 + quad * 4;
#pragma unroll
        for (int j = 0; j < 4; ++j) {
            int col = wave * 64 + j * 16 + nl;
#pragma unroll
            for (int r = 0; r < 4; ++r) {
                int row = rbase + r;
                if (row < M) {
                    unsigned u = __builtin_amdgcn_cvt_pk_fp8_f32(acc[i][j][r], acc[i][j][r], 0, false);
                    h8[(size_t)row * 256 + col] = (unsigned char)(u & 0xFF);
                }
            }
        }
    }
}

// ---------------- row-panel GEMM (bf16 A, layer 2) — round-2 champion ----------------

template<typename AT, int KC, int RT, int CW, int MINW>
__global__ __launch_bounds__(256, MINW) void gemm_panel_kernel(
        const AT* __restrict__ A, const short* __restrict__ Wt,
        unsigned short* __restrict__ Cb, int M) {
    constexpr int K = KC * 32;
    constexpr int O = KC * 4;              // 8-elem octets per row
    constexpr int F = KC * RT / 4;         // frags staged per thread
    constexpr int NCOLS = CW * 64;
    constexpr int NB = NCOLS >> 7;         // 128-col B blocks
    constexpr int MT = RT * CW / 4;        // m-tiles per wave

    __shared__ s16x8 As[KC * RT * 64];

    const int tid = threadIdx.x;
    const int m0 = blockIdx.x * (RT * 16);

    s16x8 v[F];
#pragma unroll
    for (int i = 0; i < F; ++i) {
        int idx = i * 256 + tid;
        int r = idx / O;
        int o = idx - r * O;
        int row = m0 + r;
        if (row >= M) row = M - 1;
        v[i] = *(const s16x8*)((const unsigned short*)A + (size_t)row * K + o * 8);
    }
#pragma unroll
    for (int i = 0; i < F; ++i) {
        int idx = i * 256 + tid;
        int r = idx / O;
        int o = idx - r * O;
        int c = o >> 2, q = o & 3;
        int slot = q * 16 + (((r & 15) + q + ((c & 3) << 2)) & 15);
        As[(c * RT + (r >> 4)) * 64 + slot] = v[i];
    }
    __syncthreads();

    const int lane = tid & 63;
    const int wave = tid >> 6;
    const int cw_i = wave % CW;
    const int rg = wave / CW;
    const int mtb = rg * MT;
    const int b128 = (cw_i * 64) >> 7;
    const int nt0 = (cw_i * 4) & 7;
    const int q = lane >> 4;
    const int rl = lane & 15;
    const s16x8* wt = (const s16x8*)Wt;

    f32x4 acc[MT][4];
#pragma unroll
    for (int i = 0; i < MT; ++i)
#pragma unroll
        for (int j = 0; j < 4; ++j)
            acc[i][j] = (f32x4){0.f, 0.f, 0.f, 0.f};

#pragma unroll 4
    for (int c = 0; c < KC; ++c) {
        int slot = q * 16 + ((rl + q + ((c & 3) << 2)) & 15);
        b16x8 areg[MT], breg[4];
#pragma unroll
        for (int i = 0; i < MT; ++i)
            areg[i] = __builtin_bit_cast(b16x8, As[(c * RT + mtb + i) * 64 + slot]);
        size_t bb = (size_t)(c * NB + b128) * 512 + nt0 * 64 + lane;
#pragma unroll
        for (int j = 0; j < 4; ++j)
            breg[j] = __builtin_bit_cast(b16x8, wt[bb + j * 64]);
#pragma unroll
        for (int i = 0; i < MT; ++i)
#pragma unroll
            for (int j = 0; j < 4; ++j)
                acc[i][j] = __builtin_amdgcn_mfma_f32_16x16x32_bf16(areg[i], breg[j], acc[i][j], 0, 0, 0);
    }

    const int quad = lane >> 4;
    const int nl = lane & 15;
#pragma unroll
    for (int i = 0; i < MT; ++i) {
        int rbase = m0 + (mtb + i) * 16 + quad * 4;
#pragma unroll
        for (int j = 0; j < 4; ++j) {
            int col = cw_i * 64 + j * 16 + nl;
#pragma unroll
            for (int rr = 0; rr < 4; ++rr) {
                int row = rbase + rr;
                if (row < M) Cb[(size_t)row * NCOLS + col] = (unsigned short)f2bf(acc[i][j][rr]);
            }
        }
    }
}

// ---------------- aggregation ----------------
// 4-edge-parallel gather. Wave per node; lane = (eg = edge slot 0..3, ch = 16B chunk).
// v3: edge records packed (int2 {src, weight}) -> one 8B coalesced load per lane per
// batch; inner loop unroll 4 -> 4 row-gathers (16 edges) in flight per wave (was 2).
// Cross-lane xor(16/32) reduction combines the 4 edge slots once per node.

__global__ __launch_bounds__(256) void agg256_f8_kernel(const unsigned char* __restrict__ h8,
                                                        const int* __restrict__ rp,
                                                        const int2* __restrict__ ecw,
                                                        const float* __restrict__ dinv,
                                                        const float* __restrict__ bias,
                                                        unsigned short* __restrict__ out, int n) {
    int node = blockIdx.x * 4 + (threadIdx.x >> 6);
    int lane = threadIdx.x & 63;
    if (node >= n) return;
    const int eg = lane >> 4;                    // edge slot 0..3
    const int ch = lane & 15;                    // 16-channel chunk
    float di = dinv[node];

    float acc[16];
    {
        u32x4 v = *(const u32x4*)(h8 + (size_t)node * 256 + ch * 16);
        float ws = (eg == 0) ? di * di : 0.f;    // self term counted once
#pragma unroll
        for (int u = 0; u < 4; ++u) {
            f32x2 lo = __builtin_amdgcn_cvt_pk_f32_fp8(v[u], false);
            f32x2 hi = __builtin_amdgcn_cvt_pk_f32_fp8(v[u], true);
            acc[u * 4 + 0] = ws * lo.x; acc[u * 4 + 1] = ws * lo.y;
            acc[u * 4 + 2] = ws * hi.x; acc[u * 4 + 3] = ws * hi.y;
        }
    }

    int e0 = rp[node], e1 = rp[node + 1];
    for (int base = e0; base < e1; base += 64) {
        int idx = base + lane;
        int2 er = (idx < e1) ? ecw[idx] : make_int2(0, 0);
        int sb = er.x;
        float wb = __int_as_float(er.y);
        int cnt = e1 - base; if (cnt > 64) cnt = 64;
#pragma unroll 4
        for (int i = 0; i < cnt; i += 4) {
            int s = __shfl(sb, i + eg, 64);       // i+eg <= 63 always (i step 4, i<=60)
            float w = __shfl(wb, i + eg, 64);
            u32x4 v = *(const u32x4*)(h8 + (size_t)s * 256 + ch * 16);
#pragma unroll
            for (int u = 0; u < 4; ++u) {
                f32x2 lo = __builtin_amdgcn_cvt_pk_f32_fp8(v[u], false);
                f32x2 hi = __builtin_amdgcn_cvt_pk_f32_fp8(v[u], true);
                acc[u * 4 + 0] += w * lo.x; acc[u * 4 + 1] += w * lo.y;
                acc[u * 4 + 2] += w * hi.x; acc[u * 4 + 3] += w * hi.y;
            }
        }
    }

    // combine the 4 edge slots
#pragma unroll
    for (int k = 0; k < 16; ++k) {
        acc[k] += __shfl_xor(acc[k], 16, 64);
        acc[k] += __shfl_xor(acc[k], 32, 64);
    }

    // bias + relu + pack to bf16; lanes eg 0/1 store the two 16B halves of the 32B chunk
    unsigned pk[8];
#pragma unroll
    for (int k = 0; k < 8; ++k) {
        float b0 = bias[ch * 16 + 2 * k];
        float b1 = bias[ch * 16 + 2 * k + 1];
        float a0 = fmaxf(acc[2 * k] + b0, 0.f);
        float a1 = fmaxf(acc[2 * k + 1] + b1, 0.f);
        pk[k] = ((unsigned)(unsigned short)f2bf(a0)) | (((unsigned)(unsigned short)f2bf(a1)) << 16);
    }
    if (eg < 2) {
        u32x4 ov;
        ov.x = pk[eg * 4 + 0]; ov.y = pk[eg * 4 + 1];
        ov.z = pk[eg * 4 + 2]; ov.w = pk[eg * 4 + 3];
        *(u32x4*)((char*)out + (size_t)node * 512 + ch * 32 + eg * 16) = ov;
    }
}

// Layer 2 fused with W3: 4-edge-parallel gather of bf16 h2; a2 = relu(agg+b2);
// z = a2 @ W3 (128x2) via per-lane partials + shuffle reduce. Packed edges, unroll 4.
__global__ __launch_bounds__(256) void agg128_w3_kernel(const unsigned short* __restrict__ h,
                                                        const int* __restrict__ rp,
                                                        const int2* __restrict__ ecw,
                                                        const float* __restrict__ dinv,
                                                        const float* __restrict__ b2,
                                                        const float* __restrict__ W3,
                                                        float* __restrict__ z, int n) {
    int node = blockIdx.x * 4 + (threadIdx.x >> 6);
    int lane = threadIdx.x & 63;
    if (node >= n) return;
    const int eg = lane >> 4;                    // edge slot 0..3
    const int ch = lane & 15;                    // 8-channel (16B) chunk
    float di = dinv[node];

    float acc[8];
    {
        u32x4 v = *(const u32x4*)((const char*)h + (size_t)node * 256 + ch * 16);
        float ws = (eg == 0) ? di * di : 0.f;
#pragma unroll
        for (int u = 0; u < 4; ++u) {
            acc[u * 2 + 0] = ws * __uint_as_float(v[u] << 16);
            acc[u * 2 + 1] = ws * __uint_as_float(v[u] & 0xFFFF0000u);
        }
    }

    int e0 = rp[node], e1 = rp[node + 1];
    for (int base = e0; base < e1; base += 64) {
        int idx = base + lane;
        int2 er = (idx < e1) ? ecw[idx] : make_int2(0, 0);
        int sb = er.x;
        float wb = __int_as_float(er.y);
        int cnt = e1 - base; if (cnt > 64) cnt = 64;
#pragma unroll 4
        for (int i = 0; i < cnt; i += 4) {
            int s = __shfl(sb, i + eg, 64);
            float w = __shfl(wb, i + eg, 64);
            u32x4 v = *(const u32x4*)((const char*)h + (size_t)s * 256 + ch * 16);
#pragma unroll
            for (int u = 0; u < 4; ++u) {
                acc[u * 2 + 0] += w * __uint_as_float(v[u] << 16);
                acc[u * 2 + 1] += w * __uint_as_float(v[u] & 0xFFFF0000u);
            }
        }
    }

#pragma unroll
    for (int k = 0; k < 8; ++k) {
        acc[k] += __shfl_xor(acc[k], 16, 64);
        acc[k] += __shfl_xor(acc[k], 32, 64);
    }

    // a2 = relu(acc + b2); z partials over this lane's 8 channels
    float z0 = 0.f, z1 = 0.f;
#pragma unroll
    for (int k = 0; k < 8; ++k) {
        float a = fmaxf(acc[k] + b2[ch * 8 + k], 0.f);
        z0 += a * W3[(ch * 8 + k) * 2];
        z1 += a * W3[(ch * 8 + k) * 2 + 1];
    }
    // reduce over the 16 ch groups (all eg groups hold identical values)
    for (int off = 8; off > 0; off >>= 1) {
        z0 += __shfl_xor(z0, off, 64);
        z1 += __shfl_xor(z1, off, 64);
    }
    if (lane == 0) {
        z[2 * (size_t)node] = z0;
        z[2 * (size_t)node + 1] = z1;
    }
}

// agg3: wave per node, 64-lane edge-parallel gather of z pairs + xor-tree reduce.
// Packed edge records (one 8B load per lane).
__global__ __launch_bounds__(256) void agg3_kernel(const float* __restrict__ z,
                                                   const int* __restrict__ rp,
                                                   const int2* __restrict__ ecw,
                                                   const float* __restrict__ dinv,
                                                   const float* __restrict__ bias,
                                                   float* __restrict__ out, int n) {
    int node = blockIdx.x * 4 + (threadIdx.x >> 6);
    int lane = threadIdx.x & 63;
    if (node >= n) return;
    float a0 = 0.f, a1 = 0.f;
    int e0 = rp[node], e1 = rp[node + 1];
    for (int idx = e0 + lane; idx < e1; idx += 64) {
        int2 er = ecw[idx];
        float w = __int_as_float(er.y);
        float2 zz = *(const float2*)(z + 2 * (size_t)er.x);
        a0 += w * zz.x;
        a1 += w * zz.y;
    }
    for (int off = 32; off > 0; off >>= 1) {
        a0 += __shfl_xor(a0, off, 64);
        a1 += __shfl_xor(a1, off, 64);
    }
    if (lane == 0) {
        float di = dinv[node];
        float2 zn = *(const float2*)(z + 2 * (size_t)node);
        a0 += di * di * zn.x + bias[0];
        a1 += di * di * zn.y + bias[1];
        out[2 * (size_t)node]     = 1.f / (1.f + __expf(-a0));
        out[2 * (size_t)node + 1] = 1.f / (1.f + __expf(-a1));
    }
}

// ---------------- launch ----------------

extern "C" void kernel_launch(void* const* d_in, const int* in_sizes, int n_in,
                              void* d_out, int out_size, void* d_ws, size_t ws_size,
                              hipStream_t stream) {
    const float* x  = (const float*)d_in[0];
    const int*   ei = (const int*)d_in[1];
    const float* W1 = (const float*)d_in[2];
    const float* b1 = (const float*)d_in[3];
    const float* W2 = (const float*)d_in[4];
    const float* b2 = (const float*)d_in[5];
    const float* W3 = (const float*)d_in[6];
    const float* b3 = (const float*)d_in[7];
    float* out = (float*)d_out;

    const int E  = in_sizes[1] / 2;
    const int C1 = in_sizes[3];              // 256
    const int C2 = in_sizes[5];              // 128
    const int K1 = in_sizes[2] / C1;         // 768
    const int N  = in_sizes[0] / K1;         // 50000

    const int* srcv = ei;
    const int* dstv = ei + E;

    char* p = (char*)d_ws;
    auto carve = [&](size_t bytes) {
        char* r = p;
        p += (bytes + 255) & ~(size_t)255;
        return r;
    };
    int*   cnt    = (int*)carve((size_t)N * 4);
    int*   rp     = (int*)carve((size_t)(N + 1) * 4);
    int*   cursor = (int*)carve((size_t)N * 4);
    float* dinv   = (float*)carve((size_t)N * 4);
    int*   bsum   = (int*)carve(1024 * 4);
    int2*  ecw    = (int2*)carve((size_t)E * 8);                     // packed {src, w}
    short* Wt1    = (short*)carve((size_t)K1 * C1 * 2);
    short* Wt2    = (short*)carve((size_t)C1 * C2 * 2);
    unsigned char* h8 = (unsigned char*)carve((size_t)N * C1);       // fp8 h1
    unsigned short* hB = (unsigned short*)carve((size_t)N * C1 * 2); // bf16 a1
    unsigned short* h2 = (unsigned short*)carve((size_t)N * C2 * 2); // bf16 h2
    float* zbuf   = (float*)carve((size_t)N * 2 * 4);

    const int nb = (N + 1023) / 1024;
    const int cb = (E + 255) / 256;
    const int w1b = (K1 * C1) / 256;         // 768
    const int w2b = (C1 * C2) / 256;         // 128

    // CSR + weight prep (fused)
    hipMemsetAsync(cnt, 0, (size_t)N * 4, stream);
    prep_kernel<<<cb + w1b + w2b, 256, 0, stream>>>(dstv, cnt, E, W1, Wt1, W2, Wt2, cb, w1b);
    blockscan_kernel<<<nb, 1024, 0, stream>>>(cnt, rp, bsum, N);
    fixup_kernel<<<nb, 1024, 0, stream>>>(rp, bsum, cnt, cursor, dinv, N, E);
    fill_kernel<<<(E + 255) / 256, 256, 0, stream>>>(srcv, dstv, cursor, dinv, ecw, E);

    // Layer 1: h1 = x @ W1 (fp8 out) ; a1 = relu(Ahat h1 + b1)
    gemm1_kernel<<<(N + 31) / 32, 256, 0, stream>>>(x, Wt1, h8, N);
    agg256_f8_kernel<<<(N + 3) / 4, 256, 0, stream>>>(h8, rp, ecw, dinv, b1, hB, N);

    // Layer 2: h2 = a1 @ W2 (64-row panels) ; fused a2 = relu(agg+b2), z = a2 @ W3
    gemm_panel_kernel<unsigned short, 8, 4, 2, 4><<<(N + 63) / 64, 256, 0, stream>>>(hB, Wt2, h2, N);
    agg128_w3_kernel<<<(N + 3) / 4, 256, 0, stream>>>(h2, rp, ecw, dinv, b2, W3, zbuf, N);

    // Layer 3 aggregation + sigmoid (wave-parallel)
    agg3_kernel<<<(N + 3) / 4, 256, 0, stream>>>(zbuf, rp, ecw, dinv, b3, out, N);
}

// Round 10
// 428.551 us; speedup vs baseline: 1.1233x; 1.0370x over previous
//
#include <hip/hip_runtime.h>
#include <math.h>

typedef short s16x8 __attribute__((ext_vector_type(8)));
typedef __bf16 b16x8 __attribute__((ext_vector_type(8)));
typedef float f32x4 __attribute__((ext_vector_type(4)));
typedef float f32x2 __attribute__((ext_vector_type(2)));
typedef unsigned int u32x4 __attribute__((ext_vector_type(4)));

__device__ inline short f2bf(float f) {
    unsigned u = __float_as_uint(f);
    unsigned r = u + 0x7FFFu + ((u >> 16) & 1u);   // RNE
    return (short)(r >> 16);
}
__device__ inline float bf2f(unsigned short u) {
    return __uint_as_float(((unsigned)u) << 16);
}

// ---------------- fused prep: count + make_wt1 + make_wt2 ----------------
// Wt chunk layout: [c = k0/32][b = n0/128][nt 0..7][lane 0..63][j 0..7]
//   value = W[c*32 + (lane>>4)*8 + j][b*128 + nt*16 + (lane&15)]

__device__ inline void make_wt_elem(const float* __restrict__ W, short* __restrict__ Wt,
                                    int K, int N, int idx) {
    int NB = N >> 7;
    int j = idx & 7;
    int l = (idx >> 3) & 63;
    int nt = (idx >> 9) & 7;
    int rest = idx >> 12;
    int b = rest % NB;
    int c = rest / NB;
    int k = c * 32 + (l >> 4) * 8 + j;
    int n = b * 128 + nt * 16 + (l & 15);
    Wt[idx] = f2bf(W[(size_t)k * N + n]);
}

__global__ void prep_kernel(const int* __restrict__ dst, int* __restrict__ cnt, int E,
                            const float* __restrict__ W1, short* __restrict__ Wt1,
                            const float* __restrict__ W2, short* __restrict__ Wt2,
                            int cb, int w1b) {
    int b = blockIdx.x;
    int tid = threadIdx.x;
    if (b < cb) {
        int e = b * 256 + tid;
        if (e < E) atomicAdd(&cnt[dst[e]], 1);
    } else if (b < cb + w1b) {
        int idx = (b - cb) * 256 + tid;
        make_wt_elem(W1, Wt1, 768, 256, idx);
    } else {
        int idx = (b - cb - w1b) * 256 + tid;
        make_wt_elem(W2, Wt2, 256, 128, idx);
    }
}

// ---------------- CSR scan chain ----------------

__global__ __launch_bounds__(1024) void blockscan_kernel(const int* __restrict__ cnt,
                                                         int* __restrict__ rp,
                                                         int* __restrict__ bsum, int n) {
    __shared__ int sdata[1024];
    int tid = threadIdx.x;
    int i = blockIdx.x * 1024 + tid;
    int v = (i < n) ? cnt[i] : 0;
    sdata[tid] = v;
    __syncthreads();
    for (int off = 1; off < 1024; off <<= 1) {
        int t = 0;
        if (tid >= off) t = sdata[tid - off];
        __syncthreads();
        sdata[tid] += t;
        __syncthreads();
    }
    if (i < n) rp[i] = sdata[tid] - v;       // local exclusive
    if (tid == 1023) bsum[blockIdx.x] = sdata[1023];
}

// fixup: inlines the bsum prefix (topscan) — one wave scans bsum[0..blockIdx.x-1]
// (<= 48 ints), broadcast via LDS.
__global__ __launch_bounds__(1024) void fixup_kernel(int* __restrict__ rp,
                                                     const int* __restrict__ bsum,
                                                     const int* __restrict__ cnt,
                                                     int* __restrict__ cursor,
                                                     float* __restrict__ dinv,
                                                     int n, int E) {
    __shared__ int carry_s;
    int tid = threadIdx.x;
    if (tid < 64) {
        int sum = 0;
        for (int i = tid; i < blockIdx.x; i += 64) sum += bsum[i];
        for (int off = 32; off > 0; off >>= 1) sum += __shfl_xor(sum, off, 64);
        if (tid == 0) carry_s = sum;
    }
    __syncthreads();
    int carry = carry_s;
    int i = blockIdx.x * 1024 + tid;
    if (i < n) {
        int r = rp[i] + carry;
        rp[i] = r;
        cursor[i] = r;
        dinv[i] = rsqrtf((float)cnt[i] + 1.0f);
    }
    if (i == 0) rp[n] = E;
}

// ---------------- fused GEMM1 + fill ----------------
// Blocks [0, G1B): round-2 champion gemm1 — 32 rows x 256 cols, 48 KB frag-ready LDS.
// Blocks [G1B, G1B+FB): fill — CSR edge scatter (packed int2 {src, w} records).
// The two roles are data-independent (fill: cursor/ecw; gemm1: x/Wt1 -> h8); fill's
// ~15-25 us of latency-bound scatter hides under gemm1's execution. The next launch
// boundary (agg256) guarantees both complete.

__global__ __launch_bounds__(256, 3) void gemm1_fill_kernel(
        const float* __restrict__ x, const short* __restrict__ Wt,
        unsigned char* __restrict__ h8, int M, int G1B,
        const int* __restrict__ src, const int* __restrict__ dst,
        int* __restrict__ cursor, const float* __restrict__ dinv,
        int2* __restrict__ ecw, int E) {
    constexpr int KC = 24;                     // 768 / 32
    constexpr int RT = 2;                      // row-tiles -> 32 rows per block
    constexpr int O = KC * 4;                  // 96 octets (8 k-elems) per row
    constexpr int F = KC * RT * 64 / 256;      // 12 frags staged per thread

    __shared__ s16x8 As[KC * RT * 64];         // 48 KB bf16, fragment-ready

    const int tid = threadIdx.x;

    if (blockIdx.x >= G1B) {                   // ---- fill role ----
        int e = (blockIdx.x - G1B) * 256 + tid;
        if (e < E) {
            int d = dst[e];
            int s = src[e];
            int p = atomicAdd(&cursor[d], 1);
            ecw[p] = make_int2(s, __float_as_int(dinv[s] * dinv[d]));
        }
        return;
    }

    // ---- gemm1 role ----
    const int m0 = blockIdx.x * (RT * 16);

    // stage: load fp32 pairs, truncation-pack to bf16
    s16x8 v[F];
#pragma unroll
    for (int i = 0; i < F; ++i) {
        int idx = i * 256 + tid;
        int r = idx / O;
        int o = idx - r * O;
        int row = m0 + r;
        if (row >= M) row = M - 1;
        const float4* fp = (const float4*)(x + (size_t)row * 768 + o * 8);
        float4 f0 = fp[0];
        float4 f1 = fp[1];
        u32x4 pk;
        pk.x = (__float_as_uint(f0.x) >> 16) | (__float_as_uint(f0.y) & 0xFFFF0000u);
        pk.y = (__float_as_uint(f0.z) >> 16) | (__float_as_uint(f0.w) & 0xFFFF0000u);
        pk.z = (__float_as_uint(f1.x) >> 16) | (__float_as_uint(f1.y) & 0xFFFF0000u);
        pk.w = (__float_as_uint(f1.z) >> 16) | (__float_as_uint(f1.w) & 0xFFFF0000u);
        v[i] = __builtin_bit_cast(s16x8, pk);
    }
#pragma unroll
    for (int i = 0; i < F; ++i) {
        int idx = i * 256 + tid;
        int r = idx / O;
        int o = idx - r * O;
        int c = o >> 2, q = o & 3;
        int slot = q * 16 + (((r & 15) + q + ((c & 3) << 2)) & 15);
        As[(c * RT + (r >> 4)) * 64 + slot] = v[i];
    }
    __syncthreads();

    const int lane = tid & 63;
    const int wave = tid >> 6;
    const int b128 = wave >> 1;                // 128-col B block
    const int nt0 = (wave & 1) * 4;            // first 16-col tile inside it
    const int q = lane >> 4;
    const int rl = lane & 15;
    const s16x8* wt = (const s16x8*)Wt;

    f32x4 acc[RT][4];
#pragma unroll
    for (int i = 0; i < RT; ++i)
#pragma unroll
        for (int j = 0; j < 4; ++j)
            acc[i][j] = (f32x4){0.f, 0.f, 0.f, 0.f};

#pragma unroll 4
    for (int c = 0; c < KC; ++c) {
        int slot = q * 16 + ((rl + q + ((c & 3) << 2)) & 15);
        b16x8 areg[RT], breg[4];
#pragma unroll
        for (int i = 0; i < RT; ++i)
            areg[i] = __builtin_bit_cast(b16x8, As[(c * RT + i) * 64 + slot]);
        size_t bb = (size_t)(c * 2 + b128) * 512 + nt0 * 64 + lane;
#pragma unroll
        for (int j = 0; j < 4; ++j)
            breg[j] = __builtin_bit_cast(b16x8, wt[bb + j * 64]);
#pragma unroll
        for (int i = 0; i < RT; ++i)
#pragma unroll
            for (int j = 0; j < 4; ++j)
                acc[i][j] = __builtin_amdgcn_mfma_f32_16x16x32_bf16(areg[i], breg[j], acc[i][j], 0, 0, 0);
    }

    const int quad = lane >> 4;
    const int nl = lane & 15;
#pragma unroll
    for (int i = 0; i < RT; ++i) {
        int rbase = m0 + i * 16 + quad * 4;
#pragma unroll
        for (int j = 0; j < 4; ++j) {
            int col = wave * 64 + j * 16 + nl;
#pragma unroll
            for (int r = 0; r < 4; ++r) {
                int row = rbase + r;
                if (row < M) {
                    unsigned u = __builtin_amdgcn_cvt_pk_fp8_f32(acc[i][j][r], acc[i][j][r], 0, false);
                    h8[(size_t)row * 256 + col] = (unsigned char)(u & 0xFF);
                }
            }
        }
    }
}

// ---------------- row-panel GEMM (bf16 A, layer 2) — round-2 champion ----------------

template<typename AT, int KC, int RT, int CW, int MINW>
__global__ __launch_bounds__(256, MINW) void gemm_panel_kernel(
        const AT* __restrict__ A, const short* __restrict__ Wt,
        unsigned short* __restrict__ Cb, int M) {
    constexpr int K = KC * 32;
    constexpr int O = KC * 4;              // 8-elem octets per row
    constexpr int F = KC * RT / 4;         // frags staged per thread
    constexpr int NCOLS = CW * 64;
    constexpr int NB = NCOLS >> 7;         // 128-col B blocks
    constexpr int MT = RT * CW / 4;        // m-tiles per wave

    __shared__ s16x8 As[KC * RT * 64];

    const int tid = threadIdx.x;
    const int m0 = blockIdx.x * (RT * 16);

    s16x8 v[F];
#pragma unroll
    for (int i = 0; i < F; ++i) {
        int idx = i * 256 + tid;
        int r = idx / O;
        int o = idx - r * O;
        int row = m0 + r;
        if (row >= M) row = M - 1;
        v[i] = *(const s16x8*)((const unsigned short*)A + (size_t)row * K + o * 8);
    }
#pragma unroll
    for (int i = 0; i < F; ++i) {
        int idx = i * 256 + tid;
        int r = idx / O;
        int o = idx - r * O;
        int c = o >> 2, q = o & 3;
        int slot = q * 16 + (((r & 15) + q + ((c & 3) << 2)) & 15);
        As[(c * RT + (r >> 4)) * 64 + slot] = v[i];
    }
    __syncthreads();

    const int lane = tid & 63;
    const int wave = tid >> 6;
    const int cw_i = wave % CW;
    const int rg = wave / CW;
    const int mtb = rg * MT;
    const int b128 = (cw_i * 64) >> 7;
    const int nt0 = (cw_i * 4) & 7;
    const int q = lane >> 4;
    const int rl = lane & 15;
    const s16x8* wt = (const s16x8*)Wt;

    f32x4 acc[MT][4];
#pragma unroll
    for (int i = 0; i < MT; ++i)
#pragma unroll
        for (int j = 0; j < 4; ++j)
            acc[i][j] = (f32x4){0.f, 0.f, 0.f, 0.f};

#pragma unroll 4
    for (int c = 0; c < KC; ++c) {
        int slot = q * 16 + ((rl + q + ((c & 3) << 2)) & 15);
        b16x8 areg[MT], breg[4];
#pragma unroll
        for (int i = 0; i < MT; ++i)
            areg[i] = __builtin_bit_cast(b16x8, As[(c * RT + mtb + i) * 64 + slot]);
        size_t bb = (size_t)(c * NB + b128) * 512 + nt0 * 64 + lane;
#pragma unroll
        for (int j = 0; j < 4; ++j)
            breg[j] = __builtin_bit_cast(b16x8, wt[bb + j * 64]);
#pragma unroll
        for (int i = 0; i < MT; ++i)
#pragma unroll
            for (int j = 0; j < 4; ++j)
                acc[i][j] = __builtin_amdgcn_mfma_f32_16x16x32_bf16(areg[i], breg[j], acc[i][j], 0, 0, 0);
    }

    const int quad = lane >> 4;
    const int nl = lane & 15;
#pragma unroll
    for (int i = 0; i < MT; ++i) {
        int rbase = m0 + (mtb + i) * 16 + quad * 4;
#pragma unroll
        for (int j = 0; j < 4; ++j) {
            int col = cw_i * 64 + j * 16 + nl;
#pragma unroll
            for (int rr = 0; rr < 4; ++rr) {
                int row = rbase + rr;
                if (row < M) Cb[(size_t)row * NCOLS + col] = (unsigned short)f2bf(acc[i][j][rr]);
            }
        }
    }
}

// ---------------- aggregation ----------------
// 4-edge-parallel gather. Wave per node; lane = (eg = edge slot 0..3, ch = 16B chunk).
// Edge records packed (int2 {src, weight}) -> one 8B coalesced load per lane per batch;
// inner loop unroll 4 -> 4 row-gathers (16 edges) in flight per wave.
// Cross-lane xor(16/32) reduction combines the 4 edge slots once per node.

__global__ __launch_bounds__(256) void agg256_f8_kernel(const unsigned char* __restrict__ h8,
                                                        const int* __restrict__ rp,
                                                        const int2* __restrict__ ecw,
                                                        const float* __restrict__ dinv,
                                                        const float* __restrict__ bias,
                                                        unsigned short* __restrict__ out, int n) {
    int node = blockIdx.x * 4 + (threadIdx.x >> 6);
    int lane = threadIdx.x & 63;
    if (node >= n) return;
    const int eg = lane >> 4;                    // edge slot 0..3
    const int ch = lane & 15;                    // 16-channel chunk
    float di = dinv[node];

    float acc[16];
    {
        u32x4 v = *(const u32x4*)(h8 + (size_t)node * 256 + ch * 16);
        float ws = (eg == 0) ? di * di : 0.f;    // self term counted once
#pragma unroll
        for (int u = 0; u < 4; ++u) {
            f32x2 lo = __builtin_amdgcn_cvt_pk_f32_fp8(v[u], false);
            f32x2 hi = __builtin_amdgcn_cvt_pk_f32_fp8(v[u], true);
            acc[u * 4 + 0] = ws * lo.x; acc[u * 4 + 1] = ws * lo.y;
            acc[u * 4 + 2] = ws * hi.x; acc[u * 4 + 3] = ws * hi.y;
        }
    }

    int e0 = rp[node], e1 = rp[node + 1];
    for (int base = e0; base < e1; base += 64) {
        int idx = base + lane;
        int2 er = (idx < e1) ? ecw[idx] : make_int2(0, 0);
        int sb = er.x;
        float wb = __int_as_float(er.y);
        int cnt = e1 - base; if (cnt > 64) cnt = 64;
#pragma unroll 4
        for (int i = 0; i < cnt; i += 4) {
            int s = __shfl(sb, i + eg, 64);       // i+eg <= 63 always (i step 4, i<=60)
            float w = __shfl(wb, i + eg, 64);
            u32x4 v = *(const u32x4*)(h8 + (size_t)s * 256 + ch * 16);
#pragma unroll
            for (int u = 0; u < 4; ++u) {
                f32x2 lo = __builtin_amdgcn_cvt_pk_f32_fp8(v[u], false);
                f32x2 hi = __builtin_amdgcn_cvt_pk_f32_fp8(v[u], true);
                acc[u * 4 + 0] += w * lo.x; acc[u * 4 + 1] += w * lo.y;
                acc[u * 4 + 2] += w * hi.x; acc[u * 4 + 3] += w * hi.y;
            }
        }
    }

    // combine the 4 edge slots
#pragma unroll
    for (int k = 0; k < 16; ++k) {
        acc[k] += __shfl_xor(acc[k], 16, 64);
        acc[k] += __shfl_xor(acc[k], 32, 64);
    }

    // bias + relu + pack to bf16; lanes eg 0/1 store the two 16B halves of the 32B chunk
    unsigned pk[8];
#pragma unroll
    for (int k = 0; k < 8; ++k) {
        float b0 = bias[ch * 16 + 2 * k];
        float b1 = bias[ch * 16 + 2 * k + 1];
        float a0 = fmaxf(acc[2 * k] + b0, 0.f);
        float a1 = fmaxf(acc[2 * k + 1] + b1, 0.f);
        pk[k] = ((unsigned)(unsigned short)f2bf(a0)) | (((unsigned)(unsigned short)f2bf(a1)) << 16);
    }
    if (eg < 2) {
        u32x4 ov;
        ov.x = pk[eg * 4 + 0]; ov.y = pk[eg * 4 + 1];
        ov.z = pk[eg * 4 + 2]; ov.w = pk[eg * 4 + 3];
        *(u32x4*)((char*)out + (size_t)node * 512 + ch * 32 + eg * 16) = ov;
    }
}

// Layer 2 fused with W3: 4-edge-parallel gather of bf16 h2; a2 = relu(agg+b2);
// z = a2 @ W3 (128x2) via per-lane partials + shuffle reduce. Packed edges, unroll 4.
__global__ __launch_bounds__(256) void agg128_w3_kernel(const unsigned short* __restrict__ h,
                                                        const int* __restrict__ rp,
                                                        const int2* __restrict__ ecw,
                                                        const float* __restrict__ dinv,
                                                        const float* __restrict__ b2,
                                                        const float* __restrict__ W3,
                                                        float* __restrict__ z, int n) {
    int node = blockIdx.x * 4 + (threadIdx.x >> 6);
    int lane = threadIdx.x & 63;
    if (node >= n) return;
    const int eg = lane >> 4;                    // edge slot 0..3
    const int ch = lane & 15;                    // 8-channel (16B) chunk
    float di = dinv[node];

    float acc[8];
    {
        u32x4 v = *(const u32x4*)((const char*)h + (size_t)node * 256 + ch * 16);
        float ws = (eg == 0) ? di * di : 0.f;
#pragma unroll
        for (int u = 0; u < 4; ++u) {
            acc[u * 2 + 0] = ws * __uint_as_float(v[u] << 16);
            acc[u * 2 + 1] = ws * __uint_as_float(v[u] & 0xFFFF0000u);
        }
    }

    int e0 = rp[node], e1 = rp[node + 1];
    for (int base = e0; base < e1; base += 64) {
        int idx = base + lane;
        int2 er = (idx < e1) ? ecw[idx] : make_int2(0, 0);
        int sb = er.x;
        float wb = __int_as_float(er.y);
        int cnt = e1 - base; if (cnt > 64) cnt = 64;
#pragma unroll 4
        for (int i = 0; i < cnt; i += 4) {
            int s = __shfl(sb, i + eg, 64);
            float w = __shfl(wb, i + eg, 64);
            u32x4 v = *(const u32x4*)((const char*)h + (size_t)s * 256 + ch * 16);
#pragma unroll
            for (int u = 0; u < 4; ++u) {
                acc[u * 2 + 0] += w * __uint_as_float(v[u] << 16);
                acc[u * 2 + 1] += w * __uint_as_float(v[u] & 0xFFFF0000u);
            }
        }
    }

#pragma unroll
    for (int k = 0; k < 8; ++k) {
        acc[k] += __shfl_xor(acc[k], 16, 64);
        acc[k] += __shfl_xor(acc[k], 32, 64);
    }

    // a2 = relu(acc + b2); z partials over this lane's 8 channels
    float z0 = 0.f, z1 = 0.f;
#pragma unroll
    for (int k = 0; k < 8; ++k) {
        float a = fmaxf(acc[k] + b2[ch * 8 + k], 0.f);
        z0 += a * W3[(ch * 8 + k) * 2];
        z1 += a * W3[(ch * 8 + k) * 2 + 1];
    }
    // reduce over the 16 ch groups (all eg groups hold identical values)
    for (int off = 8; off > 0; off >>= 1) {
        z0 += __shfl_xor(z0, off, 64);
        z1 += __shfl_xor(z1, off, 64);
    }
    if (lane == 0) {
        z[2 * (size_t)node] = z0;
        z[2 * (size_t)node + 1] = z1;
    }
}

// agg3: wave per node, 64-lane edge-parallel gather of z pairs + xor-tree reduce.
// Packed edge records (one 8B load per lane).
__global__ __launch_bounds__(256) void agg3_kernel(const float* __restrict__ z,
                                                   const int* __restrict__ rp,
                                                   const int2* __restrict__ ecw,
                                                   const float* __restrict__ dinv,
                                                   const float* __restrict__ bias,
                                                   float* __restrict__ out, int n) {
    int node = blockIdx.x * 4 + (threadIdx.x >> 6);
    int lane = threadIdx.x & 63;
    if (node >= n) return;
    float a0 = 0.f, a1 = 0.f;
    int e0 = rp[node], e1 = rp[node + 1];
    for (int idx = e0 + lane; idx < e1; idx += 64) {
        int2 er = ecw[idx];
        float w = __int_as_float(er.y);
        float2 zz = *(const float2*)(z + 2 * (size_t)er.x);
        a0 += w * zz.x;
        a1 += w * zz.y;
    }
    for (int off = 32; off > 0; off >>= 1) {
        a0 += __shfl_xor(a0, off, 64);
        a1 += __shfl_xor(a1, off, 64);
    }
    if (lane == 0) {
        float di = dinv[node];
        float2 zn = *(const float2*)(z + 2 * (size_t)node);
        a0 += di * di * zn.x + bias[0];
        a1 += di * di * zn.y + bias[1];
        out[2 * (size_t)node]     = 1.f / (1.f + __expf(-a0));
        out[2 * (size_t)node + 1] = 1.f / (1.f + __expf(-a1));
    }
}

// ---------------- launch ----------------

extern "C" void kernel_launch(void* const* d_in, const int* in_sizes, int n_in,
                              void* d_out, int out_size, void* d_ws, size_t ws_size,
                              hipStream_t stream) {
    const float* x  = (const float*)d_in[0];
    const int*   ei = (const int*)d_in[1];
    const float* W1 = (const float*)d_in[2];
    const float* b1 = (const float*)d_in[3];
    const float* W2 = (const float*)d_in[4];
    const float* b2 = (const float*)d_in[5];
    const float* W3 = (const float*)d_in[6];
    const float* b3 = (const float*)d_in[7];
    float* out = (float*)d_out;

    const int E  = in_sizes[1] / 2;
    const int C1 = in_sizes[3];              // 256
    const int C2 = in_sizes[5];              // 128
    const int K1 = in_sizes[2] / C1;         // 768
    const int N  = in_sizes[0] / K1;         // 50000

    const int* srcv = ei;
    const int* dstv = ei + E;

    char* p = (char*)d_ws;
    auto carve = [&](size_t bytes) {
        char* r = p;
        p += (bytes + 255) & ~(size_t)255;
        return r;
    };
    int*   cnt    = (int*)carve((size_t)N * 4);
    int*   rp     = (int*)carve((size_t)(N + 1) * 4);
    int*   cursor = (int*)carve((size_t)N * 4);
    float* dinv   = (float*)carve((size_t)N * 4);
    int*   bsum   = (int*)carve(1024 * 4);
    int2*  ecw    = (int2*)carve((size_t)E * 8);                     // packed {src, w}
    short* Wt1    = (short*)carve((size_t)K1 * C1 * 2);
    short* Wt2    = (short*)carve((size_t)C1 * C2 * 2);
    unsigned char* h8 = (unsigned char*)carve((size_t)N * C1);       // fp8 h1
    unsigned short* hB = (unsigned short*)carve((size_t)N * C1 * 2); // bf16 a1
    unsigned short* h2 = (unsigned short*)carve((size_t)N * C2 * 2); // bf16 h2
    float* zbuf   = (float*)carve((size_t)N * 2 * 4);

    const int nb = (N + 1023) / 1024;
    const int cb = (E + 255) / 256;
    const int w1b = (K1 * C1) / 256;         // 768
    const int w2b = (C1 * C2) / 256;         // 128
    const int g1b = (N + 31) / 32;           // gemm1 blocks
    const int fb  = (E + 255) / 256;         // fill blocks

    // CSR + weight prep (fused)
    hipMemsetAsync(cnt, 0, (size_t)N * 4, stream);
    prep_kernel<<<cb + w1b + w2b, 256, 0, stream>>>(dstv, cnt, E, W1, Wt1, W2, Wt2, cb, w1b);
    blockscan_kernel<<<nb, 1024, 0, stream>>>(cnt, rp, bsum, N);
    fixup_kernel<<<nb, 1024, 0, stream>>>(rp, bsum, cnt, cursor, dinv, N, E);

    // Layer 1 GEMM fused with CSR fill (independent roles, one launch):
    // h1 = x @ W1 (fp8 out) ; ecw/cursor scatter hides under gemm1.
    gemm1_fill_kernel<<<g1b + fb, 256, 0, stream>>>(x, Wt1, h8, N, g1b,
                                                    srcv, dstv, cursor, dinv, ecw, E);
    agg256_f8_kernel<<<(N + 3) / 4, 256, 0, stream>>>(h8, rp, ecw, dinv, b1, hB, N);

    // Layer 2: h2 = a1 @ W2 (64-row panels) ; fused a2 = relu(agg+b2), z = a2 @ W3
    gemm_panel_kernel<unsigned short, 8, 4, 2, 4><<<(N + 63) / 64, 256, 0, stream>>>(hB, Wt2, h2, N);
    agg128_w3_kernel<<<(N + 3) / 4, 256, 0, stream>>>(h2, rp, ecw, dinv, b2, W3, zbuf, N);

    // Layer 3 aggregation + sigmoid (wave-parallel)
    agg3_kernel<<<(N + 3) / 4, 256, 0, stream>>>(zbuf, rp, ecw, dinv, b3, out, N);
}

// Round 11
// 421.002 us; speedup vs baseline: 1.1434x; 1.0179x over previous
//
#include <hip/hip_runtime.h>
#include <math.h>

typedef short s16x8 __attribute__((ext_vector_type(8)));
typedef __bf16 b16x8 __attribute__((ext_vector_type(8)));
typedef float f32x4 __attribute__((ext_vector_type(4)));
typedef float f32x2 __attribute__((ext_vector_type(2)));
typedef unsigned int u32x4 __attribute__((ext_vector_type(4)));
typedef unsigned int u32x2 __attribute__((ext_vector_type(2)));

__device__ inline short f2bf(float f) {
    unsigned u = __float_as_uint(f);
    unsigned r = u + 0x7FFFu + ((u >> 16) & 1u);   // RNE
    return (short)(r >> 16);
}
__device__ inline float bf2f(unsigned short u) {
    return __uint_as_float(((unsigned)u) << 16);
}

// ---------------- fused prep: count + make_wt1 + make_wt2 ----------------
// Wt chunk layout: [c = k0/32][b = n0/128][nt 0..7][lane 0..63][j 0..7]
//   value = W[c*32 + (lane>>4)*8 + j][b*128 + nt*16 + (lane&15)]

__device__ inline void make_wt_elem(const float* __restrict__ W, short* __restrict__ Wt,
                                    int K, int N, int idx) {
    int NB = N >> 7;
    int j = idx & 7;
    int l = (idx >> 3) & 63;
    int nt = (idx >> 9) & 7;
    int rest = idx >> 12;
    int b = rest % NB;
    int c = rest / NB;
    int k = c * 32 + (l >> 4) * 8 + j;
    int n = b * 128 + nt * 16 + (l & 15);
    Wt[idx] = f2bf(W[(size_t)k * N + n]);
}

__global__ void prep_kernel(const int* __restrict__ dst, int* __restrict__ cnt, int E,
                            const float* __restrict__ W1, short* __restrict__ Wt1,
                            const float* __restrict__ W2, short* __restrict__ Wt2,
                            int cb, int w1b) {
    int b = blockIdx.x;
    int tid = threadIdx.x;
    if (b < cb) {
        int e = b * 256 + tid;
        if (e < E) atomicAdd(&cnt[dst[e]], 1);
    } else if (b < cb + w1b) {
        int idx = (b - cb) * 256 + tid;
        make_wt_elem(W1, Wt1, 768, 256, idx);
    } else {
        int idx = (b - cb - w1b) * 256 + tid;
        make_wt_elem(W2, Wt2, 256, 128, idx);
    }
}

// ---------------- CSR scan chain ----------------

__global__ __launch_bounds__(1024) void blockscan_kernel(const int* __restrict__ cnt,
                                                         int* __restrict__ rp,
                                                         int* __restrict__ bsum, int n) {
    __shared__ int sdata[1024];
    int tid = threadIdx.x;
    int i = blockIdx.x * 1024 + tid;
    int v = (i < n) ? cnt[i] : 0;
    sdata[tid] = v;
    __syncthreads();
    for (int off = 1; off < 1024; off <<= 1) {
        int t = 0;
        if (tid >= off) t = sdata[tid - off];
        __syncthreads();
        sdata[tid] += t;
        __syncthreads();
    }
    if (i < n) rp[i] = sdata[tid] - v;       // local exclusive
    if (tid == 1023) bsum[blockIdx.x] = sdata[1023];
}

// fixup: inlines the bsum prefix (topscan) — one wave scans bsum[0..blockIdx.x-1]
// (<= 48 ints), broadcast via LDS.
__global__ __launch_bounds__(1024) void fixup_kernel(int* __restrict__ rp,
                                                     const int* __restrict__ bsum,
                                                     const int* __restrict__ cnt,
                                                     int* __restrict__ cursor,
                                                     float* __restrict__ dinv,
                                                     int n, int E) {
    __shared__ int carry_s;
    int tid = threadIdx.x;
    if (tid < 64) {
        int sum = 0;
        for (int i = tid; i < blockIdx.x; i += 64) sum += bsum[i];
        for (int off = 32; off > 0; off >>= 1) sum += __shfl_xor(sum, off, 64);
        if (tid == 0) carry_s = sum;
    }
    __syncthreads();
    int carry = carry_s;
    int i = blockIdx.x * 1024 + tid;
    if (i < n) {
        int r = rp[i] + carry;
        rp[i] = r;
        cursor[i] = r;
        dinv[i] = rsqrtf((float)cnt[i] + 1.0f);
    }
    if (i == 0) rp[n] = E;
}

// ---------------- fused GEMM1 + fill ----------------
// Blocks [0, G1B): round-2 champion gemm1 — 32 rows x 256 cols, 48 KB frag-ready LDS.
// Blocks [G1B, G1B+FB): fill — CSR edge scatter (packed int2 {src, w} records).
// Data-independent roles; fill's latency-bound scatter hides under gemm1.

__global__ __launch_bounds__(256, 3) void gemm1_fill_kernel(
        const float* __restrict__ x, const short* __restrict__ Wt,
        unsigned char* __restrict__ h8, int M, int G1B,
        const int* __restrict__ src, const int* __restrict__ dst,
        int* __restrict__ cursor, const float* __restrict__ dinv,
        int2* __restrict__ ecw, int E) {
    constexpr int KC = 24;                     // 768 / 32
    constexpr int RT = 2;                      // row-tiles -> 32 rows per block
    constexpr int O = KC * 4;                  // 96 octets (8 k-elems) per row
    constexpr int F = KC * RT * 64 / 256;      // 12 frags staged per thread

    __shared__ s16x8 As[KC * RT * 64];         // 48 KB bf16, fragment-ready

    const int tid = threadIdx.x;

    if (blockIdx.x >= G1B) {                   // ---- fill role ----
        int e = (blockIdx.x - G1B) * 256 + tid;
        if (e < E) {
            int d = dst[e];
            int s = src[e];
            int p = atomicAdd(&cursor[d], 1);
            ecw[p] = make_int2(s, __float_as_int(dinv[s] * dinv[d]));
        }
        return;
    }

    // ---- gemm1 role ----
    const int m0 = blockIdx.x * (RT * 16);

    // stage: load fp32 pairs, truncation-pack to bf16
    s16x8 v[F];
#pragma unroll
    for (int i = 0; i < F; ++i) {
        int idx = i * 256 + tid;
        int r = idx / O;
        int o = idx - r * O;
        int row = m0 + r;
        if (row >= M) row = M - 1;
        const float4* fp = (const float4*)(x + (size_t)row * 768 + o * 8);
        float4 f0 = fp[0];
        float4 f1 = fp[1];
        u32x4 pk;
        pk.x = (__float_as_uint(f0.x) >> 16) | (__float_as_uint(f0.y) & 0xFFFF0000u);
        pk.y = (__float_as_uint(f0.z) >> 16) | (__float_as_uint(f0.w) & 0xFFFF0000u);
        pk.z = (__float_as_uint(f1.x) >> 16) | (__float_as_uint(f1.y) & 0xFFFF0000u);
        pk.w = (__float_as_uint(f1.z) >> 16) | (__float_as_uint(f1.w) & 0xFFFF0000u);
        v[i] = __builtin_bit_cast(s16x8, pk);
    }
#pragma unroll
    for (int i = 0; i < F; ++i) {
        int idx = i * 256 + tid;
        int r = idx / O;
        int o = idx - r * O;
        int c = o >> 2, q = o & 3;
        int slot = q * 16 + (((r & 15) + q + ((c & 3) << 2)) & 15);
        As[(c * RT + (r >> 4)) * 64 + slot] = v[i];
    }
    __syncthreads();

    const int lane = tid & 63;
    const int wave = tid >> 6;
    const int b128 = wave >> 1;                // 128-col B block
    const int nt0 = (wave & 1) * 4;            // first 16-col tile inside it
    const int q = lane >> 4;
    const int rl = lane & 15;
    const s16x8* wt = (const s16x8*)Wt;

    f32x4 acc[RT][4];
#pragma unroll
    for (int i = 0; i < RT; ++i)
#pragma unroll
        for (int j = 0; j < 4; ++j)
            acc[i][j] = (f32x4){0.f, 0.f, 0.f, 0.f};

#pragma unroll 4
    for (int c = 0; c < KC; ++c) {
        int slot = q * 16 + ((rl + q + ((c & 3) << 2)) & 15);
        b16x8 areg[RT], breg[4];
#pragma unroll
        for (int i = 0; i < RT; ++i)
            areg[i] = __builtin_bit_cast(b16x8, As[(c * RT + i) * 64 + slot]);
        size_t bb = (size_t)(c * 2 + b128) * 512 + nt0 * 64 + lane;
#pragma unroll
        for (int j = 0; j < 4; ++j)
            breg[j] = __builtin_bit_cast(b16x8, wt[bb + j * 64]);
#pragma unroll
        for (int i = 0; i < RT; ++i)
#pragma unroll
            for (int j = 0; j < 4; ++j)
                acc[i][j] = __builtin_amdgcn_mfma_f32_16x16x32_bf16(areg[i], breg[j], acc[i][j], 0, 0, 0);
    }

    const int quad = lane >> 4;
    const int nl = lane & 15;
#pragma unroll
    for (int i = 0; i < RT; ++i) {
        int rbase = m0 + i * 16 + quad * 4;
#pragma unroll
        for (int j = 0; j < 4; ++j) {
            int col = wave * 64 + j * 16 + nl;
#pragma unroll
            for (int r = 0; r < 4; ++r) {
                int row = rbase + r;
                if (row < M) {
                    unsigned u = __builtin_amdgcn_cvt_pk_fp8_f32(acc[i][j][r], acc[i][j][r], 0, false);
                    h8[(size_t)row * 256 + col] = (unsigned char)(u & 0xFF);
                }
            }
        }
    }
}

// ---------------- row-panel GEMM (bf16 A, layer 2) ----------------
// F8 template flag: epilogue emits fp8 e4m3 bytes (verified passing in r5).

template<typename AT, int KC, int RT, int CW, int MINW, bool F8>
__global__ __launch_bounds__(256, MINW) void gemm_panel_kernel(
        const AT* __restrict__ A, const short* __restrict__ Wt,
        void* __restrict__ Cb, int M) {
    constexpr int K = KC * 32;
    constexpr int O = KC * 4;              // 8-elem octets per row
    constexpr int F = KC * RT / 4;         // frags staged per thread
    constexpr int NCOLS = CW * 64;
    constexpr int NB = NCOLS >> 7;         // 128-col B blocks
    constexpr int MT = RT * CW / 4;        // m-tiles per wave

    __shared__ s16x8 As[KC * RT * 64];

    const int tid = threadIdx.x;
    const int m0 = blockIdx.x * (RT * 16);

    s16x8 v[F];
#pragma unroll
    for (int i = 0; i < F; ++i) {
        int idx = i * 256 + tid;
        int r = idx / O;
        int o = idx - r * O;
        int row = m0 + r;
        if (row >= M) row = M - 1;
        v[i] = *(const s16x8*)((const unsigned short*)A + (size_t)row * K + o * 8);
    }
#pragma unroll
    for (int i = 0; i < F; ++i) {
        int idx = i * 256 + tid;
        int r = idx / O;
        int o = idx - r * O;
        int c = o >> 2, q = o & 3;
        int slot = q * 16 + (((r & 15) + q + ((c & 3) << 2)) & 15);
        As[(c * RT + (r >> 4)) * 64 + slot] = v[i];
    }
    __syncthreads();

    const int lane = tid & 63;
    const int wave = tid >> 6;
    const int cw_i = wave % CW;
    const int rg = wave / CW;
    const int mtb = rg * MT;
    const int b128 = (cw_i * 64) >> 7;
    const int nt0 = (cw_i * 4) & 7;
    const int q = lane >> 4;
    const int rl = lane & 15;
    const s16x8* wt = (const s16x8*)Wt;

    f32x4 acc[MT][4];
#pragma unroll
    for (int i = 0; i < MT; ++i)
#pragma unroll
        for (int j = 0; j < 4; ++j)
            acc[i][j] = (f32x4){0.f, 0.f, 0.f, 0.f};

#pragma unroll 4
    for (int c = 0; c < KC; ++c) {
        int slot = q * 16 + ((rl + q + ((c & 3) << 2)) & 15);
        b16x8 areg[MT], breg[4];
#pragma unroll
        for (int i = 0; i < MT; ++i)
            areg[i] = __builtin_bit_cast(b16x8, As[(c * RT + mtb + i) * 64 + slot]);
        size_t bb = (size_t)(c * NB + b128) * 512 + nt0 * 64 + lane;
#pragma unroll
        for (int j = 0; j < 4; ++j)
            breg[j] = __builtin_bit_cast(b16x8, wt[bb + j * 64]);
#pragma unroll
        for (int i = 0; i < MT; ++i)
#pragma unroll
            for (int j = 0; j < 4; ++j)
                acc[i][j] = __builtin_amdgcn_mfma_f32_16x16x32_bf16(areg[i], breg[j], acc[i][j], 0, 0, 0);
    }

    const int quad = lane >> 4;
    const int nl = lane & 15;
#pragma unroll
    for (int i = 0; i < MT; ++i) {
        int rbase = m0 + (mtb + i) * 16 + quad * 4;
#pragma unroll
        for (int j = 0; j < 4; ++j) {
            int col = cw_i * 64 + j * 16 + nl;
#pragma unroll
            for (int rr = 0; rr < 4; ++rr) {
                int row = rbase + rr;
                if (row < M) {
                    if (F8) {
                        unsigned u = __builtin_amdgcn_cvt_pk_fp8_f32(acc[i][j][rr], acc[i][j][rr], 0, false);
                        ((unsigned char*)Cb)[(size_t)row * NCOLS + col] = (unsigned char)(u & 0xFF);
                    } else {
                        ((unsigned short*)Cb)[(size_t)row * NCOLS + col] = (unsigned short)f2bf(acc[i][j][rr]);
                    }
                }
            }
        }
    }
}

// ---------------- aggregation ----------------
// 4-edge-parallel gather. Wave per node; lane = (eg = edge slot 0..3, ch = chunk).
// Edge records packed (int2 {src, weight}); inner loop unroll 4.
// Cross-lane xor(16/32) reduction combines the 4 edge slots once per node.

__global__ __launch_bounds__(256) void agg256_f8_kernel(const unsigned char* __restrict__ h8,
                                                        const int* __restrict__ rp,
                                                        const int2* __restrict__ ecw,
                                                        const float* __restrict__ dinv,
                                                        const float* __restrict__ bias,
                                                        unsigned short* __restrict__ out, int n) {
    int node = blockIdx.x * 4 + (threadIdx.x >> 6);
    int lane = threadIdx.x & 63;
    if (node >= n) return;
    const int eg = lane >> 4;                    // edge slot 0..3
    const int ch = lane & 15;                    // 16-channel chunk
    float di = dinv[node];

    float acc[16];
    {
        u32x4 v = *(const u32x4*)(h8 + (size_t)node * 256 + ch * 16);
        float ws = (eg == 0) ? di * di : 0.f;    // self term counted once
#pragma unroll
        for (int u = 0; u < 4; ++u) {
            f32x2 lo = __builtin_amdgcn_cvt_pk_f32_fp8(v[u], false);
            f32x2 hi = __builtin_amdgcn_cvt_pk_f32_fp8(v[u], true);
            acc[u * 4 + 0] = ws * lo.x; acc[u * 4 + 1] = ws * lo.y;
            acc[u * 4 + 2] = ws * hi.x; acc[u * 4 + 3] = ws * hi.y;
        }
    }

    int e0 = rp[node], e1 = rp[node + 1];
    for (int base = e0; base < e1; base += 64) {
        int idx = base + lane;
        int2 er = (idx < e1) ? ecw[idx] : make_int2(0, 0);
        int sb = er.x;
        float wb = __int_as_float(er.y);
        int cnt = e1 - base; if (cnt > 64) cnt = 64;
#pragma unroll 4
        for (int i = 0; i < cnt; i += 4) {
            int s = __shfl(sb, i + eg, 64);       // i+eg <= 63 always (i step 4, i<=60)
            float w = __shfl(wb, i + eg, 64);
            u32x4 v = *(const u32x4*)(h8 + (size_t)s * 256 + ch * 16);
#pragma unroll
            for (int u = 0; u < 4; ++u) {
                f32x2 lo = __builtin_amdgcn_cvt_pk_f32_fp8(v[u], false);
                f32x2 hi = __builtin_amdgcn_cvt_pk_f32_fp8(v[u], true);
                acc[u * 4 + 0] += w * lo.x; acc[u * 4 + 1] += w * lo.y;
                acc[u * 4 + 2] += w * hi.x; acc[u * 4 + 3] += w * hi.y;
            }
        }
    }

    // combine the 4 edge slots
#pragma unroll
    for (int k = 0; k < 16; ++k) {
        acc[k] += __shfl_xor(acc[k], 16, 64);
        acc[k] += __shfl_xor(acc[k], 32, 64);
    }

    // bias + relu + pack to bf16; lanes eg 0/1 store the two 16B halves of the 32B chunk
    unsigned pk[8];
#pragma unroll
    for (int k = 0; k < 8; ++k) {
        float b0 = bias[ch * 16 + 2 * k];
        float b1 = bias[ch * 16 + 2 * k + 1];
        float a0 = fmaxf(acc[2 * k] + b0, 0.f);
        float a1 = fmaxf(acc[2 * k + 1] + b1, 0.f);
        pk[k] = ((unsigned)(unsigned short)f2bf(a0)) | (((unsigned)(unsigned short)f2bf(a1)) << 16);
    }
    if (eg < 2) {
        u32x4 ov;
        ov.x = pk[eg * 4 + 0]; ov.y = pk[eg * 4 + 1];
        ov.z = pk[eg * 4 + 2]; ov.w = pk[eg * 4 + 3];
        *(u32x4*)((char*)out + (size_t)node * 512 + ch * 32 + eg * 16) = ov;
    }
}

// Layer 2 fused with W3: v4 — h2 is fp8 e4m3 (128 B rows), SAME 4-edge-parallel wave
// structure as the champion (eg = lane>>4, ch = lane&15), lane loads 8 B (dwordx2)
// per row instead of 16 B. Gather traffic halves vs bf16. a2 = relu(agg+b2);
// z = a2 @ W3 (128x2) via per-lane partials + shuffle reduce.
__global__ __launch_bounds__(256) void agg128_w3_kernel(const unsigned char* __restrict__ h,
                                                        const int* __restrict__ rp,
                                                        const int2* __restrict__ ecw,
                                                        const float* __restrict__ dinv,
                                                        const float* __restrict__ b2,
                                                        const float* __restrict__ W3,
                                                        float* __restrict__ z, int n) {
    int node = blockIdx.x * 4 + (threadIdx.x >> 6);
    int lane = threadIdx.x & 63;
    if (node >= n) return;
    const int eg = lane >> 4;                    // edge slot 0..3
    const int ch = lane & 15;                    // 8B chunk (8 fp8 channels)
    float di = dinv[node];

    float acc[8];
    {
        u32x2 v = *(const u32x2*)(h + (size_t)node * 128 + ch * 8);
        float ws = (eg == 0) ? di * di : 0.f;
        f32x2 l0 = __builtin_amdgcn_cvt_pk_f32_fp8(v.x, false);
        f32x2 h0 = __builtin_amdgcn_cvt_pk_f32_fp8(v.x, true);
        f32x2 l1 = __builtin_amdgcn_cvt_pk_f32_fp8(v.y, false);
        f32x2 h1 = __builtin_amdgcn_cvt_pk_f32_fp8(v.y, true);
        acc[0] = ws * l0.x; acc[1] = ws * l0.y; acc[2] = ws * h0.x; acc[3] = ws * h0.y;
        acc[4] = ws * l1.x; acc[5] = ws * l1.y; acc[6] = ws * h1.x; acc[7] = ws * h1.y;
    }

    int e0 = rp[node], e1 = rp[node + 1];
    for (int base = e0; base < e1; base += 64) {
        int idx = base + lane;
        int2 er = (idx < e1) ? ecw[idx] : make_int2(0, 0);
        int sb = er.x;
        float wb = __int_as_float(er.y);
        int cnt = e1 - base; if (cnt > 64) cnt = 64;
#pragma unroll 4
        for (int i = 0; i < cnt; i += 4) {
            int s = __shfl(sb, i + eg, 64);
            float w = __shfl(wb, i + eg, 64);
            u32x2 v = *(const u32x2*)(h + (size_t)s * 128 + ch * 8);
            f32x2 l0 = __builtin_amdgcn_cvt_pk_f32_fp8(v.x, false);
            f32x2 h0 = __builtin_amdgcn_cvt_pk_f32_fp8(v.x, true);
            f32x2 l1 = __builtin_amdgcn_cvt_pk_f32_fp8(v.y, false);
            f32x2 h1 = __builtin_amdgcn_cvt_pk_f32_fp8(v.y, true);
            acc[0] += w * l0.x; acc[1] += w * l0.y; acc[2] += w * h0.x; acc[3] += w * h0.y;
            acc[4] += w * l1.x; acc[5] += w * l1.y; acc[6] += w * h1.x; acc[7] += w * h1.y;
        }
    }

#pragma unroll
    for (int k = 0; k < 8; ++k) {
        acc[k] += __shfl_xor(acc[k], 16, 64);
        acc[k] += __shfl_xor(acc[k], 32, 64);
    }

    // a2 = relu(acc + b2); z partials over this lane's 8 channels
    float z0 = 0.f, z1 = 0.f;
#pragma unroll
    for (int k = 0; k < 8; ++k) {
        float a = fmaxf(acc[k] + b2[ch * 8 + k], 0.f);
        z0 += a * W3[(ch * 8 + k) * 2];
        z1 += a * W3[(ch * 8 + k) * 2 + 1];
    }
    // reduce over the 16 ch groups (all eg groups hold identical values)
    for (int off = 8; off > 0; off >>= 1) {
        z0 += __shfl_xor(z0, off, 64);
        z1 += __shfl_xor(z1, off, 64);
    }
    if (lane == 0) {
        z[2 * (size_t)node] = z0;
        z[2 * (size_t)node + 1] = z1;
    }
}

// agg3: wave per node, 64-lane edge-parallel gather of z pairs + xor-tree reduce.
// Packed edge records (one 8B load per lane).
__global__ __launch_bounds__(256) void agg3_kernel(const float* __restrict__ z,
                                                   const int* __restrict__ rp,
                                                   const int2* __restrict__ ecw,
                                                   const float* __restrict__ dinv,
                                                   const float* __restrict__ bias,
                                                   float* __restrict__ out, int n) {
    int node = blockIdx.x * 4 + (threadIdx.x >> 6);
    int lane = threadIdx.x & 63;
    if (node >= n) return;
    float a0 = 0.f, a1 = 0.f;
    int e0 = rp[node], e1 = rp[node + 1];
    for (int idx = e0 + lane; idx < e1; idx += 64) {
        int2 er = ecw[idx];
        float w = __int_as_float(er.y);
        float2 zz = *(const float2*)(z + 2 * (size_t)er.x);
        a0 += w * zz.x;
        a1 += w * zz.y;
    }
    for (int off = 32; off > 0; off >>= 1) {
        a0 += __shfl_xor(a0, off, 64);
        a1 += __shfl_xor(a1, off, 64);
    }
    if (lane == 0) {
        float di = dinv[node];
        float2 zn = *(const float2*)(z + 2 * (size_t)node);
        a0 += di * di * zn.x + bias[0];
        a1 += di * di * zn.y + bias[1];
        out[2 * (size_t)node]     = 1.f / (1.f + __expf(-a0));
        out[2 * (size_t)node + 1] = 1.f / (1.f + __expf(-a1));
    }
}

// ---------------- launch ----------------

extern "C" void kernel_launch(void* const* d_in, const int* in_sizes, int n_in,
                              void* d_out, int out_size, void* d_ws, size_t ws_size,
                              hipStream_t stream) {
    const float* x  = (const float*)d_in[0];
    const int*   ei = (const int*)d_in[1];
    const float* W1 = (const float*)d_in[2];
    const float* b1 = (const float*)d_in[3];
    const float* W2 = (const float*)d_in[4];
    const float* b2 = (const float*)d_in[5];
    const float* W3 = (const float*)d_in[6];
    const float* b3 = (const float*)d_in[7];
    float* out = (float*)d_out;

    const int E  = in_sizes[1] / 2;
    const int C1 = in_sizes[3];              // 256
    const int C2 = in_sizes[5];              // 128
    const int K1 = in_sizes[2] / C1;         // 768
    const int N  = in_sizes[0] / K1;         // 50000

    const int* srcv = ei;
    const int* dstv = ei + E;

    char* p = (char*)d_ws;
    auto carve = [&](size_t bytes) {
        char* r = p;
        p += (bytes + 255) & ~(size_t)255;
        return r;
    };
    int*   cnt    = (int*)carve((size_t)N * 4);
    int*   rp     = (int*)carve((size_t)(N + 1) * 4);
    int*   cursor = (int*)carve((size_t)N * 4);
    float* dinv   = (float*)carve((size_t)N * 4);
    int*   bsum   = (int*)carve(1024 * 4);
    int2*  ecw    = (int2*)carve((size_t)E * 8);                     // packed {src, w}
    short* Wt1    = (short*)carve((size_t)K1 * C1 * 2);
    short* Wt2    = (short*)carve((size_t)C1 * C2 * 2);
    unsigned char* h8 = (unsigned char*)carve((size_t)N * C1);       // fp8 h1
    unsigned short* hB = (unsigned short*)carve((size_t)N * C1 * 2); // bf16 a1
    unsigned char* h2 = (unsigned char*)carve((size_t)N * C2);       // fp8 h2
    float* zbuf   = (float*)carve((size_t)N * 2 * 4);

    const int nb = (N + 1023) / 1024;
    const int cb = (E + 255) / 256;
    const int w1b = (K1 * C1) / 256;         // 768
    const int w2b = (C1 * C2) / 256;         // 128
    const int g1b = (N + 31) / 32;           // gemm1 blocks
    const int fb  = (E + 255) / 256;         // fill blocks

    // CSR + weight prep (fused)
    hipMemsetAsync(cnt, 0, (size_t)N * 4, stream);
    prep_kernel<<<cb + w1b + w2b, 256, 0, stream>>>(dstv, cnt, E, W1, Wt1, W2, Wt2, cb, w1b);
    blockscan_kernel<<<nb, 1024, 0, stream>>>(cnt, rp, bsum, N);
    fixup_kernel<<<nb, 1024, 0, stream>>>(rp, bsum, cnt, cursor, dinv, N, E);

    // Layer 1 GEMM fused with CSR fill (independent roles, one launch):
    // h1 = x @ W1 (fp8 out) ; ecw/cursor scatter hides under gemm1.
    gemm1_fill_kernel<<<g1b + fb, 256, 0, stream>>>(x, Wt1, h8, N, g1b,
                                                    srcv, dstv, cursor, dinv, ecw, E);
    agg256_f8_kernel<<<(N + 3) / 4, 256, 0, stream>>>(h8, rp, ecw, dinv, b1, hB, N);

    // Layer 2: h2 = a1 @ W2 (64-row panels, fp8 out) ; fused a2 = relu(agg+b2), z = a2 @ W3
    gemm_panel_kernel<unsigned short, 8, 4, 2, 4, true><<<(N + 63) / 64, 256, 0, stream>>>(hB, Wt2, h2, N);
    agg128_w3_kernel<<<(N + 3) / 4, 256, 0, stream>>>(h2, rp, ecw, dinv, b2, W3, zbuf, N);

    // Layer 3 aggregation + sigmoid (wave-parallel)
    agg3_kernel<<<(N + 3) / 4, 256, 0, stream>>>(zbuf, rp, ecw, dinv, b3, out, N);
}

// Round 12
// 404.196 us; speedup vs baseline: 1.1910x; 1.0416x over previous
//
#include <hip/hip_runtime.h>
#include <math.h>

typedef short s16x8 __attribute__((ext_vector_type(8)));
typedef __bf16 b16x8 __attribute__((ext_vector_type(8)));
typedef float f32x4 __attribute__((ext_vector_type(4)));
typedef float f32x2 __attribute__((ext_vector_type(2)));
typedef unsigned int u32x4 __attribute__((ext_vector_type(4)));
typedef unsigned int u32x2 __attribute__((ext_vector_type(2)));

__device__ inline short f2bf(float f) {
    unsigned u = __float_as_uint(f);
    unsigned r = u + 0x7FFFu + ((u >> 16) & 1u);   // RNE
    return (short)(r >> 16);
}
__device__ inline float bf2f(unsigned short u) {
    return __uint_as_float(((unsigned)u) << 16);
}

// ---------------- fused prep: count + make_wt1 + make_wt2 ----------------
// Wt chunk layout: [c = k0/32][b = n0/128][nt 0..7][lane 0..63][j 0..7]
//   value = W[c*32 + (lane>>4)*8 + j][b*128 + nt*16 + (lane&15)]

__device__ inline void make_wt_elem(const float* __restrict__ W, short* __restrict__ Wt,
                                    int K, int N, int idx) {
    int NB = N >> 7;
    int j = idx & 7;
    int l = (idx >> 3) & 63;
    int nt = (idx >> 9) & 7;
    int rest = idx >> 12;
    int b = rest % NB;
    int c = rest / NB;
    int k = c * 32 + (l >> 4) * 8 + j;
    int n = b * 128 + nt * 16 + (l & 15);
    Wt[idx] = f2bf(W[(size_t)k * N + n]);
}

__global__ void prep_kernel(const int* __restrict__ dst, int* __restrict__ cnt, int E,
                            const float* __restrict__ W1, short* __restrict__ Wt1,
                            const float* __restrict__ W2, short* __restrict__ Wt2,
                            int cb, int w1b) {
    int b = blockIdx.x;
    int tid = threadIdx.x;
    if (b < cb) {
        int e = b * 256 + tid;
        if (e < E) atomicAdd(&cnt[dst[e]], 1);
    } else if (b < cb + w1b) {
        int idx = (b - cb) * 256 + tid;
        make_wt_elem(W1, Wt1, 768, 256, idx);
    } else {
        int idx = (b - cb - w1b) * 256 + tid;
        make_wt_elem(W2, Wt2, 256, 128, idx);
    }
}

// ---------------- CSR scan chain ----------------

__global__ __launch_bounds__(1024) void blockscan_kernel(const int* __restrict__ cnt,
                                                         int* __restrict__ rp,
                                                         int* __restrict__ bsum, int n) {
    __shared__ int sdata[1024];
    int tid = threadIdx.x;
    int i = blockIdx.x * 1024 + tid;
    int v = (i < n) ? cnt[i] : 0;
    sdata[tid] = v;
    __syncthreads();
    for (int off = 1; off < 1024; off <<= 1) {
        int t = 0;
        if (tid >= off) t = sdata[tid - off];
        __syncthreads();
        sdata[tid] += t;
        __syncthreads();
    }
    if (i < n) rp[i] = sdata[tid] - v;       // local exclusive
    if (tid == 1023) bsum[blockIdx.x] = sdata[1023];
}

// fixup: inlines the bsum prefix (topscan) — one wave scans bsum[0..blockIdx.x-1]
// (<= 48 ints), broadcast via LDS.
__global__ __launch_bounds__(1024) void fixup_kernel(int* __restrict__ rp,
                                                     const int* __restrict__ bsum,
                                                     const int* __restrict__ cnt,
                                                     int* __restrict__ cursor,
                                                     float* __restrict__ dinv,
                                                     int n, int E) {
    __shared__ int carry_s;
    int tid = threadIdx.x;
    if (tid < 64) {
        int sum = 0;
        for (int i = tid; i < blockIdx.x; i += 64) sum += bsum[i];
        for (int off = 32; off > 0; off >>= 1) sum += __shfl_xor(sum, off, 64);
        if (tid == 0) carry_s = sum;
    }
    __syncthreads();
    int carry = carry_s;
    int i = blockIdx.x * 1024 + tid;
    if (i < n) {
        int r = rp[i] + carry;
        rp[i] = r;
        cursor[i] = r;
        dinv[i] = rsqrtf((float)cnt[i] + 1.0f);
    }
    if (i == 0) rp[n] = E;
}

// ---------------- fused GEMM1 + fill (interleaved roles) ----------------
// v2: roles interleaved by block index via Bresenham proportional mapping
// (fid(i) = floor(i*FB/total); block is fill iff fid(i+1) > fid(i)), so fill's
// latency-bound scatter co-resides with gemm1's MFMA blocks for the whole dispatch
// instead of running as a ~30 us tail after gemm1 drains (r10/r11: 117 us ≈ 88 + tail).
// Mapping is bijective onto [0,FB) fill ids and [0,G1B) gemm ids.

__global__ __launch_bounds__(256, 3) void gemm1_fill_kernel(
        const float* __restrict__ x, const short* __restrict__ Wt,
        unsigned char* __restrict__ h8, int M, int G1B, int FB,
        const int* __restrict__ src, const int* __restrict__ dst,
        int* __restrict__ cursor, const float* __restrict__ dinv,
        int2* __restrict__ ecw, int E) {
    constexpr int KC = 24;                     // 768 / 32
    constexpr int RT = 2;                      // row-tiles -> 32 rows per block
    constexpr int O = KC * 4;                  // 96 octets (8 k-elems) per row
    constexpr int F = KC * RT * 64 / 256;      // 12 frags staged per thread

    __shared__ s16x8 As[KC * RT * 64];         // 48 KB bf16, fragment-ready

    const int tid = threadIdx.x;
    const int total = G1B + FB;
    const long long bi = (long long)blockIdx.x;
    const int fid  = (int)(bi * FB / total);
    const int fid1 = (int)((bi + 1) * FB / total);

    if (fid1 > fid) {                          // ---- fill role ----
        int e = fid * 256 + tid;
        if (e < E) {
            int d = dst[e];
            int s = src[e];
            int p = atomicAdd(&cursor[d], 1);
            ecw[p] = make_int2(s, __float_as_int(dinv[s] * dinv[d]));
        }
        return;
    }
    const int gid = blockIdx.x - fid;          // gemm1 block id, 0..G1B-1

    // ---- gemm1 role ----
    const int m0 = gid * (RT * 16);

    // stage: load fp32 pairs, truncation-pack to bf16
    s16x8 v[F];
#pragma unroll
    for (int i = 0; i < F; ++i) {
        int idx = i * 256 + tid;
        int r = idx / O;
        int o = idx - r * O;
        int row = m0 + r;
        if (row >= M) row = M - 1;
        const float4* fp = (const float4*)(x + (size_t)row * 768 + o * 8);
        float4 f0 = fp[0];
        float4 f1 = fp[1];
        u32x4 pk;
        pk.x = (__float_as_uint(f0.x) >> 16) | (__float_as_uint(f0.y) & 0xFFFF0000u);
        pk.y = (__float_as_uint(f0.z) >> 16) | (__float_as_uint(f0.w) & 0xFFFF0000u);
        pk.z = (__float_as_uint(f1.x) >> 16) | (__float_as_uint(f1.y) & 0xFFFF0000u);
        pk.w = (__float_as_uint(f1.z) >> 16) | (__float_as_uint(f1.w) & 0xFFFF0000u);
        v[i] = __builtin_bit_cast(s16x8, pk);
    }
#pragma unroll
    for (int i = 0; i < F; ++i) {
        int idx = i * 256 + tid;
        int r = idx / O;
        int o = idx - r * O;
        int c = o >> 2, q = o & 3;
        int slot = q * 16 + (((r & 15) + q + ((c & 3) << 2)) & 15);
        As[(c * RT + (r >> 4)) * 64 + slot] = v[i];
    }
    __syncthreads();

    const int lane = tid & 63;
    const int wave = tid >> 6;
    const int b128 = wave >> 1;                // 128-col B block
    const int nt0 = (wave & 1) * 4;            // first 16-col tile inside it
    const int q = lane >> 4;
    const int rl = lane & 15;
    const s16x8* wt = (const s16x8*)Wt;

    f32x4 acc[RT][4];
#pragma unroll
    for (int i = 0; i < RT; ++i)
#pragma unroll
        for (int j = 0; j < 4; ++j)
            acc[i][j] = (f32x4){0.f, 0.f, 0.f, 0.f};

#pragma unroll 4
    for (int c = 0; c < KC; ++c) {
        int slot = q * 16 + ((rl + q + ((c & 3) << 2)) & 15);
        b16x8 areg[RT], breg[4];
#pragma unroll
        for (int i = 0; i < RT; ++i)
            areg[i] = __builtin_bit_cast(b16x8, As[(c * RT + i) * 64 + slot]);
        size_t bb = (size_t)(c * 2 + b128) * 512 + nt0 * 64 + lane;
#pragma unroll
        for (int j = 0; j < 4; ++j)
            breg[j] = __builtin_bit_cast(b16x8, wt[bb + j * 64]);
#pragma unroll
        for (int i = 0; i < RT; ++i)
#pragma unroll
            for (int j = 0; j < 4; ++j)
                acc[i][j] = __builtin_amdgcn_mfma_f32_16x16x32_bf16(areg[i], breg[j], acc[i][j], 0, 0, 0);
    }

    const int quad = lane >> 4;
    const int nl = lane & 15;
#pragma unroll
    for (int i = 0; i < RT; ++i) {
        int rbase = m0 + i * 16 + quad * 4;
#pragma unroll
        for (int j = 0; j < 4; ++j) {
            int col = wave * 64 + j * 16 + nl;
#pragma unroll
            for (int r = 0; r < 4; ++r) {
                int row = rbase + r;
                if (row < M) {
                    unsigned u = __builtin_amdgcn_cvt_pk_fp8_f32(acc[i][j][r], acc[i][j][r], 0, false);
                    h8[(size_t)row * 256 + col] = (unsigned char)(u & 0xFF);
                }
            }
        }
    }
}

// ---------------- row-panel GEMM (bf16 A, layer 2) ----------------
// F8 template flag: epilogue emits fp8 e4m3 bytes (verified passing in r5/r11).

template<typename AT, int KC, int RT, int CW, int MINW, bool F8>
__global__ __launch_bounds__(256, MINW) void gemm_panel_kernel(
        const AT* __restrict__ A, const short* __restrict__ Wt,
        void* __restrict__ Cb, int M) {
    constexpr int K = KC * 32;
    constexpr int O = KC * 4;              // 8-elem octets per row
    constexpr int F = KC * RT / 4;         // frags staged per thread
    constexpr int NCOLS = CW * 64;
    constexpr int NB = NCOLS >> 7;         // 128-col B blocks
    constexpr int MT = RT * CW / 4;        // m-tiles per wave

    __shared__ s16x8 As[KC * RT * 64];

    const int tid = threadIdx.x;
    const int m0 = blockIdx.x * (RT * 16);

    s16x8 v[F];
#pragma unroll
    for (int i = 0; i < F; ++i) {
        int idx = i * 256 + tid;
        int r = idx / O;
        int o = idx - r * O;
        int row = m0 + r;
        if (row >= M) row = M - 1;
        v[i] = *(const s16x8*)((const unsigned short*)A + (size_t)row * K + o * 8);
    }
#pragma unroll
    for (int i = 0; i < F; ++i) {
        int idx = i * 256 + tid;
        int r = idx / O;
        int o = idx - r * O;
        int c = o >> 2, q = o & 3;
        int slot = q * 16 + (((r & 15) + q + ((c & 3) << 2)) & 15);
        As[(c * RT + (r >> 4)) * 64 + slot] = v[i];
    }
    __syncthreads();

    const int lane = tid & 63;
    const int wave = tid >> 6;
    const int cw_i = wave % CW;
    const int rg = wave / CW;
    const int mtb = rg * MT;
    const int b128 = (cw_i * 64) >> 7;
    const int nt0 = (cw_i * 4) & 7;
    const int q = lane >> 4;
    const int rl = lane & 15;
    const s16x8* wt = (const s16x8*)Wt;

    f32x4 acc[MT][4];
#pragma unroll
    for (int i = 0; i < MT; ++i)
#pragma unroll
        for (int j = 0; j < 4; ++j)
            acc[i][j] = (f32x4){0.f, 0.f, 0.f, 0.f};

#pragma unroll 4
    for (int c = 0; c < KC; ++c) {
        int slot = q * 16 + ((rl + q + ((c & 3) << 2)) & 15);
        b16x8 areg[MT], breg[4];
#pragma unroll
        for (int i = 0; i < MT; ++i)
            areg[i] = __builtin_bit_cast(b16x8, As[(c * RT + mtb + i) * 64 + slot]);
        size_t bb = (size_t)(c * NB + b128) * 512 + nt0 * 64 + lane;
#pragma unroll
        for (int j = 0; j < 4; ++j)
            breg[j] = __builtin_bit_cast(b16x8, wt[bb + j * 64]);
#pragma unroll
        for (int i = 0; i < MT; ++i)
#pragma unroll
            for (int j = 0; j < 4; ++j)
                acc[i][j] = __builtin_amdgcn_mfma_f32_16x16x32_bf16(areg[i], breg[j], acc[i][j], 0, 0, 0);
    }

    const int quad = lane >> 4;
    const int nl = lane & 15;
#pragma unroll
    for (int i = 0; i < MT; ++i) {
        int rbase = m0 + (mtb + i) * 16 + quad * 4;
#pragma unroll
        for (int j = 0; j < 4; ++j) {
            int col = cw_i * 64 + j * 16 + nl;
#pragma unroll
            for (int rr = 0; rr < 4; ++rr) {
                int row = rbase + rr;
                if (row < M) {
                    if (F8) {
                        unsigned u = __builtin_amdgcn_cvt_pk_fp8_f32(acc[i][j][rr], acc[i][j][rr], 0, false);
                        ((unsigned char*)Cb)[(size_t)row * NCOLS + col] = (unsigned char)(u & 0xFF);
                    } else {
                        ((unsigned short*)Cb)[(size_t)row * NCOLS + col] = (unsigned short)f2bf(acc[i][j][rr]);
                    }
                }
            }
        }
    }
}

// ---------------- aggregation ----------------
// 4-edge-parallel gather. Wave per node; lane = (eg = edge slot 0..3, ch = chunk).
// Edge records packed (int2 {src, weight}); inner loop unroll 4.
// Cross-lane xor(16/32) reduction combines the 4 edge slots once per node.

__global__ __launch_bounds__(256) void agg256_f8_kernel(const unsigned char* __restrict__ h8,
                                                        const int* __restrict__ rp,
                                                        const int2* __restrict__ ecw,
                                                        const float* __restrict__ dinv,
                                                        const float* __restrict__ bias,
                                                        unsigned short* __restrict__ out, int n) {
    int node = blockIdx.x * 4 + (threadIdx.x >> 6);
    int lane = threadIdx.x & 63;
    if (node >= n) return;
    const int eg = lane >> 4;                    // edge slot 0..3
    const int ch = lane & 15;                    // 16-channel chunk
    float di = dinv[node];

    float acc[16];
    {
        u32x4 v = *(const u32x4*)(h8 + (size_t)node * 256 + ch * 16);
        float ws = (eg == 0) ? di * di : 0.f;    // self term counted once
#pragma unroll
        for (int u = 0; u < 4; ++u) {
            f32x2 lo = __builtin_amdgcn_cvt_pk_f32_fp8(v[u], false);
            f32x2 hi = __builtin_amdgcn_cvt_pk_f32_fp8(v[u], true);
            acc[u * 4 + 0] = ws * lo.x; acc[u * 4 + 1] = ws * lo.y;
            acc[u * 4 + 2] = ws * hi.x; acc[u * 4 + 3] = ws * hi.y;
        }
    }

    int e0 = rp[node], e1 = rp[node + 1];
    for (int base = e0; base < e1; base += 64) {
        int idx = base + lane;
        int2 er = (idx < e1) ? ecw[idx] : make_int2(0, 0);
        int sb = er.x;
        float wb = __int_as_float(er.y);
        int cnt = e1 - base; if (cnt > 64) cnt = 64;
#pragma unroll 4
        for (int i = 0; i < cnt; i += 4) {
            int s = __shfl(sb, i + eg, 64);       // i+eg <= 63 always (i step 4, i<=60)
            float w = __shfl(wb, i + eg, 64);
            u32x4 v = *(const u32x4*)(h8 + (size_t)s * 256 + ch * 16);
#pragma unroll
            for (int u = 0; u < 4; ++u) {
                f32x2 lo = __builtin_amdgcn_cvt_pk_f32_fp8(v[u], false);
                f32x2 hi = __builtin_amdgcn_cvt_pk_f32_fp8(v[u], true);
                acc[u * 4 + 0] += w * lo.x; acc[u * 4 + 1] += w * lo.y;
                acc[u * 4 + 2] += w * hi.x; acc[u * 4 + 3] += w * hi.y;
            }
        }
    }

    // combine the 4 edge slots
#pragma unroll
    for (int k = 0; k < 16; ++k) {
        acc[k] += __shfl_xor(acc[k], 16, 64);
        acc[k] += __shfl_xor(acc[k], 32, 64);
    }

    // bias + relu + pack to bf16; lanes eg 0/1 store the two 16B halves of the 32B chunk
    unsigned pk[8];
#pragma unroll
    for (int k = 0; k < 8; ++k) {
        float b0 = bias[ch * 16 + 2 * k];
        float b1 = bias[ch * 16 + 2 * k + 1];
        float a0 = fmaxf(acc[2 * k] + b0, 0.f);
        float a1 = fmaxf(acc[2 * k + 1] + b1, 0.f);
        pk[k] = ((unsigned)(unsigned short)f2bf(a0)) | (((unsigned)(unsigned short)f2bf(a1)) << 16);
    }
    if (eg < 2) {
        u32x4 ov;
        ov.x = pk[eg * 4 + 0]; ov.y = pk[eg * 4 + 1];
        ov.z = pk[eg * 4 + 2]; ov.w = pk[eg * 4 + 3];
        *(u32x4*)((char*)out + (size_t)node * 512 + ch * 32 + eg * 16) = ov;
    }
}

// Layer 2 fused with W3: h2 is fp8 e4m3 (128 B rows), 4-edge-parallel wave structure
// (eg = lane>>4, ch = lane&15), lane loads 8 B (dwordx2) per row. a2 = relu(agg+b2);
// z = a2 @ W3 (128x2) via per-lane partials + shuffle reduce.
__global__ __launch_bounds__(256) void agg128_w3_kernel(const unsigned char* __restrict__ h,
                                                        const int* __restrict__ rp,
                                                        const int2* __restrict__ ecw,
                                                        const float* __restrict__ dinv,
                                                        const float* __restrict__ b2,
                                                        const float* __restrict__ W3,
                                                        float* __restrict__ z, int n) {
    int node = blockIdx.x * 4 + (threadIdx.x >> 6);
    int lane = threadIdx.x & 63;
    if (node >= n) return;
    const int eg = lane >> 4;                    // edge slot 0..3
    const int ch = lane & 15;                    // 8B chunk (8 fp8 channels)
    float di = dinv[node];

    float acc[8];
    {
        u32x2 v = *(const u32x2*)(h + (size_t)node * 128 + ch * 8);
        float ws = (eg == 0) ? di * di : 0.f;
        f32x2 l0 = __builtin_amdgcn_cvt_pk_f32_fp8(v.x, false);
        f32x2 h0 = __builtin_amdgcn_cvt_pk_f32_fp8(v.x, true);
        f32x2 l1 = __builtin_amdgcn_cvt_pk_f32_fp8(v.y, false);
        f32x2 h1 = __builtin_amdgcn_cvt_pk_f32_fp8(v.y, true);
        acc[0] = ws * l0.x; acc[1] = ws * l0.y; acc[2] = ws * h0.x; acc[3] = ws * h0.y;
        acc[4] = ws * l1.x; acc[5] = ws * l1.y; acc[6] = ws * h1.x; acc[7] = ws * h1.y;
    }

    int e0 = rp[node], e1 = rp[node + 1];
    for (int base = e0; base < e1; base += 64) {
        int idx = base + lane;
        int2 er = (idx < e1) ? ecw[idx] : make_int2(0, 0);
        int sb = er.x;
        float wb = __int_as_float(er.y);
        int cnt = e1 - base; if (cnt > 64) cnt = 64;
#pragma unroll 4
        for (int i = 0; i < cnt; i += 4) {
            int s = __shfl(sb, i + eg, 64);
            float w = __shfl(wb, i + eg, 64);
            u32x2 v = *(const u32x2*)(h + (size_t)s * 128 + ch * 8);
            f32x2 l0 = __builtin_amdgcn_cvt_pk_f32_fp8(v.x, false);
            f32x2 h0 = __builtin_amdgcn_cvt_pk_f32_fp8(v.x, true);
            f32x2 l1 = __builtin_amdgcn_cvt_pk_f32_fp8(v.y, false);
            f32x2 h1 = __builtin_amdgcn_cvt_pk_f32_fp8(v.y, true);
            acc[0] += w * l0.x; acc[1] += w * l0.y; acc[2] += w * h0.x; acc[3] += w * h0.y;
            acc[4] += w * l1.x; acc[5] += w * l1.y; acc[6] += w * h1.x; acc[7] += w * h1.y;
        }
    }

#pragma unroll
    for (int k = 0; k < 8; ++k) {
        acc[k] += __shfl_xor(acc[k], 16, 64);
        acc[k] += __shfl_xor(acc[k], 32, 64);
    }

    // a2 = relu(acc + b2); z partials over this lane's 8 channels
    float z0 = 0.f, z1 = 0.f;
#pragma unroll
    for (int k = 0; k < 8; ++k) {
        float a = fmaxf(acc[k] + b2[ch * 8 + k], 0.f);
        z0 += a * W3[(ch * 8 + k) * 2];
        z1 += a * W3[(ch * 8 + k) * 2 + 1];
    }
    // reduce over the 16 ch groups (all eg groups hold identical values)
    for (int off = 8; off > 0; off >>= 1) {
        z0 += __shfl_xor(z0, off, 64);
        z1 += __shfl_xor(z1, off, 64);
    }
    if (lane == 0) {
        z[2 * (size_t)node] = z0;
        z[2 * (size_t)node + 1] = z1;
    }
}

// agg3: wave per node, 64-lane edge-parallel gather of z pairs + xor-tree reduce.
// Packed edge records (one 8B load per lane).
__global__ __launch_bounds__(256) void agg3_kernel(const float* __restrict__ z,
                                                   const int* __restrict__ rp,
                                                   const int2* __restrict__ ecw,
                                                   const float* __restrict__ dinv,
                                                   const float* __restrict__ bias,
                                                   float* __restrict__ out, int n) {
    int node = blockIdx.x * 4 + (threadIdx.x >> 6);
    int lane = threadIdx.x & 63;
    if (node >= n) return;
    float a0 = 0.f, a1 = 0.f;
    int e0 = rp[node], e1 = rp[node + 1];
    for (int idx = e0 + lane; idx < e1; idx += 64) {
        int2 er = ecw[idx];
        float w = __int_as_float(er.y);
        float2 zz = *(const float2*)(z + 2 * (size_t)er.x);
        a0 += w * zz.x;
        a1 += w * zz.y;
    }
    for (int off = 32; off > 0; off >>= 1) {
        a0 += __shfl_xor(a0, off, 64);
        a1 += __shfl_xor(a1, off, 64);
    }
    if (lane == 0) {
        float di = dinv[node];
        float2 zn = *(const float2*)(z + 2 * (size_t)node);
        a0 += di * di * zn.x + bias[0];
        a1 += di * di * zn.y + bias[1];
        out[2 * (size_t)node]     = 1.f / (1.f + __expf(-a0));
        out[2 * (size_t)node + 1] = 1.f / (1.f + __expf(-a1));
    }
}

// ---------------- launch ----------------

extern "C" void kernel_launch(void* const* d_in, const int* in_sizes, int n_in,
                              void* d_out, int out_size, void* d_ws, size_t ws_size,
                              hipStream_t stream) {
    const float* x  = (const float*)d_in[0];
    const int*   ei = (const int*)d_in[1];
    const float* W1 = (const float*)d_in[2];
    const float* b1 = (const float*)d_in[3];
    const float* W2 = (const float*)d_in[4];
    const float* b2 = (const float*)d_in[5];
    const float* W3 = (const float*)d_in[6];
    const float* b3 = (const float*)d_in[7];
    float* out = (float*)d_out;

    const int E  = in_sizes[1] / 2;
    const int C1 = in_sizes[3];              // 256
    const int C2 = in_sizes[5];              // 128
    const int K1 = in_sizes[2] / C1;         // 768
    const int N  = in_sizes[0] / K1;         // 50000

    const int* srcv = ei;
    const int* dstv = ei + E;

    char* p = (char*)d_ws;
    auto carve = [&](size_t bytes) {
        char* r = p;
        p += (bytes + 255) & ~(size_t)255;
        return r;
    };
    int*   cnt    = (int*)carve((size_t)N * 4);
    int*   rp     = (int*)carve((size_t)(N + 1) * 4);
    int*   cursor = (int*)carve((size_t)N * 4);
    float* dinv   = (float*)carve((size_t)N * 4);
    int*   bsum   = (int*)carve(1024 * 4);
    int2*  ecw    = (int2*)carve((size_t)E * 8);                     // packed {src, w}
    short* Wt1    = (short*)carve((size_t)K1 * C1 * 2);
    short* Wt2    = (short*)carve((size_t)C1 * C2 * 2);
    unsigned char* h8 = (unsigned char*)carve((size_t)N * C1);       // fp8 h1
    unsigned short* hB = (unsigned short*)carve((size_t)N * C1 * 2); // bf16 a1
    unsigned char* h2 = (unsigned char*)carve((size_t)N * C2);       // fp8 h2
    float* zbuf   = (float*)carve((size_t)N * 2 * 4);

    const int nb = (N + 1023) / 1024;
    const int cb = (E + 255) / 256;
    const int w1b = (K1 * C1) / 256;         // 768
    const int w2b = (C1 * C2) / 256;         // 128
    const int g1b = (N + 31) / 32;           // gemm1 blocks
    const int fb  = (E + 255) / 256;         // fill blocks

    // CSR + weight prep (fused)
    hipMemsetAsync(cnt, 0, (size_t)N * 4, stream);
    prep_kernel<<<cb + w1b + w2b, 256, 0, stream>>>(dstv, cnt, E, W1, Wt1, W2, Wt2, cb, w1b);
    blockscan_kernel<<<nb, 1024, 0, stream>>>(cnt, rp, bsum, N);
    fixup_kernel<<<nb, 1024, 0, stream>>>(rp, bsum, cnt, cursor, dinv, N, E);

    // Layer 1 GEMM fused with CSR fill (interleaved roles, one launch):
    // h1 = x @ W1 (fp8 out) ; ecw/cursor scatter co-resides with gemm1 blocks.
    gemm1_fill_kernel<<<g1b + fb, 256, 0, stream>>>(x, Wt1, h8, N, g1b, fb,
                                                    srcv, dstv, cursor, dinv, ecw, E);
    agg256_f8_kernel<<<(N + 3) / 4, 256, 0, stream>>>(h8, rp, ecw, dinv, b1, hB, N);

    // Layer 2: h2 = a1 @ W2 (64-row panels, fp8 out) ; fused a2 = relu(agg+b2), z = a2 @ W3
    gemm_panel_kernel<unsigned short, 8, 4, 2, 4, true><<<(N + 63) / 64, 256, 0, stream>>>(hB, Wt2, h2, N);
    agg128_w3_kernel<<<(N + 3) / 4, 256, 0, stream>>>(h2, rp, ecw, dinv, b2, W3, zbuf, N);

    // Layer 3 aggregation + sigmoid (wave-parallel)
    agg3_kernel<<<(N + 3) / 4, 256, 0, stream>>>(zbuf, rp, ecw, dinv, b3, out, N);
}

// Round 13
// 404.030 us; speedup vs baseline: 1.1914x; 1.0004x over previous
//
#include <hip/hip_runtime.h>
#include <math.h>

typedef short s16x8 __attribute__((ext_vector_type(8)));
typedef __bf16 b16x8 __attribute__((ext_vector_type(8)));
typedef float f32x4 __attribute__((ext_vector_type(4)));
typedef float f32x2 __attribute__((ext_vector_type(2)));
typedef unsigned int u32x4 __attribute__((ext_vector_type(4)));
typedef unsigned int u32x2 __attribute__((ext_vector_type(2)));

__device__ inline short f2bf(float f) {
    unsigned u = __float_as_uint(f);
    unsigned r = u + 0x7FFFu + ((u >> 16) & 1u);   // RNE
    return (short)(r >> 16);
}
__device__ inline float bf2f(unsigned short u) {
    return __uint_as_float(((unsigned)u) << 16);
}

// ---------------- count (CSR degree) ----------------

__global__ void count_kernel(const int* __restrict__ dst, int* __restrict__ cnt, int E) {
    int e = blockIdx.x * 256 + threadIdx.x;
    if (e < E) atomicAdd(&cnt[dst[e]], 1);
}

// ---------------- fused scan + fixup + weight conversion ----------------
// Blocks [0, SB): single-pass scan — each block LDS-scans its 1024-chunk of cnt,
// publishes (total+1) to bsum with device-scope release (sentinel 0 from memset),
// lanes 0..blockIdx-1 of wave 0 spin-acquire prior totals (all SB blocks co-resident:
// 2 blocks/CU at 1024 thr, SB=49), then writes final rp/cursor/dinv directly.
// Blocks [SB, SB+w1b+w2b): Wt1/Wt2 frag-layout conversion (1024-thread roles) —
// fills the otherwise-idle CUs during the scan.
// Wt chunk layout: [c = k0/32][b = n0/128][nt 0..7][lane 0..63][j 0..7]
//   value = W[c*32 + (lane>>4)*8 + j][b*128 + nt*16 + (lane&15)]

__device__ inline void make_wt_elem(const float* __restrict__ W, short* __restrict__ Wt,
                                    int K, int N, int idx) {
    int NB = N >> 7;
    int j = idx & 7;
    int l = (idx >> 3) & 63;
    int nt = (idx >> 9) & 7;
    int rest = idx >> 12;
    int b = rest % NB;
    int c = rest / NB;
    int k = c * 32 + (l >> 4) * 8 + j;
    int n = b * 128 + nt * 16 + (l & 15);
    Wt[idx] = f2bf(W[(size_t)k * N + n]);
}

__global__ __launch_bounds__(1024) void scanfix_kernel(
        const int* __restrict__ cnt, int* __restrict__ rp, int* __restrict__ cursor,
        float* __restrict__ dinv, int* __restrict__ bsum, int n, int E, int SB,
        const float* __restrict__ W1, short* __restrict__ Wt1,
        const float* __restrict__ W2, short* __restrict__ Wt2, int w1b) {
    int tid = threadIdx.x;
    if (blockIdx.x >= SB) {                    // ---- weight-conversion role ----
        int b = blockIdx.x - SB;
        if (b < w1b) {
            int idx = b * 1024 + tid;
            make_wt_elem(W1, Wt1, 768, 256, idx);
        } else {
            int idx = (b - w1b) * 1024 + tid;
            make_wt_elem(W2, Wt2, 256, 128, idx);
        }
        return;
    }

    // ---- scan role ----
    __shared__ int sdata[1024];
    __shared__ int parts[64];
    __shared__ int carry_s;
    int i = blockIdx.x * 1024 + tid;
    int v = (i < n) ? cnt[i] : 0;
    sdata[tid] = v;
    __syncthreads();
    for (int off = 1; off < 1024; off <<= 1) {
        int t = 0;
        if (tid >= off) t = sdata[tid - off];
        __syncthreads();
        sdata[tid] += t;
        __syncthreads();
    }
    if (tid == 1023)
        __hip_atomic_store(&bsum[blockIdx.x], sdata[1023] + 1,
                           __ATOMIC_RELEASE, __HIP_MEMORY_SCOPE_AGENT);
    int part = 0;
    if (tid < blockIdx.x) {                    // lanes 0..47 of wave 0 (SB <= 49)
        int b;
        while ((b = __hip_atomic_load(&bsum[tid], __ATOMIC_ACQUIRE,
                                      __HIP_MEMORY_SCOPE_AGENT)) == 0) {}
        part = b - 1;
    }
    if (tid < 64) parts[tid] = part;
    __syncthreads();
    if (tid == 0) {
        int c = 0;
        for (int k = 0; k < 64; ++k) c += parts[k];
        carry_s = c;
    }
    __syncthreads();
    int r = sdata[tid] - v + carry_s;          // exclusive prefix + carry
    if (i < n) {
        rp[i] = r;
        cursor[i] = r;
        dinv[i] = rsqrtf((float)cnt[i] + 1.0f);
    }
    if (i == 0) rp[n] = E;
}

// ---------------- fused GEMM1 + fill (interleaved roles) ----------------
// Roles interleaved by block index via Bresenham proportional mapping
// (fid(i) = floor(i*FB/total); block is fill iff fid(i+1) > fid(i)), so fill's
// latency-bound scatter co-resides with gemm1's MFMA blocks for the whole dispatch.

__global__ __launch_bounds__(256, 3) void gemm1_fill_kernel(
        const float* __restrict__ x, const short* __restrict__ Wt,
        unsigned char* __restrict__ h8, int M, int G1B, int FB,
        const int* __restrict__ src, const int* __restrict__ dst,
        int* __restrict__ cursor, const float* __restrict__ dinv,
        int2* __restrict__ ecw, int E) {
    constexpr int KC = 24;                     // 768 / 32
    constexpr int RT = 2;                      // row-tiles -> 32 rows per block
    constexpr int O = KC * 4;                  // 96 octets (8 k-elems) per row
    constexpr int F = KC * RT * 64 / 256;      // 12 frags staged per thread

    __shared__ s16x8 As[KC * RT * 64];         // 48 KB bf16, fragment-ready

    const int tid = threadIdx.x;
    const int total = G1B + FB;
    const long long bi = (long long)blockIdx.x;
    const int fid  = (int)(bi * FB / total);
    const int fid1 = (int)((bi + 1) * FB / total);

    if (fid1 > fid) {                          // ---- fill role ----
        int e = fid * 256 + tid;
        if (e < E) {
            int d = dst[e];
            int s = src[e];
            int p = atomicAdd(&cursor[d], 1);
            ecw[p] = make_int2(s, __float_as_int(dinv[s] * dinv[d]));
        }
        return;
    }
    const int gid = blockIdx.x - fid;          // gemm1 block id, 0..G1B-1

    // ---- gemm1 role ----
    const int m0 = gid * (RT * 16);

    // stage: load fp32 pairs, truncation-pack to bf16
    s16x8 v[F];
#pragma unroll
    for (int i = 0; i < F; ++i) {
        int idx = i * 256 + tid;
        int r = idx / O;
        int o = idx - r * O;
        int row = m0 + r;
        if (row >= M) row = M - 1;
        const float4* fp = (const float4*)(x + (size_t)row * 768 + o * 8);
        float4 f0 = fp[0];
        float4 f1 = fp[1];
        u32x4 pk;
        pk.x = (__float_as_uint(f0.x) >> 16) | (__float_as_uint(f0.y) & 0xFFFF0000u);
        pk.y = (__float_as_uint(f0.z) >> 16) | (__float_as_uint(f0.w) & 0xFFFF0000u);
        pk.z = (__float_as_uint(f1.x) >> 16) | (__float_as_uint(f1.y) & 0xFFFF0000u);
        pk.w = (__float_as_uint(f1.z) >> 16) | (__float_as_uint(f1.w) & 0xFFFF0000u);
        v[i] = __builtin_bit_cast(s16x8, pk);
    }
#pragma unroll
    for (int i = 0; i < F; ++i) {
        int idx = i * 256 + tid;
        int r = idx / O;
        int o = idx - r * O;
        int c = o >> 2, q = o & 3;
        int slot = q * 16 + (((r & 15) + q + ((c & 3) << 2)) & 15);
        As[(c * RT + (r >> 4)) * 64 + slot] = v[i];
    }
    __syncthreads();

    const int lane = tid & 63;
    const int wave = tid >> 6;
    const int b128 = wave >> 1;                // 128-col B block
    const int nt0 = (wave & 1) * 4;            // first 16-col tile inside it
    const int q = lane >> 4;
    const int rl = lane & 15;
    const s16x8* wt = (const s16x8*)Wt;

    f32x4 acc[RT][4];
#pragma unroll
    for (int i = 0; i < RT; ++i)
#pragma unroll
        for (int j = 0; j < 4; ++j)
            acc[i][j] = (f32x4){0.f, 0.f, 0.f, 0.f};

#pragma unroll 4
    for (int c = 0; c < KC; ++c) {
        int slot = q * 16 + ((rl + q + ((c & 3) << 2)) & 15);
        b16x8 areg[RT], breg[4];
#pragma unroll
        for (int i = 0; i < RT; ++i)
            areg[i] = __builtin_bit_cast(b16x8, As[(c * RT + i) * 64 + slot]);
        size_t bb = (size_t)(c * 2 + b128) * 512 + nt0 * 64 + lane;
#pragma unroll
        for (int j = 0; j < 4; ++j)
            breg[j] = __builtin_bit_cast(b16x8, wt[bb + j * 64]);
#pragma unroll
        for (int i = 0; i < RT; ++i)
#pragma unroll
            for (int j = 0; j < 4; ++j)
                acc[i][j] = __builtin_amdgcn_mfma_f32_16x16x32_bf16(areg[i], breg[j], acc[i][j], 0, 0, 0);
    }

    const int quad = lane >> 4;
    const int nl = lane & 15;
#pragma unroll
    for (int i = 0; i < RT; ++i) {
        int rbase = m0 + i * 16 + quad * 4;
#pragma unroll
        for (int j = 0; j < 4; ++j) {
            int col = wave * 64 + j * 16 + nl;
#pragma unroll
            for (int r = 0; r < 4; ++r) {
                int row = rbase + r;
                if (row < M) {
                    unsigned u = __builtin_amdgcn_cvt_pk_fp8_f32(acc[i][j][r], acc[i][j][r], 0, false);
                    h8[(size_t)row * 256 + col] = (unsigned char)(u & 0xFF);
                }
            }
        }
    }
}

// ---------------- row-panel GEMM (bf16 A, layer 2) ----------------
// F8 template flag: epilogue emits fp8 e4m3 bytes (verified passing in r5/r11).

template<typename AT, int KC, int RT, int CW, int MINW, bool F8>
__global__ __launch_bounds__(256, MINW) void gemm_panel_kernel(
        const AT* __restrict__ A, const short* __restrict__ Wt,
        void* __restrict__ Cb, int M) {
    constexpr int K = KC * 32;
    constexpr int O = KC * 4;              // 8-elem octets per row
    constexpr int F = KC * RT / 4;         // frags staged per thread
    constexpr int NCOLS = CW * 64;
    constexpr int NB = NCOLS >> 7;         // 128-col B blocks
    constexpr int MT = RT * CW / 4;        // m-tiles per wave

    __shared__ s16x8 As[KC * RT * 64];

    const int tid = threadIdx.x;
    const int m0 = blockIdx.x * (RT * 16);

    s16x8 v[F];
#pragma unroll
    for (int i = 0; i < F; ++i) {
        int idx = i * 256 + tid;
        int r = idx / O;
        int o = idx - r * O;
        int row = m0 + r;
        if (row >= M) row = M - 1;
        v[i] = *(const s16x8*)((const unsigned short*)A + (size_t)row * K + o * 8);
    }
#pragma unroll
    for (int i = 0; i < F; ++i) {
        int idx = i * 256 + tid;
        int r = idx / O;
        int o = idx - r * O;
        int c = o >> 2, q = o & 3;
        int slot = q * 16 + (((r & 15) + q + ((c & 3) << 2)) & 15);
        As[(c * RT + (r >> 4)) * 64 + slot] = v[i];
    }
    __syncthreads();

    const int lane = tid & 63;
    const int wave = tid >> 6;
    const int cw_i = wave % CW;
    const int rg = wave / CW;
    const int mtb = rg * MT;
    const int b128 = (cw_i * 64) >> 7;
    const int nt0 = (cw_i * 4) & 7;
    const int q = lane >> 4;
    const int rl = lane & 15;
    const s16x8* wt = (const s16x8*)Wt;

    f32x4 acc[MT][4];
#pragma unroll
    for (int i = 0; i < MT; ++i)
#pragma unroll
        for (int j = 0; j < 4; ++j)
            acc[i][j] = (f32x4){0.f, 0.f, 0.f, 0.f};

#pragma unroll 4
    for (int c = 0; c < KC; ++c) {
        int slot = q * 16 + ((rl + q + ((c & 3) << 2)) & 15);
        b16x8 areg[MT], breg[4];
#pragma unroll
        for (int i = 0; i < MT; ++i)
            areg[i] = __builtin_bit_cast(b16x8, As[(c * RT + mtb + i) * 64 + slot]);
        size_t bb = (size_t)(c * NB + b128) * 512 + nt0 * 64 + lane;
#pragma unroll
        for (int j = 0; j < 4; ++j)
            breg[j] = __builtin_bit_cast(b16x8, wt[bb + j * 64]);
#pragma unroll
        for (int i = 0; i < MT; ++i)
#pragma unroll
            for (int j = 0; j < 4; ++j)
                acc[i][j] = __builtin_amdgcn_mfma_f32_16x16x32_bf16(areg[i], breg[j], acc[i][j], 0, 0, 0);
    }

    const int quad = lane >> 4;
    const int nl = lane & 15;
#pragma unroll
    for (int i = 0; i < MT; ++i) {
        int rbase = m0 + (mtb + i) * 16 + quad * 4;
#pragma unroll
        for (int j = 0; j < 4; ++j) {
            int col = cw_i * 64 + j * 16 + nl;
#pragma unroll
            for (int rr = 0; rr < 4; ++rr) {
                int row = rbase + rr;
                if (row < M) {
                    if (F8) {
                        unsigned u = __builtin_amdgcn_cvt_pk_fp8_f32(acc[i][j][rr], acc[i][j][rr], 0, false);
                        ((unsigned char*)Cb)[(size_t)row * NCOLS + col] = (unsigned char)(u & 0xFF);
                    } else {
                        ((unsigned short*)Cb)[(size_t)row * NCOLS + col] = (unsigned short)f2bf(acc[i][j][rr]);
                    }
                }
            }
        }
    }
}

// ---------------- aggregation ----------------
// 4-edge-parallel gather. Wave per node; lane = (eg = edge slot 0..3, ch = chunk).
// Edge records packed (int2 {src, weight}); inner loop unroll 4.
// Cross-lane xor(16/32) reduction combines the 4 edge slots once per node.

__global__ __launch_bounds__(256) void agg256_f8_kernel(const unsigned char* __restrict__ h8,
                                                        const int* __restrict__ rp,
                                                        const int2* __restrict__ ecw,
                                                        const float* __restrict__ dinv,
                                                        const float* __restrict__ bias,
                                                        unsigned short* __restrict__ out, int n) {
    int node = blockIdx.x * 4 + (threadIdx.x >> 6);
    int lane = threadIdx.x & 63;
    if (node >= n) return;
    const int eg = lane >> 4;                    // edge slot 0..3
    const int ch = lane & 15;                    // 16-channel chunk
    float di = dinv[node];

    float acc[16];
    {
        u32x4 v = *(const u32x4*)(h8 + (size_t)node * 256 + ch * 16);
        float ws = (eg == 0) ? di * di : 0.f;    // self term counted once
#pragma unroll
        for (int u = 0; u < 4; ++u) {
            f32x2 lo = __builtin_amdgcn_cvt_pk_f32_fp8(v[u], false);
            f32x2 hi = __builtin_amdgcn_cvt_pk_f32_fp8(v[u], true);
            acc[u * 4 + 0] = ws * lo.x; acc[u * 4 + 1] = ws * lo.y;
            acc[u * 4 + 2] = ws * hi.x; acc[u * 4 + 3] = ws * hi.y;
        }
    }

    int e0 = rp[node], e1 = rp[node + 1];
    for (int base = e0; base < e1; base += 64) {
        int idx = base + lane;
        int2 er = (idx < e1) ? ecw[idx] : make_int2(0, 0);
        int sb = er.x;
        float wb = __int_as_float(er.y);
        int cnt = e1 - base; if (cnt > 64) cnt = 64;
#pragma unroll 4
        for (int i = 0; i < cnt; i += 4) {
            int s = __shfl(sb, i + eg, 64);       // i+eg <= 63 always (i step 4, i<=60)
            float w = __shfl(wb, i + eg, 64);
            u32x4 v = *(const u32x4*)(h8 + (size_t)s * 256 + ch * 16);
#pragma unroll
            for (int u = 0; u < 4; ++u) {
                f32x2 lo = __builtin_amdgcn_cvt_pk_f32_fp8(v[u], false);
                f32x2 hi = __builtin_amdgcn_cvt_pk_f32_fp8(v[u], true);
                acc[u * 4 + 0] += w * lo.x; acc[u * 4 + 1] += w * lo.y;
                acc[u * 4 + 2] += w * hi.x; acc[u * 4 + 3] += w * hi.y;
            }
        }
    }

    // combine the 4 edge slots
#pragma unroll
    for (int k = 0; k < 16; ++k) {
        acc[k] += __shfl_xor(acc[k], 16, 64);
        acc[k] += __shfl_xor(acc[k], 32, 64);
    }

    // bias + relu + pack to bf16; lanes eg 0/1 store the two 16B halves of the 32B chunk
    unsigned pk[8];
#pragma unroll
    for (int k = 0; k < 8; ++k) {
        float b0 = bias[ch * 16 + 2 * k];
        float b1 = bias[ch * 16 + 2 * k + 1];
        float a0 = fmaxf(acc[2 * k] + b0, 0.f);
        float a1 = fmaxf(acc[2 * k + 1] + b1, 0.f);
        pk[k] = ((unsigned)(unsigned short)f2bf(a0)) | (((unsigned)(unsigned short)f2bf(a1)) << 16);
    }
    if (eg < 2) {
        u32x4 ov;
        ov.x = pk[eg * 4 + 0]; ov.y = pk[eg * 4 + 1];
        ov.z = pk[eg * 4 + 2]; ov.w = pk[eg * 4 + 3];
        *(u32x4*)((char*)out + (size_t)node * 512 + ch * 32 + eg * 16) = ov;
    }
}

// Layer 2 fused with W3: h2 is fp8 e4m3 (128 B rows), 4-edge-parallel wave structure
// (eg = lane>>4, ch = lane&15), lane loads 8 B (dwordx2) per row. a2 = relu(agg+b2);
// z = a2 @ W3 (128x2) via per-lane partials + shuffle reduce.
__global__ __launch_bounds__(256) void agg128_w3_kernel(const unsigned char* __restrict__ h,
                                                        const int* __restrict__ rp,
                                                        const int2* __restrict__ ecw,
                                                        const float* __restrict__ dinv,
                                                        const float* __restrict__ b2,
                                                        const float* __restrict__ W3,
                                                        float* __restrict__ z, int n) {
    int node = blockIdx.x * 4 + (threadIdx.x >> 6);
    int lane = threadIdx.x & 63;
    if (node >= n) return;
    const int eg = lane >> 4;                    // edge slot 0..3
    const int ch = lane & 15;                    // 8B chunk (8 fp8 channels)
    float di = dinv[node];

    float acc[8];
    {
        u32x2 v = *(const u32x2*)(h + (size_t)node * 128 + ch * 8);
        float ws = (eg == 0) ? di * di : 0.f;
        f32x2 l0 = __builtin_amdgcn_cvt_pk_f32_fp8(v.x, false);
        f32x2 h0 = __builtin_amdgcn_cvt_pk_f32_fp8(v.x, true);
        f32x2 l1 = __builtin_amdgcn_cvt_pk_f32_fp8(v.y, false);
        f32x2 h1 = __builtin_amdgcn_cvt_pk_f32_fp8(v.y, true);
        acc[0] = ws * l0.x; acc[1] = ws * l0.y; acc[2] = ws * h0.x; acc[3] = ws * h0.y;
        acc[4] = ws * l1.x; acc[5] = ws * l1.y; acc[6] = ws * h1.x; acc[7] = ws * h1.y;
    }

    int e0 = rp[node], e1 = rp[node + 1];
    for (int base = e0; base < e1; base += 64) {
        int idx = base + lane;
        int2 er = (idx < e1) ? ecw[idx] : make_int2(0, 0);
        int sb = er.x;
        float wb = __int_as_float(er.y);
        int cnt = e1 - base; if (cnt > 64) cnt = 64;
#pragma unroll 4
        for (int i = 0; i < cnt; i += 4) {
            int s = __shfl(sb, i + eg, 64);
            float w = __shfl(wb, i + eg, 64);
            u32x2 v = *(const u32x2*)(h + (size_t)s * 128 + ch * 8);
            f32x2 l0 = __builtin_amdgcn_cvt_pk_f32_fp8(v.x, false);
            f32x2 h0 = __builtin_amdgcn_cvt_pk_f32_fp8(v.x, true);
            f32x2 l1 = __builtin_amdgcn_cvt_pk_f32_fp8(v.y, false);
            f32x2 h1 = __builtin_amdgcn_cvt_pk_f32_fp8(v.y, true);
            acc[0] += w * l0.x; acc[1] += w * l0.y; acc[2] += w * h0.x; acc[3] += w * h0.y;
            acc[4] += w * l1.x; acc[5] += w * l1.y; acc[6] += w * h1.x; acc[7] += w * h1.y;
        }
    }

#pragma unroll
    for (int k = 0; k < 8; ++k) {
        acc[k] += __shfl_xor(acc[k], 16, 64);
        acc[k] += __shfl_xor(acc[k], 32, 64);
    }

    // a2 = relu(acc + b2); z partials over this lane's 8 channels
    float z0 = 0.f, z1 = 0.f;
#pragma unroll
    for (int k = 0; k < 8; ++k) {
        float a = fmaxf(acc[k] + b2[ch * 8 + k], 0.f);
        z0 += a * W3[(ch * 8 + k) * 2];
        z1 += a * W3[(ch * 8 + k) * 2 + 1];
    }
    // reduce over the 16 ch groups (all eg groups hold identical values)
    for (int off = 8; off > 0; off >>= 1) {
        z0 += __shfl_xor(z0, off, 64);
        z1 += __shfl_xor(z1, off, 64);
    }
    if (lane == 0) {
        z[2 * (size_t)node] = z0;
        z[2 * (size_t)node + 1] = z1;
    }
}

// agg3: wave per node, 64-lane edge-parallel gather of z pairs + xor-tree reduce.
// Packed edge records (one 8B load per lane).
__global__ __launch_bounds__(256) void agg3_kernel(const float* __restrict__ z,
                                                   const int* __restrict__ rp,
                                                   const int2* __restrict__ ecw,
                                                   const float* __restrict__ dinv,
                                                   const float* __restrict__ bias,
                                                   float* __restrict__ out, int n) {
    int node = blockIdx.x * 4 + (threadIdx.x >> 6);
    int lane = threadIdx.x & 63;
    if (node >= n) return;
    float a0 = 0.f, a1 = 0.f;
    int e0 = rp[node], e1 = rp[node + 1];
    for (int idx = e0 + lane; idx < e1; idx += 64) {
        int2 er = ecw[idx];
        float w = __int_as_float(er.y);
        float2 zz = *(const float2*)(z + 2 * (size_t)er.x);
        a0 += w * zz.x;
        a1 += w * zz.y;
    }
    for (int off = 32; off > 0; off >>= 1) {
        a0 += __shfl_xor(a0, off, 64);
        a1 += __shfl_xor(a1, off, 64);
    }
    if (lane == 0) {
        float di = dinv[node];
        float2 zn = *(const float2*)(z + 2 * (size_t)node);
        a0 += di * di * zn.x + bias[0];
        a1 += di * di * zn.y + bias[1];
        out[2 * (size_t)node]     = 1.f / (1.f + __expf(-a0));
        out[2 * (size_t)node + 1] = 1.f / (1.f + __expf(-a1));
    }
}

// ---------------- launch ----------------

extern "C" void kernel_launch(void* const* d_in, const int* in_sizes, int n_in,
                              void* d_out, int out_size, void* d_ws, size_t ws_size,
                              hipStream_t stream) {
    const float* x  = (const float*)d_in[0];
    const int*   ei = (const int*)d_in[1];
    const float* W1 = (const float*)d_in[2];
    const float* b1 = (const float*)d_in[3];
    const float* W2 = (const float*)d_in[4];
    const float* b2 = (const float*)d_in[5];
    const float* W3 = (const float*)d_in[6];
    const float* b3 = (const float*)d_in[7];
    float* out = (float*)d_out;

    const int E  = in_sizes[1] / 2;
    const int C1 = in_sizes[3];              // 256
    const int C2 = in_sizes[5];              // 128
    const int K1 = in_sizes[2] / C1;         // 768
    const int N  = in_sizes[0] / K1;         // 50000

    const int* srcv = ei;
    const int* dstv = ei + E;

    char* p = (char*)d_ws;
    auto carve = [&](size_t bytes) {
        char* r = p;
        p += (bytes + 255) & ~(size_t)255;
        return r;
    };
    // cnt and bsum adjacent so one memset zeroes both (bsum sentinel = 0)
    int*   cnt    = (int*)carve((size_t)N * 4);
    int*   bsum   = (int*)carve(1024 * 4);
    int*   rp     = (int*)carve((size_t)(N + 1) * 4);
    int*   cursor = (int*)carve((size_t)N * 4);
    float* dinv   = (float*)carve((size_t)N * 4);
    int2*  ecw    = (int2*)carve((size_t)E * 8);                     // packed {src, w}
    short* Wt1    = (short*)carve((size_t)K1 * C1 * 2);
    short* Wt2    = (short*)carve((size_t)C1 * C2 * 2);
    unsigned char* h8 = (unsigned char*)carve((size_t)N * C1);       // fp8 h1
    unsigned short* hB = (unsigned short*)carve((size_t)N * C1 * 2); // bf16 a1
    unsigned char* h2 = (unsigned char*)carve((size_t)N * C2);       // fp8 h2
    float* zbuf   = (float*)carve((size_t)N * 2 * 4);

    const int nb  = (N + 1023) / 1024;       // scan blocks (49)
    const int cb  = (E + 255) / 256;         // count blocks
    const int w1b = (K1 * C1) / 1024;        // 192 wt1 blocks (1024 thr)
    const int w2b = (C1 * C2) / 1024;        // 32 wt2 blocks
    const int g1b = (N + 31) / 32;           // gemm1 blocks
    const int fb  = (E + 255) / 256;         // fill blocks

    // zero cnt + bsum sentinels in one memset (adjacent carves)
    size_t cntpad = (((size_t)N * 4) + 255) & ~(size_t)255;
    hipMemsetAsync(cnt, 0, cntpad + 1024 * 4, stream);
    count_kernel<<<cb, 256, 0, stream>>>(dstv, cnt, E);
    // fused scan+fixup (device-scope published totals) + Wt1/Wt2 conversion
    scanfix_kernel<<<nb + w1b + w2b, 1024, 0, stream>>>(cnt, rp, cursor, dinv, bsum,
                                                        N, E, nb, W1, Wt1, W2, Wt2, w1b);

    // Layer 1 GEMM fused with CSR fill (interleaved roles, one launch):
    // h1 = x @ W1 (fp8 out) ; ecw/cursor scatter co-resides with gemm1 blocks.
    gemm1_fill_kernel<<<g1b + fb, 256, 0, stream>>>(x, Wt1, h8, N, g1b, fb,
                                                    srcv, dstv, cursor, dinv, ecw, E);
    agg256_f8_kernel<<<(N + 3) / 4, 256, 0, stream>>>(h8, rp, ecw, dinv, b1, hB, N);

    // Layer 2: h2 = a1 @ W2 (64-row panels, fp8 out) ; fused a2 = relu(agg+b2), z = a2 @ W3
    gemm_panel_kernel<unsigned short, 8, 4, 2, 4, true><<<(N + 63) / 64, 256, 0, stream>>>(hB, Wt2, h2, N);
    agg128_w3_kernel<<<(N + 3) / 4, 256, 0, stream>>>(h2, rp, ecw, dinv, b2, W3, zbuf, N);

    // Layer 3 aggregation + sigmoid (wave-parallel)
    agg3_kernel<<<(N + 3) / 4, 256, 0, stream>>>(zbuf, rp, ecw, dinv, b3, out, N);
}